// Round 9
// baseline (239.751 us; speedup 1.0000x reference)
//
#include <hip/hip_runtime.h>

#define CONC_N 2000
#define ITEM_N 20000
#define STU_N  50000
#define NE_CC  40000
#define NE_IC  80000
#define NE_SI  1000000
#define TBUCK  382   // 63+63+79+79+98

typedef unsigned int uint;
typedef unsigned short ushort;
typedef __attribute__((ext_vector_type(8))) short bf16x8;
typedef __attribute__((ext_vector_type(4))) float f32x4;

__device__ __forceinline__ ushort f2bf(float f) {
  uint u = __float_as_uint(f);
  uint r = (u + 0x7FFFu + ((u >> 16) & 1u)) >> 16;
  return (ushort)r;
}

__device__ __forceinline__ bf16x8 packfrag(float4 lo, float4 hi) {
  union { bf16x8 s; uint u[4]; } p;
  p.u[0] = (uint)f2bf(lo.x) | ((uint)f2bf(lo.y) << 16);
  p.u[1] = (uint)f2bf(lo.z) | ((uint)f2bf(lo.w) << 16);
  p.u[2] = (uint)f2bf(hi.x) | ((uint)f2bf(hi.y) << 16);
  p.u[3] = (uint)f2bf(hi.z) | ((uint)f2bf(hi.w) << 16);
  return p.s;
}

// ---------------- CSR structures ----------------

struct CsrG {
  const int* dst; const int* src;
  unsigned* keys; int* srcs; int* offs;
  int E, n, shift, nbuck, tb, sb;
};
struct CsrGs { CsrG g[5]; };

// ------- setup: proj vectors (LDS-staged) + CSR histograms + W->frag-bf16 --

struct ProjDesc { const float* W; const float* a; float* out; };
struct SetupArgs {
  ProjDesc p[10];
  CsrGs G;
  int* pcnt;                 // [5*32][128]
  const float* wsrc[5];
  ushort* wdst[5];           // fragment-ordered bf16, 2048 recs x 16B
};

__global__ __launch_bounds__(256) void setup_k(SetupArgs A) {
  int b = blockIdx.x;
  int tid = threadIdx.x;
  if (b < 10) {              // proj: out = W^T a, LDS-staged coalesced
    __shared__ float Wl[128 * 132];
    __shared__ float a_s[128];
    ProjDesc d = A.p[b];
    #pragma unroll
    for (int i = 0; i < 16; ++i) {
      int s = tid + i * 256;
      int row = s >> 5, c4 = s & 31;
      float4 w = *(const float4*)&d.W[s * 4];
      float* dst = &Wl[row * 132 + c4 * 4];
      dst[0] = w.x; dst[1] = w.y; dst[2] = w.z; dst[3] = w.w;
    }
    if (tid < 128) a_s[tid] = d.a[tid];
    __syncthreads();
    if (tid < 128) {
      float acc = 0.f;
      #pragma unroll 4
      for (int j = 0; j < 128; ++j) acc += Wl[j * 132 + tid] * a_s[j];
      d.out[tid] = acc;
    }
    return;
  }
  if (b >= 170) {            // W fp32 -> fragment-ordered bf16
    int wi = b - 170;
    const float* Ws = A.wsrc[wi];
    ushort* Wd = A.wdst[wi];
    for (int rec = tid; rec < 2048; rec += 256) {
      int lane = rec & 63;
      int kk = (rec >> 6) & 3;
      int nt = rec >> 8;
      int x = lane & 15, g = lane >> 4;
      const float* src = &Ws[(nt * 16 + x) * 128 + kk * 32 + 4 * g];
      float4 lo = *(const float4*)src;
      float4 hi = *(const float4*)(src + 16);
      bf16x8 pk = packfrag(lo, hi);
      *(bf16x8*)&Wd[rec * 8] = pk;
    }
    return;
  }
  int bsel = b - 10;            // 0..159: histogram
  int gi = bsel >> 5, blk = bsel & 31;
  CsrG g = A.G.g[gi];
  __shared__ int lcnt[128];
  if (tid < 128) lcnt[tid] = 0;
  __syncthreads();
  int chunk = (g.E + 31) >> 5;
  int e0 = blk * chunk, e1 = min(g.E, e0 + chunk);
  for (int e = e0 + tid; e < e1; e += 256)
    atomicAdd(&lcnt[g.dst[e] >> g.shift], 1);
  __syncthreads();
  if (tid < 128) A.pcnt[bsel * 128 + tid] = lcnt[tid];
}

// ---------------- CSR scan ----------------

__global__ __launch_bounds__(512) void csr_scan(CsrGs G, const int* __restrict__ pcnt,
                                                int* __restrict__ cur, int* __restrict__ bases) {
  __shared__ int lc[TBUCK];
  __shared__ int lb[TBUCK + 5];
  int tid = threadIdx.x, lane = tid & 63, wv = tid >> 6;
  if (tid < TBUCK) {
    int gi = 0;
    #pragma unroll
    for (int k = 1; k < 5; ++k) if (tid >= G.g[k].tb) gi = k;
    int b = tid - G.g[gi].tb;
    int s = 0;
    for (int blk = 0; blk < 32; ++blk) s += pcnt[((gi << 5) + blk) * 128 + b];
    lc[tid] = s;
  }
  __syncthreads();
  if (wv < 5) {
    CsrG g = G.g[wv];
    int carry = 0;
    for (int base = 0; base < g.nbuck; base += 64) {
      int idx = base + lane;
      int v = (idx < g.nbuck) ? lc[g.tb + idx] : 0;
      int incl = v;
      #pragma unroll
      for (int o = 1; o < 64; o <<= 1) {
        int y = __shfl_up(incl, o);
        if (lane >= o) incl += y;
      }
      if (idx < g.nbuck) lb[g.sb + idx] = carry + incl - v;
      carry += __shfl(incl, 63);
    }
    if (lane == 0) lb[g.sb + g.nbuck] = carry;
  }
  __syncthreads();
  if (tid < TBUCK + 5) bases[tid] = lb[tid];
  if (tid < TBUCK) {
    int gi = 0;
    for (int k = 1; k < 5; ++k) if (tid >= G.g[k].tb) gi = k;
    cur[tid] = lb[tid + gi];
  }
  if (tid < 5) G.g[tid].offs[G.g[tid].n] = G.g[tid].E;
}

// ------------- mid_k: csr_partition ∥ batched MFMA GEMM + rdot ------------

struct GemmDesc { const float* X; ushort* Y; int n, b0; const float* dv[6]; float* dq[6]; };
struct BigC {
  GemmDesc g[5];
  int gemm_blocks;
  const float* rx; const float* rv; float* ro; int rnb;
};

__device__ void partition_body(const CsrGs& G, int* __restrict__ cur, int gi, int bx,
                               int nbx, unsigned char* smem) {
  CsrG g = G.g[gi];
  unsigned* ck = (unsigned*)smem;                 // 16384 B
  unsigned char* cb = smem + 16384;               // 4096 B
  int* lcnt = (int*)(smem + 20480);               // 512 B
  int* lcur = (int*)(smem + 20992);               // 512 B
  int tid = threadIdx.x;
  unsigned dmask = (1u << g.shift) - 1;
  for (int c0 = bx * 4096; c0 < g.E; c0 += nbx * 4096) {
    if (tid < 128) lcnt[tid] = 0;
    __syncthreads();
    #pragma unroll
    for (int i = 0; i < 16; ++i) {
      int e = c0 + i * 256 + tid;
      if (e < g.E) {
        int d = g.dst[e], s = g.src[e];
        int b = d >> g.shift;
        ck[i * 256 + tid] = ((unsigned)(d & dmask) << 16) | (unsigned)s;
        cb[i * 256 + tid] = (unsigned char)b;
        atomicAdd(&lcnt[b], 1);
      } else cb[i * 256 + tid] = 255;
    }
    __syncthreads();
    if (tid < g.nbuck && lcnt[tid] > 0) lcur[tid] = atomicAdd(&cur[g.tb + tid], lcnt[tid]);
    __syncthreads();
    #pragma unroll
    for (int i = 0; i < 16; ++i) {
      int b = cb[i * 256 + tid];
      if (b != 255) {
        int pos = atomicAdd(&lcur[b], 1);
        g.keys[pos] = ck[i * 256 + tid];
      }
    }
    __syncthreads();
  }
}

template <int NV>
__device__ void gemm_bodyT(const GemmDesc& gd, const ushort* __restrict__ Wf, int blk,
                           ushort* lds /*64 x 136*/) {
  int tid = threadIdx.x;
  int lane = tid & 63, wv = tid >> 6;
  int x = lane & 15, g = lane >> 4;
  int row = blk * 64 + wv * 16 + x;
  const float* xr = &gd.X[(size_t)(row < gd.n ? row : 0) * 128];
  bf16x8 afrag[4];
  float dacc[NV == 0 ? 1 : NV];
  #pragma unroll
  for (int v = 0; v < NV; ++v) dacc[v] = 0.f;
  #pragma unroll
  for (int kk = 0; kk < 4; ++kk) {
    float4 lo = *(const float4*)&xr[kk * 32 + 4 * g];
    float4 hi = *(const float4*)&xr[kk * 32 + 16 + 4 * g];
    afrag[kk] = packfrag(lo, hi);
    #pragma unroll
    for (int v = 0; v < NV; ++v) {
      const float* vp = gd.dv[v];
      float4 vlo = *(const float4*)&vp[kk * 32 + 4 * g];
      float4 vhi = *(const float4*)&vp[kk * 32 + 16 + 4 * g];
      dacc[v] += lo.x * vlo.x + lo.y * vlo.y + lo.z * vlo.z + lo.w * vlo.w
               + hi.x * vhi.x + hi.y * vhi.y + hi.z * vhi.z + hi.w * vhi.w;
    }
  }
  #pragma unroll
  for (int v = 0; v < NV; ++v) {
    float dsum = dacc[v];
    dsum += __shfl_xor(dsum, 16);
    dsum += __shfl_xor(dsum, 32);
    if (lane < 16 && row < gd.n) gd.dq[v][row] = dsum;
  }
  f32x4 acc[8];
  #pragma unroll
  for (int t = 0; t < 8; ++t) acc[t] = (f32x4){0.f, 0.f, 0.f, 0.f};
  #pragma unroll
  for (int nt = 0; nt < 8; ++nt) {
    #pragma unroll
    for (int kk = 0; kk < 4; ++kk) {
      union { uint4 u; bf16x8 s; } bu;
      bu.u = *(const uint4*)&Wf[(size_t)((nt * 4 + kk) * 64 + lane) * 8];
      acc[nt] = __builtin_amdgcn_mfma_f32_16x16x32_bf16(afrag[kk], bu.s, acc[nt], 0, 0, 0);
    }
  }
  // stage D (bf16) in LDS, then coalesced global stores
  int lrow = wv * 16 + 4 * g;
  #pragma unroll
  for (int r = 0; r < 4; ++r)
    #pragma unroll
    for (int nt = 0; nt < 8; ++nt)
      lds[(lrow + r) * 136 + nt * 16 + x] = f2bf(acc[nt][r]);
  __syncthreads();
  int rowbase = blk * 64;
  #pragma unroll
  for (int i = 0; i < 4; ++i) {
    int s = tid + i * 256;           // ushort8 slot 0..1023
    int rw = s >> 4, c8 = s & 15;
    int gr = rowbase + rw;
    if (gr < gd.n)
      *(uint4*)&gd.Y[(size_t)gr * 128 + c8 * 8] = *(const uint4*)&lds[rw * 136 + c8 * 8];
  }
}

__device__ void rdot_body(const float* __restrict__ x, const float* __restrict__ v,
                          float* __restrict__ o, int n, int blk, int nblk) {
  int lane = threadIdx.x & 63;
  int wid = (blk * 256 + threadIdx.x) >> 6;
  int nw = nblk * 4;
  float va = v[lane], vb = v[64 + lane];
  for (int r = wid; r < n; r += nw) {
    float a = x[r * 128 + lane] * va + x[r * 128 + 64 + lane] * vb;
    #pragma unroll
    for (int of = 32; of; of >>= 1) a += __shfl_xor(a, of);
    if (lane == 0) o[r] = a;
  }
}

__global__ __launch_bounds__(256) void mid_k(CsrGs G, int* cur, BigC C,
                                             const ushort* W0, const ushort* W1,
                                             const ushort* W2, const ushort* W3,
                                             const ushort* W4) {
  __shared__ __align__(16) unsigned char smem[21504];
  int b = blockIdx.x;
  if (b < 600) {
    partition_body(G, cur, b / 120, b % 120, 120, smem);
    return;
  }
  b -= 600;
  if (b < C.gemm_blocks) {
    ushort* lds = (ushort*)smem;
    if (b < C.g[1].b0)      gemm_bodyT<6>(C.g[0], W0, b - C.g[0].b0, lds);
    else if (b < C.g[2].b0) gemm_bodyT<4>(C.g[1], W1, b - C.g[1].b0, lds);
    else if (b < C.g[3].b0) gemm_bodyT<0>(C.g[2], W2, b - C.g[2].b0, lds);
    else if (b < C.g[4].b0) gemm_bodyT<1>(C.g[3], W3, b - C.g[3].b0, lds);
    else                    gemm_bodyT<0>(C.g[4], W4, b - C.g[4].b0, lds);
  } else {
    rdot_body(C.rx, C.rv, C.ro, STU_N, b - C.gemm_blocks, C.rnb);
  }
}

// ---------------- csr_build ----------------

__global__ __launch_bounds__(256) void csr_build(CsrGs G, const int* __restrict__ bases) {
  int bid = blockIdx.x;
  int gi = 0;
  for (int k = 1; k < 5; ++k) if (bid >= G.g[k].tb) gi = k;
  CsrG g = G.g[gi];
  int b = bid - g.tb;
  int base = bases[g.sb + b];
  int cnt = bases[g.sb + b + 1] - base;
  if (cnt > 16384) cnt = 16384;

  __shared__ unsigned lkeys[16384];
  __shared__ int lh[512], lex[512], lcu[512], wsum[4];
  int tid = threadIdx.x;
  lh[tid] = 0; lh[tid + 256] = 0;
  __syncthreads();
  for (int j = tid; j < cnt; j += 256) {
    unsigned k = g.keys[base + j];
    lkeys[j] = k;
    atomicAdd(&lh[k >> 16], 1);
  }
  __syncthreads();
  int a0 = lh[2 * tid], a1 = lh[2 * tid + 1];
  int pair = a0 + a1;
  int lane = tid & 63, wv = tid >> 6;
  int incl = pair;
  #pragma unroll
  for (int o = 1; o < 64; o <<= 1) {
    int y = __shfl_up(incl, o);
    if (lane >= o) incl += y;
  }
  if (lane == 63) wsum[wv] = incl;
  __syncthreads();
  if (tid == 0) {
    int s = 0;
    #pragma unroll
    for (int w = 0; w < 4; ++w) { int t = wsum[w]; wsum[w] = s; s += t; }
  }
  __syncthreads();
  int ep = wsum[wv] + incl - pair;
  lex[2 * tid] = ep;       lex[2 * tid + 1] = ep + a0;
  lcu[2 * tid] = ep;       lcu[2 * tid + 1] = ep + a0;
  __syncthreads();
  int dst0 = b << g.shift;
  int ndst = min(1 << g.shift, g.n - dst0);
  for (int dl = tid; dl < ndst; dl += 256) g.offs[dst0 + dl] = base + lex[dl];
  for (int j = tid; j < cnt; j += 256) {
    unsigned k = lkeys[j];
    int dl = k >> 16;
    int pos = atomicAdd(&lcu[dl], 1);
    g.srcs[base + pos] = (int)(k & 0xFFFFu);
  }
}

// ---------------- GAT cores ----------------

__device__ void gat_core_bf(const int* __restrict__ offs, const int* __restrict__ srcs,
                            const float* __restrict__ sl, const float* __restrict__ sr,
                            const uint* __restrict__ xl, int t, int lane, float acc[8]) {
  int sbeg = offs[t], send = offs[t + 1];
  float srt = sr[t];
  int i0l = sbeg + lane;
  bool act0 = i0l < send;
  int s0 = act0 ? srcs[i0l] : 0;
  float e0;
  {
    float e = sl[s0] + srt;
    e = e > 0.f ? e : 0.2f * e;
    e0 = act0 ? e : -1e30f;
  }
  float m = e0, se = act0 ? 1.f : 0.f;
  for (int i = i0l + 64; i < send; i += 64) {
    int s = srcs[i];
    float e = sl[s] + srt;
    e = e > 0.f ? e : 0.2f * e;
    float mn = fmaxf(m, e);
    se = se * __expf(m - mn) + __expf(e - mn);
    m = mn;
  }
  #pragma unroll
  for (int o = 32; o; o >>= 1) {
    float m2 = __shfl_xor(m, o), s2 = __shfl_xor(se, o);
    float mn = fmaxf(m, m2);
    se = se * __expf(m - mn) + s2 * __expf(m2 - mn);
    m = mn;
  }
  float inv = 1.f / (se + 1e-16f);

  int g = lane & 15;
  int q = lane >> 4;
  #pragma unroll
  for (int r = 0; r < 8; ++r) acc[r] = 0.f;

  for (int i0 = sbeg; i0 < send; i0 += 64) {
    int cnt = min(64, send - i0);
    int s; float wgt;
    if (i0 == sbeg) {
      s = s0;
      wgt = act0 ? __expf(e0 - m) * inv : 0.f;
    } else {
      s = 0; wgt = 0.f;
      if (lane < cnt) {
        s = srcs[i0 + lane];
        float e = sl[s] + srt;
        e = e > 0.f ? e : 0.2f * e;
        wgt = __expf(e - m) * inv;
      }
    }
    int kmax = (cnt + 3) >> 2;
    #pragma unroll 2
    for (int k = 0; k < kmax; ++k) {
      int ej = 4 * k + q;
      int sj = __shfl(s, ej);
      float wj = __shfl(wgt, ej);
      const uint4 u = *(const uint4*)&xl[(size_t)sj * 64 + g * 4];
      acc[0] += wj * __uint_as_float(u.x << 16);
      acc[1] += wj * __uint_as_float(u.x & 0xFFFF0000u);
      acc[2] += wj * __uint_as_float(u.y << 16);
      acc[3] += wj * __uint_as_float(u.y & 0xFFFF0000u);
      acc[4] += wj * __uint_as_float(u.z << 16);
      acc[5] += wj * __uint_as_float(u.z & 0xFFFF0000u);
      acc[6] += wj * __uint_as_float(u.w << 16);
      acc[7] += wj * __uint_as_float(u.w & 0xFFFF0000u);
    }
  }
  #pragma unroll
  for (int r = 0; r < 8; ++r) {
    acc[r] += __shfl_xor(acc[r], 16);
    acc[r] += __shfl_xor(acc[r], 32);
  }
}

__device__ __forceinline__ void gat_store(const float acc[8], const float* base0,
                                          float* out, int t, int lane) {
  int g = lane & 15;
  if (lane < 16) {
    int d = t * 128 + g * 8;
    float4 a0 = make_float4(acc[0], acc[1], acc[2], acc[3]);
    float4 a1 = make_float4(acc[4], acc[5], acc[6], acc[7]);
    if (base0) {
      const float4 b0 = *(const float4*)&base0[d];
      const float4 b1 = *(const float4*)&base0[d + 4];
      a0.x += b0.x; a0.y += b0.y; a0.z += b0.z; a0.w += b0.w;
      a1.x += b1.x; a1.y += b1.y; a1.z += b1.z; a1.w += b1.w;
    }
    *(float4*)&out[d] = a0;
    *(float4*)&out[d + 4] = a1;
  }
}

__device__ void c1c2_body(const int* offs, const int* srcs, const float* sl,
                          const float* sr, const uint* xl, const float* al,
                          float* o, float* slo, int t, int lane) {
  float acc[8];
  gat_core_bf(offs, srcs, sl, sr, xl, t, lane, acc);
  int g = lane & 15;
  float4 v0 = *(const float4*)&al[g * 8];
  float4 v1 = *(const float4*)&al[g * 8 + 4];
  float p = acc[0] * v0.x + acc[1] * v0.y + acc[2] * v0.z + acc[3] * v0.w +
            acc[4] * v1.x + acc[5] * v1.y + acc[6] * v1.z + acc[7] * v1.w;
  #pragma unroll
  for (int o2 = 8; o2; o2 >>= 1) p += __shfl_xor(p, o2);
  if (lane == 0) slo[t] = p;
  if (lane < 16) {
    int d = t * 128 + g * 8;
    *(float4*)&o[d] = make_float4(acc[0], acc[1], acc[2], acc[3]);
    *(float4*)&o[d + 4] = make_float4(acc[4], acc[5], acc[6], acc[7]);
  }
}

__device__ void gat_dual_core(const int* __restrict__ offs, const int* __restrict__ srcs,
                              const float* __restrict__ sl1, const float* __restrict__ sr1,
                              const float* __restrict__ xl1,
                              const float* __restrict__ sl2, const float* __restrict__ sr2,
                              const float* __restrict__ xl2,
                              const float* __restrict__ base,
                              float* __restrict__ out, int t, int lane) {
  int sbeg = offs[t], send = offs[t + 1];
  float srt1 = sr1[t], srt2 = sr2[t];
  float m1 = -1e30f, m2 = -1e30f;
  for (int i = sbeg + lane; i < send; i += 64) {
    int s = srcs[i];
    float e1 = sl1[s] + srt1; e1 = e1 > 0.f ? e1 : 0.2f * e1;
    float e2 = sl2[s] + srt2; e2 = e2 > 0.f ? e2 : 0.2f * e2;
    m1 = fmaxf(m1, e1); m2 = fmaxf(m2, e2);
  }
  #pragma unroll
  for (int o = 32; o; o >>= 1) {
    m1 = fmaxf(m1, __shfl_xor(m1, o));
    m2 = fmaxf(m2, __shfl_xor(m2, o));
  }
  float se1 = 0.f, se2 = 0.f;
  for (int i = sbeg + lane; i < send; i += 64) {
    int s = srcs[i];
    float e1 = sl1[s] + srt1; e1 = e1 > 0.f ? e1 : 0.2f * e1;
    float e2 = sl2[s] + srt2; e2 = e2 > 0.f ? e2 : 0.2f * e2;
    se1 += __expf(e1 - m1); se2 += __expf(e2 - m2);
  }
  #pragma unroll
  for (int o = 32; o; o >>= 1) {
    se1 += __shfl_xor(se1, o);
    se2 += __shfl_xor(se2, o);
  }
  float inv1 = 1.f / (se1 + 1e-16f), inv2 = 1.f / (se2 + 1e-16f);
  float ax = 0.f, ay = 0.f;
  for (int i0 = sbeg; i0 < send; i0 += 64) {
    int cnt = min(64, send - i0);
    int s = 0; float w1 = 0.f, w2 = 0.f;
    if (lane < cnt) {
      s = srcs[i0 + lane];
      float e1 = sl1[s] + srt1; e1 = e1 > 0.f ? e1 : 0.2f * e1;
      float e2 = sl2[s] + srt2; e2 = e2 > 0.f ? e2 : 0.2f * e2;
      w1 = __expf(e1 - m1) * inv1;
      w2 = __expf(e2 - m2) * inv2;
    }
    for (int j = 0; j < cnt; ++j) {
      int sj = __shfl(s, j);
      float wj1 = __shfl(w1, j);
      float wj2 = __shfl(w2, j);
      const float2 v1 = *(const float2*)&xl1[sj * 128 + lane * 2];
      const float2 v2 = *(const float2*)&xl2[sj * 128 + lane * 2];
      ax += wj1 * v1.x + wj2 * v2.x;
      ay += wj1 * v1.y + wj2 * v2.y;
    }
  }
  const float2 b = *(const float2*)&base[t * 128 + lane * 2];
  float2 o2; o2.x = ax + b.x; o2.y = ay + b.y;
  *(float2*)&out[t * 128 + lane * 2] = o2;
}

// ---- gats_k: [s1 | i2->i2buf | i1 | c1c2] all-parallel --------------------

#define NB_S1 12500
#define NB_I2 5000
#define NB_I1 5000

struct GatsArgs {
  const int *offs4, *srcs4; const float *sl_is, *sr_is; const uint* xl_is;
  const float* stu_raw_x; float* out_stu;
  const int *offs3, *srcs3; const float *sl_si, *sr_si; const uint* xl_si; float* i2buf;
  const int *offs2, *srcs2; const float *sl_ci, *sr_ci; const uint* xl_ci;
  const float* item_x; float* out_item;
  const int *offs0, *srcs0; const float *sl_cc, *sr_cc; const uint* xl_cc;
  const float* al_cce; float *c1, *sl_cce;
  const int *offs1, *srcs1; const float *sl_ic, *sr_ic; const uint* xl_ic;
  const float* al_ice; float *c2, *sl_ice;
};

__global__ void gats_k(GatsArgs A) {
  int b = blockIdx.x;
  int lane = threadIdx.x & 63;
  if (b < NB_S1) {
    int t = (b * blockDim.x + threadIdx.x) >> 6;
    if (t >= STU_N) return;
    float acc[8];
    gat_core_bf(A.offs4, A.srcs4, A.sl_is, A.sr_is, A.xl_is, t, lane, acc);
    gat_store(acc, A.stu_raw_x, A.out_stu, t, lane);
  } else if (b < NB_S1 + NB_I2) {
    int t = ((b - NB_S1) * blockDim.x + threadIdx.x) >> 6;
    if (t >= ITEM_N) return;
    float acc[8];
    gat_core_bf(A.offs3, A.srcs3, A.sl_si, A.sr_si, A.xl_si, t, lane, acc);
    gat_store(acc, nullptr, A.i2buf, t, lane);
  } else if (b < NB_S1 + NB_I2 + NB_I1) {
    int t = ((b - NB_S1 - NB_I2) * blockDim.x + threadIdx.x) >> 6;
    if (t >= ITEM_N) return;
    float acc[8];
    gat_core_bf(A.offs2, A.srcs2, A.sl_ci, A.sr_ci, A.xl_ci, t, lane, acc);
    gat_store(acc, A.item_x, A.out_item, t, lane);
  } else {
    int sub = b - NB_S1 - NB_I2 - NB_I1;   // 0..999
    int which = sub >= 500;
    int t = ((sub - which * 500) * blockDim.x + threadIdx.x) >> 6;
    if (t >= CONC_N) return;
    if (!which)
      c1c2_body(A.offs0, A.srcs0, A.sl_cc, A.sr_cc, A.xl_cc, A.al_cce, A.c1, A.sl_cce, t, lane);
    else
      c1c2_body(A.offs1, A.srcs1, A.sl_ic, A.sr_ic, A.xl_ic, A.al_ice, A.c2, A.sl_ice, t, lane);
  }
}

// ---- fin_k: [dual(conc) | out_item += i2buf] ------------------------------

__global__ void fin_k(const int* offs0, const int* srcs0,
                      const float* sl_cce, const float* sr_cce, const float* c1,
                      const float* sl_ice, const float* sr_ice, const float* c2,
                      const float* conc_x, float* out_conc,
                      float* out_item, const float* i2buf) {
  int b = blockIdx.x;
  if (b < 500) {
    int t = (b * blockDim.x + threadIdx.x) >> 6;
    if (t >= CONC_N) return;
    gat_dual_core(offs0, srcs0, sl_cce, sr_cce, c1, sl_ice, sr_ice, c2,
                  conc_x, out_conc, t, threadIdx.x & 63);
  } else {
    int idx = (b - 500) * 256 + threadIdx.x;      // float4 index
    float4 a = *(const float4*)&out_item[idx * 4];
    const float4 v = *(const float4*)&i2buf[idx * 4];
    a.x += v.x; a.y += v.y; a.z += v.z; a.w += v.w;
    *(float4*)&out_item[idx * 4] = a;
  }
}

// ---------------- launch ----------------

extern "C" void kernel_launch(void* const* d_in, const int* in_sizes, int n_in,
                              void* d_out, int out_size, void* d_ws, size_t ws_size,
                              hipStream_t stream) {
  const float* stu_x     = (const float*)d_in[0];
  const float* item_x    = (const float*)d_in[1];
  const float* conc_x    = (const float*)d_in[2];
  const float* stu_raw_x = (const float*)d_in[3];
  const float* W_cc  = (const float*)d_in[4];
  const float* al_cc = (const float*)d_in[5];
  const float* ar_cc = (const float*)d_in[6];
  const float* W_ic  = (const float*)d_in[7];
  const float* al_ic = (const float*)d_in[8];
  const float* ar_ic = (const float*)d_in[9];
  const float* al_cce = (const float*)d_in[10];
  const float* ar_cce = (const float*)d_in[11];
  const float* al_ice = (const float*)d_in[12];
  const float* ar_ice = (const float*)d_in[13];
  const float* W_ci  = (const float*)d_in[14];
  const float* al_ci = (const float*)d_in[15];
  const float* ar_ci = (const float*)d_in[16];
  const float* W_si  = (const float*)d_in[17];
  const float* al_si = (const float*)d_in[18];
  const float* ar_si = (const float*)d_in[19];
  const float* W_is  = (const float*)d_in[22];
  const float* al_is = (const float*)d_in[23];
  const float* ar_is = (const float*)d_in[24];
  const int* cc_src  = (const int*)d_in[25];
  const int* cc_dst  = (const int*)d_in[26];
  const int* ic_item = (const int*)d_in[27];
  const int* ic_conc = (const int*)d_in[28];
  const int* si_stu  = (const int*)d_in[29];
  const int* si_item = (const int*)d_in[30];

  char* wsb = (char*)d_ws;
  size_t off = 0;
  auto alloc = [&](size_t bytes) -> void* {
    void* p = wsb + off;
    off = (off + bytes + 255) & ~(size_t)255;
    return p;
  };

  ushort* concWcc = (ushort*)alloc((size_t)CONC_N * 128 * 2);
  ushort* itemWic = (ushort*)alloc((size_t)ITEM_N * 128 * 2);
  ushort* concWci = (ushort*)alloc((size_t)CONC_N * 128 * 2);
  ushort* stuWsi  = (ushort*)alloc((size_t)STU_N  * 128 * 2);
  ushort* itemWis = (ushort*)alloc((size_t)ITEM_N * 128 * 2);
  ushort* Wbf[5];
  for (int i = 0; i < 5; ++i) Wbf[i] = (ushort*)alloc(128 * 128 * 2);
  float* c1buf   = (float*)alloc((size_t)CONC_N * 128 * 4);
  float* c2buf   = (float*)alloc((size_t)CONC_N * 128 * 4);
  float* i2buf   = (float*)alloc((size_t)ITEM_N * 128 * 4);
  float* vecs    = (float*)alloc(10 * 128 * 4);
  float* sl_cc  = (float*)alloc(CONC_N * 4);
  float* sr_cc  = (float*)alloc(CONC_N * 4);
  float* sl_ic  = (float*)alloc(ITEM_N * 4);
  float* sr_ic  = (float*)alloc(CONC_N * 4);
  float* sl_ci  = (float*)alloc(CONC_N * 4);
  float* sr_ci  = (float*)alloc(ITEM_N * 4);
  float* sl_si  = (float*)alloc(STU_N * 4);
  float* sr_si  = (float*)alloc(ITEM_N * 4);
  float* sl_is  = (float*)alloc(ITEM_N * 4);
  float* sr_is  = (float*)alloc(STU_N * 4);
  float* sl_cce = (float*)alloc(CONC_N * 4);
  float* sr_cce = (float*)alloc(CONC_N * 4);
  float* sl_ice = (float*)alloc(CONC_N * 4);
  float* sr_ice = (float*)alloc(CONC_N * 4);

  unsigned* keys0 = (unsigned*)alloc((size_t)NE_CC * 4);
  unsigned* keys1 = (unsigned*)alloc((size_t)NE_IC * 4);
  unsigned* keys2 = (unsigned*)alloc((size_t)NE_IC * 4);
  unsigned* keys3 = (unsigned*)alloc((size_t)NE_SI * 4);
  unsigned* keys4 = (unsigned*)alloc((size_t)NE_SI * 4);
  int* srcs0 = (int*)alloc((size_t)NE_CC * 4);
  int* srcs1 = (int*)alloc((size_t)NE_IC * 4);
  int* srcs2 = (int*)alloc((size_t)NE_IC * 4);
  int* srcs3 = (int*)alloc((size_t)NE_SI * 4);
  int* srcs4 = (int*)alloc((size_t)NE_SI * 4);
  int* offs0 = (int*)alloc((CONC_N + 1) * 4);
  int* offs1 = (int*)alloc((CONC_N + 1) * 4);
  int* offs2 = (int*)alloc((ITEM_N + 1) * 4);
  int* offs3 = (int*)alloc((ITEM_N + 1) * 4);
  int* offs4 = (int*)alloc((STU_N + 1) * 4);
  int* pcnt      = (int*)alloc(5 * 32 * 128 * 4);
  int* cur_all   = (int*)alloc(TBUCK * 4);
  int* bases_all = (int*)alloc((TBUCK + 5) * 4);

  float* out = (float*)d_out;
  float* out_conc = out;
  float* out_item = out + (size_t)CONC_N * 128;
  float* out_stu  = out + (size_t)(CONC_N + ITEM_N) * 128;

  CsrGs G;
  G.g[0] = {cc_dst,  cc_src,  keys0, srcs0, offs0, NE_CC, CONC_N, 5, 63,   0,   0};
  G.g[1] = {ic_conc, ic_item, keys1, srcs1, offs1, NE_IC, CONC_N, 5, 63,  63,  64};
  G.g[2] = {ic_item, ic_conc, keys2, srcs2, offs2, NE_IC, ITEM_N, 8, 79, 126, 128};
  G.g[3] = {si_item, si_stu,  keys3, srcs3, offs3, NE_SI, ITEM_N, 8, 79, 205, 208};
  G.g[4] = {si_stu,  si_item, keys4, srcs4, offs4, NE_SI, STU_N,  9, 98, 284, 288};

  // K1: setup
  SetupArgs SA;
  SA.p[0] = {W_cc, al_cc, vecs + 0 * 128};
  SA.p[1] = {W_cc, ar_cc, vecs + 1 * 128};
  SA.p[2] = {W_ic, al_ic, vecs + 2 * 128};
  SA.p[3] = {W_ic, ar_ic, vecs + 3 * 128};
  SA.p[4] = {W_ci, al_ci, vecs + 4 * 128};
  SA.p[5] = {W_ci, ar_ci, vecs + 5 * 128};
  SA.p[6] = {W_si, al_si, vecs + 6 * 128};
  SA.p[7] = {W_si, ar_si, vecs + 7 * 128};
  SA.p[8] = {W_is, al_is, vecs + 8 * 128};
  SA.p[9] = {W_is, ar_is, vecs + 9 * 128};
  SA.G = G;
  SA.pcnt = pcnt;
  SA.wsrc[0] = W_cc; SA.wsrc[1] = W_ic; SA.wsrc[2] = W_ci;
  SA.wsrc[3] = W_si; SA.wsrc[4] = W_is;
  for (int i = 0; i < 5; ++i) SA.wdst[i] = Wbf[i];
  setup_k<<<175, 256, 0, stream>>>(SA);

  // K2: scan
  csr_scan<<<1, 512, 0, stream>>>(G, pcnt, cur_all, bases_all);

  // K3: partition (600) || gemms+rdot (2496)
  BigC C;
  C.g[0] = {conc_x, concWcc, CONC_N, 0,
            {vecs + 0 * 128, vecs + 1 * 128, vecs + 3 * 128, vecs + 4 * 128, ar_cce, ar_ice},
            {sl_cc, sr_cc, sr_ic, sl_ci, sr_cce, sr_ice}};
  C.g[1] = {item_x, itemWic, ITEM_N, 32,
            {vecs + 2 * 128, vecs + 5 * 128, vecs + 7 * 128, vecs + 8 * 128, nullptr, nullptr},
            {sl_ic, sr_ci, sr_si, sl_is, nullptr, nullptr}};
  C.g[2] = {conc_x, concWci, CONC_N, 345,
            {nullptr, nullptr, nullptr, nullptr, nullptr, nullptr},
            {nullptr, nullptr, nullptr, nullptr, nullptr, nullptr}};
  C.g[3] = {stu_x, stuWsi, STU_N, 377,
            {vecs + 6 * 128, nullptr, nullptr, nullptr, nullptr, nullptr},
            {sl_si, nullptr, nullptr, nullptr, nullptr, nullptr}};
  C.g[4] = {item_x, itemWis, ITEM_N, 1159,
            {nullptr, nullptr, nullptr, nullptr, nullptr, nullptr},
            {nullptr, nullptr, nullptr, nullptr, nullptr, nullptr}};
  C.gemm_blocks = 1472;
  C.rx = stu_raw_x; C.rv = vecs + 9 * 128; C.ro = sr_is; C.rnb = 1024;
  mid_k<<<600 + 2496, 256, 0, stream>>>(G, cur_all, C, Wbf[0], Wbf[1], Wbf[2], Wbf[3], Wbf[4]);

  // K4: build
  csr_build<<<TBUCK, 256, 0, stream>>>(G, bases_all);

  // K5: all independent GATs in one launch
  GatsArgs GA;
  GA.offs4 = offs4; GA.srcs4 = srcs4; GA.sl_is = sl_is; GA.sr_is = sr_is;
  GA.xl_is = (const uint*)itemWis; GA.stu_raw_x = stu_raw_x; GA.out_stu = out_stu;
  GA.offs3 = offs3; GA.srcs3 = srcs3; GA.sl_si = sl_si; GA.sr_si = sr_si;
  GA.xl_si = (const uint*)stuWsi; GA.i2buf = i2buf;
  GA.offs2 = offs2; GA.srcs2 = srcs2; GA.sl_ci = sl_ci; GA.sr_ci = sr_ci;
  GA.xl_ci = (const uint*)concWci; GA.item_x = item_x; GA.out_item = out_item;
  GA.offs0 = offs0; GA.srcs0 = srcs0; GA.sl_cc = sl_cc; GA.sr_cc = sr_cc;
  GA.xl_cc = (const uint*)concWcc; GA.al_cce = al_cce; GA.c1 = c1buf; GA.sl_cce = sl_cce;
  GA.offs1 = offs1; GA.srcs1 = srcs1; GA.sl_ic = sl_ic; GA.sr_ic = sr_ic;
  GA.xl_ic = (const uint*)itemWic; GA.al_ice = al_ice; GA.c2 = c2buf; GA.sl_ice = sl_ice;
  gats_k<<<NB_S1 + NB_I2 + NB_I1 + 1000, 256, 0, stream>>>(GA);

  // K6: dual (needs c1/c2 + their dots) || out_item += i2buf
  fin_k<<<500 + 2500, 256, 0, stream>>>(offs0, srcs0, sl_cce, sr_cce, c1buf,
                                        sl_ice, sr_ice, c2buf, conc_x, out_conc,
                                        out_item, i2buf);
}

// Round 10
// 224.473 us; speedup vs baseline: 1.0681x; 1.0681x over previous
//
#include <hip/hip_runtime.h>

#define CONC_N 2000
#define ITEM_N 20000
#define STU_N  50000
#define NE_CC  40000
#define NE_IC  80000
#define NE_SI  1000000
#define TBUCK  382   // 63+63+79+79+98

typedef unsigned int uint;
typedef unsigned short ushort;
typedef __attribute__((ext_vector_type(8))) short bf16x8;
typedef __attribute__((ext_vector_type(4))) float f32x4;

__device__ __forceinline__ ushort f2bf(float f) {
  uint u = __float_as_uint(f);
  uint r = (u + 0x7FFFu + ((u >> 16) & 1u)) >> 16;
  return (ushort)r;
}

__device__ __forceinline__ bf16x8 packfrag(float4 lo, float4 hi) {
  union { bf16x8 s; uint u[4]; } p;
  p.u[0] = (uint)f2bf(lo.x) | ((uint)f2bf(lo.y) << 16);
  p.u[1] = (uint)f2bf(lo.z) | ((uint)f2bf(lo.w) << 16);
  p.u[2] = (uint)f2bf(hi.x) | ((uint)f2bf(hi.y) << 16);
  p.u[3] = (uint)f2bf(hi.z) | ((uint)f2bf(hi.w) << 16);
  return p.s;
}

// ---------------- CSR structures ----------------

struct CsrG {
  const int* dst; const int* src;
  unsigned* keys; int* srcs; int* offs;
  int E, n, shift, nbuck, tb, sb;
};
struct CsrGs { CsrG g[5]; };

// ------- setup: proj vectors (LDS-staged) + CSR histograms + W->frag-bf16 --

struct ProjDesc { const float* W; const float* a; float* out; };
struct SetupArgs {
  ProjDesc p[10];
  CsrGs G;
  int* pcnt;                 // [5*32][128]
  const float* wsrc[5];
  ushort* wdst[5];           // fragment-ordered bf16, 2048 recs x 16B
};

__global__ __launch_bounds__(256) void setup_k(SetupArgs A) {
  int b = blockIdx.x;
  int tid = threadIdx.x;
  if (b < 10) {              // proj: out = W^T a, LDS-staged coalesced
    __shared__ float Wl[128 * 132];
    __shared__ float a_s[128];
    ProjDesc d = A.p[b];
    #pragma unroll
    for (int i = 0; i < 16; ++i) {
      int s = tid + i * 256;
      int row = s >> 5, c4 = s & 31;
      float4 w = *(const float4*)&d.W[s * 4];
      float* dst = &Wl[row * 132 + c4 * 4];
      dst[0] = w.x; dst[1] = w.y; dst[2] = w.z; dst[3] = w.w;
    }
    if (tid < 128) a_s[tid] = d.a[tid];
    __syncthreads();
    if (tid < 128) {
      float acc = 0.f;
      #pragma unroll 4
      for (int j = 0; j < 128; ++j) acc += Wl[j * 132 + tid] * a_s[j];
      d.out[tid] = acc;
    }
    return;
  }
  if (b >= 170) {            // W fp32 -> fragment-ordered bf16
    int wi = b - 170;
    const float* Ws = A.wsrc[wi];
    ushort* Wd = A.wdst[wi];
    for (int rec = tid; rec < 2048; rec += 256) {
      int lane = rec & 63;
      int kk = (rec >> 6) & 3;
      int nt = rec >> 8;
      int x = lane & 15, g = lane >> 4;
      const float* src = &Ws[(nt * 16 + x) * 128 + kk * 32 + 4 * g];
      float4 lo = *(const float4*)src;
      float4 hi = *(const float4*)(src + 16);
      bf16x8 pk = packfrag(lo, hi);
      *(bf16x8*)&Wd[rec * 8] = pk;
    }
    return;
  }
  int bsel = b - 10;            // 0..159: histogram
  int gi = bsel >> 5, blk = bsel & 31;
  CsrG g = A.G.g[gi];
  __shared__ int lcnt[128];
  if (tid < 128) lcnt[tid] = 0;
  __syncthreads();
  int chunk = (g.E + 31) >> 5;
  int e0 = blk * chunk, e1 = min(g.E, e0 + chunk);
  for (int e = e0 + tid; e < e1; e += 256)
    atomicAdd(&lcnt[g.dst[e] >> g.shift], 1);
  __syncthreads();
  if (tid < 128) A.pcnt[bsel * 128 + tid] = lcnt[tid];
}

// ---------------- CSR scan ----------------

__global__ __launch_bounds__(512) void csr_scan(CsrGs G, const int* __restrict__ pcnt,
                                                int* __restrict__ cur, int* __restrict__ bases) {
  __shared__ int lc[TBUCK];
  __shared__ int lb[TBUCK + 5];
  int tid = threadIdx.x, lane = tid & 63, wv = tid >> 6;
  if (tid < TBUCK) {
    int gi = 0;
    #pragma unroll
    for (int k = 1; k < 5; ++k) if (tid >= G.g[k].tb) gi = k;
    int b = tid - G.g[gi].tb;
    int s = 0;
    for (int blk = 0; blk < 32; ++blk) s += pcnt[((gi << 5) + blk) * 128 + b];
    lc[tid] = s;
  }
  __syncthreads();
  if (wv < 5) {
    CsrG g = G.g[wv];
    int carry = 0;
    for (int base = 0; base < g.nbuck; base += 64) {
      int idx = base + lane;
      int v = (idx < g.nbuck) ? lc[g.tb + idx] : 0;
      int incl = v;
      #pragma unroll
      for (int o = 1; o < 64; o <<= 1) {
        int y = __shfl_up(incl, o);
        if (lane >= o) incl += y;
      }
      if (idx < g.nbuck) lb[g.sb + idx] = carry + incl - v;
      carry += __shfl(incl, 63);
    }
    if (lane == 0) lb[g.sb + g.nbuck] = carry;
  }
  __syncthreads();
  if (tid < TBUCK + 5) bases[tid] = lb[tid];
  if (tid < TBUCK) {
    int gi = 0;
    for (int k = 1; k < 5; ++k) if (tid >= G.g[k].tb) gi = k;
    cur[tid] = lb[tid + gi];
  }
  if (tid < 5) G.g[tid].offs[G.g[tid].n] = G.g[tid].E;
}

// ---------------- csr_partition (standalone) ----------------

__global__ __launch_bounds__(256) void csr_partition(CsrGs G, int* __restrict__ cur) {
  CsrG g = G.g[blockIdx.y];
  __shared__ unsigned ck[4096];
  __shared__ unsigned char cb[4096];
  __shared__ int lcnt[128], lcur[128];
  int tid = threadIdx.x;
  unsigned dmask = (1u << g.shift) - 1;
  for (int c0 = blockIdx.x * 4096; c0 < g.E; c0 += gridDim.x * 4096) {
    if (tid < 128) lcnt[tid] = 0;
    __syncthreads();
    #pragma unroll
    for (int i = 0; i < 16; ++i) {
      int e = c0 + i * 256 + tid;
      if (e < g.E) {
        int d = g.dst[e], s = g.src[e];
        int b = d >> g.shift;
        ck[i * 256 + tid] = ((unsigned)(d & dmask) << 16) | (unsigned)s;
        cb[i * 256 + tid] = (unsigned char)b;
        atomicAdd(&lcnt[b], 1);
      } else cb[i * 256 + tid] = 255;
    }
    __syncthreads();
    if (tid < g.nbuck && lcnt[tid] > 0) lcur[tid] = atomicAdd(&cur[g.tb + tid], lcnt[tid]);
    __syncthreads();
    #pragma unroll
    for (int i = 0; i < 16; ++i) {
      int b = cb[i * 256 + tid];
      if (b != 255) {
        int pos = atomicAdd(&lcur[b], 1);
        g.keys[pos] = ck[i * 256 + tid];
      }
    }
    __syncthreads();
  }
}

// ------------- big_compute: batched MFMA GEMM (+fused dots) + rdot --------

struct GemmDesc { const float* X; ushort* Y; int n, b0; const float* dv[6]; float* dq[6]; };
struct BigC {
  GemmDesc g[5];
  int gemm_blocks;
  const float* rx; const float* rv; float* ro; int rnb;
};

template <int NV>
__device__ void gemm_bodyT(const GemmDesc& gd, const ushort* __restrict__ Wf, int blk) {
  int tid = threadIdx.x;
  int lane = tid & 63, wv = tid >> 6;
  int x = lane & 15, g = lane >> 4;
  int row = blk * 64 + wv * 16 + x;
  const float* xr = &gd.X[(size_t)(row < gd.n ? row : 0) * 128];
  bf16x8 afrag[4];
  float dacc[NV == 0 ? 1 : NV];
  #pragma unroll
  for (int v = 0; v < NV; ++v) dacc[v] = 0.f;
  #pragma unroll
  for (int kk = 0; kk < 4; ++kk) {
    float4 lo = *(const float4*)&xr[kk * 32 + 4 * g];
    float4 hi = *(const float4*)&xr[kk * 32 + 16 + 4 * g];
    afrag[kk] = packfrag(lo, hi);
    #pragma unroll
    for (int v = 0; v < NV; ++v) {
      const float* vp = gd.dv[v];
      float4 vlo = *(const float4*)&vp[kk * 32 + 4 * g];
      float4 vhi = *(const float4*)&vp[kk * 32 + 16 + 4 * g];
      dacc[v] += lo.x * vlo.x + lo.y * vlo.y + lo.z * vlo.z + lo.w * vlo.w
               + hi.x * vhi.x + hi.y * vhi.y + hi.z * vhi.z + hi.w * vhi.w;
    }
  }
  #pragma unroll
  for (int v = 0; v < NV; ++v) {
    float dsum = dacc[v];
    dsum += __shfl_xor(dsum, 16);
    dsum += __shfl_xor(dsum, 32);
    if (lane < 16 && row < gd.n) gd.dq[v][row] = dsum;
  }
  f32x4 acc[8];
  #pragma unroll
  for (int t = 0; t < 8; ++t) acc[t] = (f32x4){0.f, 0.f, 0.f, 0.f};
  #pragma unroll
  for (int nt = 0; nt < 8; ++nt) {
    #pragma unroll
    for (int kk = 0; kk < 4; ++kk) {
      union { uint4 u; bf16x8 s; } bu;
      bu.u = *(const uint4*)&Wf[(size_t)((nt * 4 + kk) * 64 + lane) * 8];
      acc[nt] = __builtin_amdgcn_mfma_f32_16x16x32_bf16(afrag[kk], bu.s, acc[nt], 0, 0, 0);
    }
  }
  // D layout: col = lane&15, row = (lane>>4)*4 + r
  int orow = blk * 64 + wv * 16 + 4 * g;
  #pragma unroll
  for (int r = 0; r < 4; ++r) {
    int gr = orow + r;
    if (gr < gd.n) {
      #pragma unroll
      for (int nt = 0; nt < 8; ++nt)
        gd.Y[(size_t)gr * 128 + nt * 16 + x] = f2bf(acc[nt][r]);
    }
  }
}

__device__ void rdot_body(const float* __restrict__ x, const float* __restrict__ v,
                          float* __restrict__ o, int n, int blk, int nblk) {
  int lane = threadIdx.x & 63;
  int wid = (blk * 256 + threadIdx.x) >> 6;
  int nw = nblk * 4;
  float va = v[lane], vb = v[64 + lane];
  for (int r = wid; r < n; r += nw) {
    float a = x[r * 128 + lane] * va + x[r * 128 + 64 + lane] * vb;
    #pragma unroll
    for (int of = 32; of; of >>= 1) a += __shfl_xor(a, of);
    if (lane == 0) o[r] = a;
  }
}

__global__ __launch_bounds__(256, 2) void big_compute(BigC C, const ushort* W0,
                                                      const ushort* W1, const ushort* W2,
                                                      const ushort* W3, const ushort* W4) {
  int b = blockIdx.x;
  if (b < C.gemm_blocks) {
    if (b < C.g[1].b0)      gemm_bodyT<6>(C.g[0], W0, b - C.g[0].b0);
    else if (b < C.g[2].b0) gemm_bodyT<4>(C.g[1], W1, b - C.g[1].b0);
    else if (b < C.g[3].b0) gemm_bodyT<0>(C.g[2], W2, b - C.g[2].b0);
    else if (b < C.g[4].b0) gemm_bodyT<1>(C.g[3], W3, b - C.g[3].b0);
    else                    gemm_bodyT<0>(C.g[4], W4, b - C.g[4].b0);
  } else {
    rdot_body(C.rx, C.rv, C.ro, STU_N, b - C.gemm_blocks, C.rnb);
  }
}

// ---------------- csr_build ----------------

__global__ __launch_bounds__(256) void csr_build(CsrGs G, const int* __restrict__ bases) {
  int bid = blockIdx.x;
  int gi = 0;
  for (int k = 1; k < 5; ++k) if (bid >= G.g[k].tb) gi = k;
  CsrG g = G.g[gi];
  int b = bid - g.tb;
  int base = bases[g.sb + b];
  int cnt = bases[g.sb + b + 1] - base;
  if (cnt > 16384) cnt = 16384;

  __shared__ unsigned lkeys[16384];
  __shared__ int lh[512], lex[512], lcu[512], wsum[4];
  int tid = threadIdx.x;
  lh[tid] = 0; lh[tid + 256] = 0;
  __syncthreads();
  for (int j = tid; j < cnt; j += 256) {
    unsigned k = g.keys[base + j];
    lkeys[j] = k;
    atomicAdd(&lh[k >> 16], 1);
  }
  __syncthreads();
  int a0 = lh[2 * tid], a1 = lh[2 * tid + 1];
  int pair = a0 + a1;
  int lane = tid & 63, wv = tid >> 6;
  int incl = pair;
  #pragma unroll
  for (int o = 1; o < 64; o <<= 1) {
    int y = __shfl_up(incl, o);
    if (lane >= o) incl += y;
  }
  if (lane == 63) wsum[wv] = incl;
  __syncthreads();
  if (tid == 0) {
    int s = 0;
    #pragma unroll
    for (int w = 0; w < 4; ++w) { int t = wsum[w]; wsum[w] = s; s += t; }
  }
  __syncthreads();
  int ep = wsum[wv] + incl - pair;
  lex[2 * tid] = ep;       lex[2 * tid + 1] = ep + a0;
  lcu[2 * tid] = ep;       lcu[2 * tid + 1] = ep + a0;
  __syncthreads();
  int dst0 = b << g.shift;
  int ndst = min(1 << g.shift, g.n - dst0);
  for (int dl = tid; dl < ndst; dl += 256) g.offs[dst0 + dl] = base + lex[dl];
  for (int j = tid; j < cnt; j += 256) {
    unsigned k = lkeys[j];
    int dl = k >> 16;
    int pos = atomicAdd(&lcu[dl], 1);
    g.srcs[base + pos] = (int)(k & 0xFFFFu);
  }
}

// ---------------- GAT cores ----------------

__device__ void gat_core_bf(const int* __restrict__ offs, const int* __restrict__ srcs,
                            const float* __restrict__ sl, const float* __restrict__ sr,
                            const uint* __restrict__ xl, int t, int lane, float acc[8]) {
  int sbeg = offs[t], send = offs[t + 1];
  float srt = sr[t];
  int i0l = sbeg + lane;
  bool act0 = i0l < send;
  int s0 = act0 ? srcs[i0l] : 0;
  float e0;
  {
    float e = sl[s0] + srt;
    e = e > 0.f ? e : 0.2f * e;
    e0 = act0 ? e : -1e30f;
  }
  float m = e0, se = act0 ? 1.f : 0.f;
  for (int i = i0l + 64; i < send; i += 64) {
    int s = srcs[i];
    float e = sl[s] + srt;
    e = e > 0.f ? e : 0.2f * e;
    float mn = fmaxf(m, e);
    se = se * __expf(m - mn) + __expf(e - mn);
    m = mn;
  }
  #pragma unroll
  for (int o = 32; o; o >>= 1) {
    float m2 = __shfl_xor(m, o), s2 = __shfl_xor(se, o);
    float mn = fmaxf(m, m2);
    se = se * __expf(m - mn) + s2 * __expf(m2 - mn);
    m = mn;
  }
  float inv = 1.f / (se + 1e-16f);

  int g = lane & 15;
  int q = lane >> 4;
  #pragma unroll
  for (int r = 0; r < 8; ++r) acc[r] = 0.f;

  for (int i0 = sbeg; i0 < send; i0 += 64) {
    int cnt = min(64, send - i0);
    int s; float wgt;
    if (i0 == sbeg) {
      s = s0;
      wgt = act0 ? __expf(e0 - m) * inv : 0.f;
    } else {
      s = 0; wgt = 0.f;
      if (lane < cnt) {
        s = srcs[i0 + lane];
        float e = sl[s] + srt;
        e = e > 0.f ? e : 0.2f * e;
        wgt = __expf(e - m) * inv;
      }
    }
    int kmax = (cnt + 3) >> 2;
    #pragma unroll 2
    for (int k = 0; k < kmax; ++k) {
      int ej = 4 * k + q;
      int sj = __shfl(s, ej);
      float wj = __shfl(wgt, ej);
      const uint4 u = *(const uint4*)&xl[(size_t)sj * 64 + g * 4];
      acc[0] += wj * __uint_as_float(u.x << 16);
      acc[1] += wj * __uint_as_float(u.x & 0xFFFF0000u);
      acc[2] += wj * __uint_as_float(u.y << 16);
      acc[3] += wj * __uint_as_float(u.y & 0xFFFF0000u);
      acc[4] += wj * __uint_as_float(u.z << 16);
      acc[5] += wj * __uint_as_float(u.z & 0xFFFF0000u);
      acc[6] += wj * __uint_as_float(u.w << 16);
      acc[7] += wj * __uint_as_float(u.w & 0xFFFF0000u);
    }
  }
  #pragma unroll
  for (int r = 0; r < 8; ++r) {
    acc[r] += __shfl_xor(acc[r], 16);
    acc[r] += __shfl_xor(acc[r], 32);
  }
}

__device__ __forceinline__ void gat_store(const float acc[8], const float* base0,
                                          float* out, int t, int lane) {
  int g = lane & 15;
  if (lane < 16) {
    int d = t * 128 + g * 8;
    float4 a0 = make_float4(acc[0], acc[1], acc[2], acc[3]);
    float4 a1 = make_float4(acc[4], acc[5], acc[6], acc[7]);
    if (base0) {
      const float4 b0 = *(const float4*)&base0[d];
      const float4 b1 = *(const float4*)&base0[d + 4];
      a0.x += b0.x; a0.y += b0.y; a0.z += b0.z; a0.w += b0.w;
      a1.x += b1.x; a1.y += b1.y; a1.z += b1.z; a1.w += b1.w;
    }
    *(float4*)&out[d] = a0;
    *(float4*)&out[d + 4] = a1;
  }
}

__device__ void c1c2_body(const int* offs, const int* srcs, const float* sl,
                          const float* sr, const uint* xl, const float* al,
                          float* o, float* slo, int t, int lane) {
  float acc[8];
  gat_core_bf(offs, srcs, sl, sr, xl, t, lane, acc);
  int g = lane & 15;
  float4 v0 = *(const float4*)&al[g * 8];
  float4 v1 = *(const float4*)&al[g * 8 + 4];
  float p = acc[0] * v0.x + acc[1] * v0.y + acc[2] * v0.z + acc[3] * v0.w +
            acc[4] * v1.x + acc[5] * v1.y + acc[6] * v1.z + acc[7] * v1.w;
  #pragma unroll
  for (int o2 = 8; o2; o2 >>= 1) p += __shfl_xor(p, o2);
  if (lane == 0) slo[t] = p;
  if (lane < 16) {
    int d = t * 128 + g * 8;
    *(float4*)&o[d] = make_float4(acc[0], acc[1], acc[2], acc[3]);
    *(float4*)&o[d + 4] = make_float4(acc[4], acc[5], acc[6], acc[7]);
  }
}

__device__ void gat_dual_core(const int* __restrict__ offs, const int* __restrict__ srcs,
                              const float* __restrict__ sl1, const float* __restrict__ sr1,
                              const float* __restrict__ xl1,
                              const float* __restrict__ sl2, const float* __restrict__ sr2,
                              const float* __restrict__ xl2,
                              const float* __restrict__ base,
                              float* __restrict__ out, int t, int lane) {
  int sbeg = offs[t], send = offs[t + 1];
  float srt1 = sr1[t], srt2 = sr2[t];
  float m1 = -1e30f, m2 = -1e30f;
  for (int i = sbeg + lane; i < send; i += 64) {
    int s = srcs[i];
    float e1 = sl1[s] + srt1; e1 = e1 > 0.f ? e1 : 0.2f * e1;
    float e2 = sl2[s] + srt2; e2 = e2 > 0.f ? e2 : 0.2f * e2;
    m1 = fmaxf(m1, e1); m2 = fmaxf(m2, e2);
  }
  #pragma unroll
  for (int o = 32; o; o >>= 1) {
    m1 = fmaxf(m1, __shfl_xor(m1, o));
    m2 = fmaxf(m2, __shfl_xor(m2, o));
  }
  float se1 = 0.f, se2 = 0.f;
  for (int i = sbeg + lane; i < send; i += 64) {
    int s = srcs[i];
    float e1 = sl1[s] + srt1; e1 = e1 > 0.f ? e1 : 0.2f * e1;
    float e2 = sl2[s] + srt2; e2 = e2 > 0.f ? e2 : 0.2f * e2;
    se1 += __expf(e1 - m1); se2 += __expf(e2 - m2);
  }
  #pragma unroll
  for (int o = 32; o; o >>= 1) {
    se1 += __shfl_xor(se1, o);
    se2 += __shfl_xor(se2, o);
  }
  float inv1 = 1.f / (se1 + 1e-16f), inv2 = 1.f / (se2 + 1e-16f);
  float ax = 0.f, ay = 0.f;
  for (int i0 = sbeg; i0 < send; i0 += 64) {
    int cnt = min(64, send - i0);
    int s = 0; float w1 = 0.f, w2 = 0.f;
    if (lane < cnt) {
      s = srcs[i0 + lane];
      float e1 = sl1[s] + srt1; e1 = e1 > 0.f ? e1 : 0.2f * e1;
      float e2 = sl2[s] + srt2; e2 = e2 > 0.f ? e2 : 0.2f * e2;
      w1 = __expf(e1 - m1) * inv1;
      w2 = __expf(e2 - m2) * inv2;
    }
    for (int j = 0; j < cnt; ++j) {
      int sj = __shfl(s, j);
      float wj1 = __shfl(w1, j);
      float wj2 = __shfl(w2, j);
      const float2 v1 = *(const float2*)&xl1[sj * 128 + lane * 2];
      const float2 v2 = *(const float2*)&xl2[sj * 128 + lane * 2];
      ax += wj1 * v1.x + wj2 * v2.x;
      ay += wj1 * v1.y + wj2 * v2.y;
    }
  }
  const float2 b = *(const float2*)&base[t * 128 + lane * 2];
  float2 o2; o2.x = ax + b.x; o2.y = ay + b.y;
  *(float2*)&out[t * 128 + lane * 2] = o2;
}

// ---- gats_k: [s1 | i2->i2buf | i1 | c1c2] all-parallel --------------------

#define NB_S1 12500
#define NB_I2 5000
#define NB_I1 5000

struct GatsArgs {
  const int *offs4, *srcs4; const float *sl_is, *sr_is; const uint* xl_is;
  const float* stu_raw_x; float* out_stu;
  const int *offs3, *srcs3; const float *sl_si, *sr_si; const uint* xl_si; float* i2buf;
  const int *offs2, *srcs2; const float *sl_ci, *sr_ci; const uint* xl_ci;
  const float* item_x; float* out_item;
  const int *offs0, *srcs0; const float *sl_cc, *sr_cc; const uint* xl_cc;
  const float* al_cce; float *c1, *sl_cce;
  const int *offs1, *srcs1; const float *sl_ic, *sr_ic; const uint* xl_ic;
  const float* al_ice; float *c2, *sl_ice;
};

__global__ void gats_k(GatsArgs A) {
  int b = blockIdx.x;
  int lane = threadIdx.x & 63;
  if (b < NB_S1) {
    int t = (b * blockDim.x + threadIdx.x) >> 6;
    if (t >= STU_N) return;
    float acc[8];
    gat_core_bf(A.offs4, A.srcs4, A.sl_is, A.sr_is, A.xl_is, t, lane, acc);
    gat_store(acc, A.stu_raw_x, A.out_stu, t, lane);
  } else if (b < NB_S1 + NB_I2) {
    int t = ((b - NB_S1) * blockDim.x + threadIdx.x) >> 6;
    if (t >= ITEM_N) return;
    float acc[8];
    gat_core_bf(A.offs3, A.srcs3, A.sl_si, A.sr_si, A.xl_si, t, lane, acc);
    gat_store(acc, nullptr, A.i2buf, t, lane);
  } else if (b < NB_S1 + NB_I2 + NB_I1) {
    int t = ((b - NB_S1 - NB_I2) * blockDim.x + threadIdx.x) >> 6;
    if (t >= ITEM_N) return;
    float acc[8];
    gat_core_bf(A.offs2, A.srcs2, A.sl_ci, A.sr_ci, A.xl_ci, t, lane, acc);
    gat_store(acc, A.item_x, A.out_item, t, lane);
  } else {
    int sub = b - NB_S1 - NB_I2 - NB_I1;   // 0..999
    int which = sub >= 500;
    int t = ((sub - which * 500) * blockDim.x + threadIdx.x) >> 6;
    if (t >= CONC_N) return;
    if (!which)
      c1c2_body(A.offs0, A.srcs0, A.sl_cc, A.sr_cc, A.xl_cc, A.al_cce, A.c1, A.sl_cce, t, lane);
    else
      c1c2_body(A.offs1, A.srcs1, A.sl_ic, A.sr_ic, A.xl_ic, A.al_ice, A.c2, A.sl_ice, t, lane);
  }
}

// ---- fin_k: [dual(conc) | out_item += i2buf] ------------------------------

__global__ void fin_k(const int* offs0, const int* srcs0,
                      const float* sl_cce, const float* sr_cce, const float* c1,
                      const float* sl_ice, const float* sr_ice, const float* c2,
                      const float* conc_x, float* out_conc,
                      float* out_item, const float* i2buf) {
  int b = blockIdx.x;
  if (b < 500) {
    int t = (b * blockDim.x + threadIdx.x) >> 6;
    if (t >= CONC_N) return;
    gat_dual_core(offs0, srcs0, sl_cce, sr_cce, c1, sl_ice, sr_ice, c2,
                  conc_x, out_conc, t, threadIdx.x & 63);
  } else {
    int idx = (b - 500) * 256 + threadIdx.x;      // float4 index
    float4 a = *(const float4*)&out_item[idx * 4];
    const float4 v = *(const float4*)&i2buf[idx * 4];
    a.x += v.x; a.y += v.y; a.z += v.z; a.w += v.w;
    *(float4*)&out_item[idx * 4] = a;
  }
}

// ---------------- launch ----------------

extern "C" void kernel_launch(void* const* d_in, const int* in_sizes, int n_in,
                              void* d_out, int out_size, void* d_ws, size_t ws_size,
                              hipStream_t stream) {
  const float* stu_x     = (const float*)d_in[0];
  const float* item_x    = (const float*)d_in[1];
  const float* conc_x    = (const float*)d_in[2];
  const float* stu_raw_x = (const float*)d_in[3];
  const float* W_cc  = (const float*)d_in[4];
  const float* al_cc = (const float*)d_in[5];
  const float* ar_cc = (const float*)d_in[6];
  const float* W_ic  = (const float*)d_in[7];
  const float* al_ic = (const float*)d_in[8];
  const float* ar_ic = (const float*)d_in[9];
  const float* al_cce = (const float*)d_in[10];
  const float* ar_cce = (const float*)d_in[11];
  const float* al_ice = (const float*)d_in[12];
  const float* ar_ice = (const float*)d_in[13];
  const float* W_ci  = (const float*)d_in[14];
  const float* al_ci = (const float*)d_in[15];
  const float* ar_ci = (const float*)d_in[16];
  const float* W_si  = (const float*)d_in[17];
  const float* al_si = (const float*)d_in[18];
  const float* ar_si = (const float*)d_in[19];
  const float* W_is  = (const float*)d_in[22];
  const float* al_is = (const float*)d_in[23];
  const float* ar_is = (const float*)d_in[24];
  const int* cc_src  = (const int*)d_in[25];
  const int* cc_dst  = (const int*)d_in[26];
  const int* ic_item = (const int*)d_in[27];
  const int* ic_conc = (const int*)d_in[28];
  const int* si_stu  = (const int*)d_in[29];
  const int* si_item = (const int*)d_in[30];

  char* wsb = (char*)d_ws;
  size_t off = 0;
  auto alloc = [&](size_t bytes) -> void* {
    void* p = wsb + off;
    off = (off + bytes + 255) & ~(size_t)255;
    return p;
  };

  ushort* concWcc = (ushort*)alloc((size_t)CONC_N * 128 * 2);
  ushort* itemWic = (ushort*)alloc((size_t)ITEM_N * 128 * 2);
  ushort* concWci = (ushort*)alloc((size_t)CONC_N * 128 * 2);
  ushort* stuWsi  = (ushort*)alloc((size_t)STU_N  * 128 * 2);
  ushort* itemWis = (ushort*)alloc((size_t)ITEM_N * 128 * 2);
  ushort* Wbf[5];
  for (int i = 0; i < 5; ++i) Wbf[i] = (ushort*)alloc(128 * 128 * 2);
  float* c1buf   = (float*)alloc((size_t)CONC_N * 128 * 4);
  float* c2buf   = (float*)alloc((size_t)CONC_N * 128 * 4);
  float* i2buf   = (float*)alloc((size_t)ITEM_N * 128 * 4);
  float* vecs    = (float*)alloc(10 * 128 * 4);
  float* sl_cc  = (float*)alloc(CONC_N * 4);
  float* sr_cc  = (float*)alloc(CONC_N * 4);
  float* sl_ic  = (float*)alloc(ITEM_N * 4);
  float* sr_ic  = (float*)alloc(CONC_N * 4);
  float* sl_ci  = (float*)alloc(CONC_N * 4);
  float* sr_ci  = (float*)alloc(ITEM_N * 4);
  float* sl_si  = (float*)alloc(STU_N * 4);
  float* sr_si  = (float*)alloc(ITEM_N * 4);
  float* sl_is  = (float*)alloc(ITEM_N * 4);
  float* sr_is  = (float*)alloc(STU_N * 4);
  float* sl_cce = (float*)alloc(CONC_N * 4);
  float* sr_cce = (float*)alloc(CONC_N * 4);
  float* sl_ice = (float*)alloc(CONC_N * 4);
  float* sr_ice = (float*)alloc(CONC_N * 4);

  unsigned* keys0 = (unsigned*)alloc((size_t)NE_CC * 4);
  unsigned* keys1 = (unsigned*)alloc((size_t)NE_IC * 4);
  unsigned* keys2 = (unsigned*)alloc((size_t)NE_IC * 4);
  unsigned* keys3 = (unsigned*)alloc((size_t)NE_SI * 4);
  unsigned* keys4 = (unsigned*)alloc((size_t)NE_SI * 4);
  int* srcs0 = (int*)alloc((size_t)NE_CC * 4);
  int* srcs1 = (int*)alloc((size_t)NE_IC * 4);
  int* srcs2 = (int*)alloc((size_t)NE_IC * 4);
  int* srcs3 = (int*)alloc((size_t)NE_SI * 4);
  int* srcs4 = (int*)alloc((size_t)NE_SI * 4);
  int* offs0 = (int*)alloc((CONC_N + 1) * 4);
  int* offs1 = (int*)alloc((CONC_N + 1) * 4);
  int* offs2 = (int*)alloc((ITEM_N + 1) * 4);
  int* offs3 = (int*)alloc((ITEM_N + 1) * 4);
  int* offs4 = (int*)alloc((STU_N + 1) * 4);
  int* pcnt      = (int*)alloc(5 * 32 * 128 * 4);
  int* cur_all   = (int*)alloc(TBUCK * 4);
  int* bases_all = (int*)alloc((TBUCK + 5) * 4);

  float* out = (float*)d_out;
  float* out_conc = out;
  float* out_item = out + (size_t)CONC_N * 128;
  float* out_stu  = out + (size_t)(CONC_N + ITEM_N) * 128;

  CsrGs G;
  G.g[0] = {cc_dst,  cc_src,  keys0, srcs0, offs0, NE_CC, CONC_N, 5, 63,   0,   0};
  G.g[1] = {ic_conc, ic_item, keys1, srcs1, offs1, NE_IC, CONC_N, 5, 63,  63,  64};
  G.g[2] = {ic_item, ic_conc, keys2, srcs2, offs2, NE_IC, ITEM_N, 8, 79, 126, 128};
  G.g[3] = {si_item, si_stu,  keys3, srcs3, offs3, NE_SI, ITEM_N, 8, 79, 205, 208};
  G.g[4] = {si_stu,  si_item, keys4, srcs4, offs4, NE_SI, STU_N,  9, 98, 284, 288};

  // K1: setup (proj vectors + CSR histograms + W->frag-bf16)
  SetupArgs SA;
  SA.p[0] = {W_cc, al_cc, vecs + 0 * 128};
  SA.p[1] = {W_cc, ar_cc, vecs + 1 * 128};
  SA.p[2] = {W_ic, al_ic, vecs + 2 * 128};
  SA.p[3] = {W_ic, ar_ic, vecs + 3 * 128};
  SA.p[4] = {W_ci, al_ci, vecs + 4 * 128};
  SA.p[5] = {W_ci, ar_ci, vecs + 5 * 128};
  SA.p[6] = {W_si, al_si, vecs + 6 * 128};
  SA.p[7] = {W_si, ar_si, vecs + 7 * 128};
  SA.p[8] = {W_is, al_is, vecs + 8 * 128};
  SA.p[9] = {W_is, ar_is, vecs + 9 * 128};
  SA.G = G;
  SA.pcnt = pcnt;
  SA.wsrc[0] = W_cc; SA.wsrc[1] = W_ic; SA.wsrc[2] = W_ci;
  SA.wsrc[3] = W_si; SA.wsrc[4] = W_is;
  for (int i = 0; i < 5; ++i) SA.wdst[i] = Wbf[i];
  setup_k<<<175, 256, 0, stream>>>(SA);

  // K2: scan
  csr_scan<<<1, 512, 0, stream>>>(G, pcnt, cur_all, bases_all);

  // K3: partition (standalone, low-VGPR)
  csr_partition<<<dim3(120, 5), 256, 0, stream>>>(G, cur_all);

  // K4: build
  csr_build<<<TBUCK, 256, 0, stream>>>(G, bases_all);

  // K5: batched MFMA gemms (+fused score dots) + stu_raw dot
  BigC C;
  C.g[0] = {conc_x, concWcc, CONC_N, 0,
            {vecs + 0 * 128, vecs + 1 * 128, vecs + 3 * 128, vecs + 4 * 128, ar_cce, ar_ice},
            {sl_cc, sr_cc, sr_ic, sl_ci, sr_cce, sr_ice}};
  C.g[1] = {item_x, itemWic, ITEM_N, 32,
            {vecs + 2 * 128, vecs + 5 * 128, vecs + 7 * 128, vecs + 8 * 128, nullptr, nullptr},
            {sl_ic, sr_ci, sr_si, sl_is, nullptr, nullptr}};
  C.g[2] = {conc_x, concWci, CONC_N, 345,
            {nullptr, nullptr, nullptr, nullptr, nullptr, nullptr},
            {nullptr, nullptr, nullptr, nullptr, nullptr, nullptr}};
  C.g[3] = {stu_x, stuWsi, STU_N, 377,
            {vecs + 6 * 128, nullptr, nullptr, nullptr, nullptr, nullptr},
            {sl_si, nullptr, nullptr, nullptr, nullptr, nullptr}};
  C.g[4] = {item_x, itemWis, ITEM_N, 1159,
            {nullptr, nullptr, nullptr, nullptr, nullptr, nullptr},
            {nullptr, nullptr, nullptr, nullptr, nullptr, nullptr}};
  C.gemm_blocks = 1472;
  C.rx = stu_raw_x; C.rv = vecs + 9 * 128; C.ro = sr_is; C.rnb = 1024;
  big_compute<<<2496, 256, 0, stream>>>(C, Wbf[0], Wbf[1], Wbf[2], Wbf[3], Wbf[4]);

  // K6: all independent GATs in one launch
  GatsArgs GA;
  GA.offs4 = offs4; GA.srcs4 = srcs4; GA.sl_is = sl_is; GA.sr_is = sr_is;
  GA.xl_is = (const uint*)itemWis; GA.stu_raw_x = stu_raw_x; GA.out_stu = out_stu;
  GA.offs3 = offs3; GA.srcs3 = srcs3; GA.sl_si = sl_si; GA.sr_si = sr_si;
  GA.xl_si = (const uint*)stuWsi; GA.i2buf = i2buf;
  GA.offs2 = offs2; GA.srcs2 = srcs2; GA.sl_ci = sl_ci; GA.sr_ci = sr_ci;
  GA.xl_ci = (const uint*)concWci; GA.item_x = item_x; GA.out_item = out_item;
  GA.offs0 = offs0; GA.srcs0 = srcs0; GA.sl_cc = sl_cc; GA.sr_cc = sr_cc;
  GA.xl_cc = (const uint*)concWcc; GA.al_cce = al_cce; GA.c1 = c1buf; GA.sl_cce = sl_cce;
  GA.offs1 = offs1; GA.srcs1 = srcs1; GA.sl_ic = sl_ic; GA.sr_ic = sr_ic;
  GA.xl_ic = (const uint*)itemWic; GA.al_ice = al_ice; GA.c2 = c2buf; GA.sl_ice = sl_ice;
  gats_k<<<NB_S1 + NB_I2 + NB_I1 + 1000, 256, 0, stream>>>(GA);

  // K7: dual (needs c1/c2 + their dots) || out_item += i2buf
  fin_k<<<500 + 2500, 256, 0, stream>>>(offs0, srcs0, sl_cce, sr_cce, c1buf,
                                        sl_ice, sr_ice, c2buf, conc_x, out_conc,
                                        out_item, i2buf);
}

// Round 11
// 208.806 us; speedup vs baseline: 1.1482x; 1.0750x over previous
//
#include <hip/hip_runtime.h>

#define CONC_N 2000
#define ITEM_N 20000
#define STU_N  50000
#define NE_CC  40000
#define NE_IC  80000
#define NE_SI  1000000
#define TBUCK  382   // 63+63+79+79+98

typedef unsigned int uint;
typedef unsigned short ushort;
typedef __attribute__((ext_vector_type(8))) short bf16x8;
typedef __attribute__((ext_vector_type(4))) float f32x4;

__device__ __forceinline__ ushort f2bf(float f) {
  uint u = __float_as_uint(f);
  uint r = (u + 0x7FFFu + ((u >> 16) & 1u)) >> 16;
  return (ushort)r;
}

__device__ __forceinline__ bf16x8 packfrag(float4 lo, float4 hi) {
  union { bf16x8 s; uint u[4]; } p;
  p.u[0] = (uint)f2bf(lo.x) | ((uint)f2bf(lo.y) << 16);
  p.u[1] = (uint)f2bf(lo.z) | ((uint)f2bf(lo.w) << 16);
  p.u[2] = (uint)f2bf(hi.x) | ((uint)f2bf(hi.y) << 16);
  p.u[3] = (uint)f2bf(hi.z) | ((uint)f2bf(hi.w) << 16);
  return p.s;
}

// ---------------- CSR structures ----------------

struct CsrG {
  const int* dst; const int* src;
  unsigned* keys; int* srcs; int* offs;
  int E, n, shift, nbuck, tb, sb;
};
struct CsrGs { CsrG g[5]; };

// ------- setup: proj vectors (LDS-staged) + CSR histograms + W->frag-bf16 --

struct ProjDesc { const float* W; const float* a; float* out; };
struct SetupArgs {
  ProjDesc p[10];
  CsrGs G;
  int* pcnt;                 // [5*32][128]
  const float* wsrc[5];
  ushort* wdst[5];           // fragment-ordered bf16, 2048 recs x 16B
};

__global__ __launch_bounds__(256) void setup_k(SetupArgs A) {
  int b = blockIdx.x;
  int tid = threadIdx.x;
  if (b < 10) {              // proj: out = W^T a, LDS-staged coalesced
    __shared__ float Wl[128 * 132];
    __shared__ float a_s[128];
    ProjDesc d = A.p[b];
    #pragma unroll
    for (int i = 0; i < 16; ++i) {
      int s = tid + i * 256;
      int row = s >> 5, c4 = s & 31;
      float4 w = *(const float4*)&d.W[s * 4];
      float* dst = &Wl[row * 132 + c4 * 4];
      dst[0] = w.x; dst[1] = w.y; dst[2] = w.z; dst[3] = w.w;
    }
    if (tid < 128) a_s[tid] = d.a[tid];
    __syncthreads();
    if (tid < 128) {
      float acc = 0.f;
      #pragma unroll 4
      for (int j = 0; j < 128; ++j) acc += Wl[j * 132 + tid] * a_s[j];
      d.out[tid] = acc;
    }
    return;
  }
  if (b >= 170) {            // W fp32 -> fragment-ordered bf16
    int wi = b - 170;
    const float* Ws = A.wsrc[wi];
    ushort* Wd = A.wdst[wi];
    for (int rec = tid; rec < 2048; rec += 256) {
      int lane = rec & 63;
      int kk = (rec >> 6) & 3;
      int nt = rec >> 8;
      int x = lane & 15, g = lane >> 4;
      const float* src = &Ws[(nt * 16 + x) * 128 + kk * 32 + 4 * g];
      float4 lo = *(const float4*)src;
      float4 hi = *(const float4*)(src + 16);
      bf16x8 pk = packfrag(lo, hi);
      *(bf16x8*)&Wd[rec * 8] = pk;
    }
    return;
  }
  int bsel = b - 10;            // 0..159: histogram
  int gi = bsel >> 5, blk = bsel & 31;
  CsrG g = A.G.g[gi];
  __shared__ int lcnt[128];
  if (tid < 128) lcnt[tid] = 0;
  __syncthreads();
  int chunk = (g.E + 31) >> 5;
  int e0 = blk * chunk, e1 = min(g.E, e0 + chunk);
  for (int e = e0 + tid; e < e1; e += 256)
    atomicAdd(&lcnt[g.dst[e] >> g.shift], 1);
  __syncthreads();
  if (tid < 128) A.pcnt[bsel * 128 + tid] = lcnt[tid];
}

// ---------------- CSR scan ----------------

__global__ __launch_bounds__(512) void csr_scan(CsrGs G, const int* __restrict__ pcnt,
                                                int* __restrict__ cur, int* __restrict__ bases) {
  __shared__ int lc[TBUCK];
  __shared__ int lb[TBUCK + 5];
  int tid = threadIdx.x, lane = tid & 63, wv = tid >> 6;
  if (tid < TBUCK) {
    int gi = 0;
    #pragma unroll
    for (int k = 1; k < 5; ++k) if (tid >= G.g[k].tb) gi = k;
    int b = tid - G.g[gi].tb;
    int s = 0;
    for (int blk = 0; blk < 32; ++blk) s += pcnt[((gi << 5) + blk) * 128 + b];
    lc[tid] = s;
  }
  __syncthreads();
  if (wv < 5) {
    CsrG g = G.g[wv];
    int carry = 0;
    for (int base = 0; base < g.nbuck; base += 64) {
      int idx = base + lane;
      int v = (idx < g.nbuck) ? lc[g.tb + idx] : 0;
      int incl = v;
      #pragma unroll
      for (int o = 1; o < 64; o <<= 1) {
        int y = __shfl_up(incl, o);
        if (lane >= o) incl += y;
      }
      if (idx < g.nbuck) lb[g.sb + idx] = carry + incl - v;
      carry += __shfl(incl, 63);
    }
    if (lane == 0) lb[g.sb + g.nbuck] = carry;
  }
  __syncthreads();
  if (tid < TBUCK + 5) bases[tid] = lb[tid];
  if (tid < TBUCK) {
    int gi = 0;
    for (int k = 1; k < 5; ++k) if (tid >= G.g[k].tb) gi = k;
    cur[tid] = lb[tid + gi];
  }
  if (tid < 5) G.g[tid].offs[G.g[tid].n] = G.g[tid].E;
}

// ------------- mid2_k: csr_partition (600 blks) ∥ MFMA GEMMs + rdot -------
// Partition path uses 21KB LDS; gemm path uses none (per-lane stores, as in
// round-8 big_compute which stayed off the critical profile). launch_bounds
// (256,2) caps VGPR; LDS 21504/block allows 7 blocks/CU.

struct GemmDesc { const float* X; ushort* Y; int n, b0; const float* dv[6]; float* dq[6]; };
struct BigC {
  GemmDesc g[5];
  int gemm_blocks;
  const float* rx; const float* rv; float* ro; int rnb;
};

__device__ void partition_body(const CsrGs& G, int* __restrict__ cur, int gi, int bx,
                               int nbx, unsigned char* smem) {
  CsrG g = G.g[gi];
  unsigned* ck = (unsigned*)smem;                 // 16384 B
  unsigned char* cb = smem + 16384;               // 4096 B
  int* lcnt = (int*)(smem + 20480);               // 512 B
  int* lcur = (int*)(smem + 20992);               // 512 B
  int tid = threadIdx.x;
  unsigned dmask = (1u << g.shift) - 1;
  for (int c0 = bx * 4096; c0 < g.E; c0 += nbx * 4096) {
    if (tid < 128) lcnt[tid] = 0;
    __syncthreads();
    #pragma unroll
    for (int i = 0; i < 16; ++i) {
      int e = c0 + i * 256 + tid;
      if (e < g.E) {
        int d = g.dst[e], s = g.src[e];
        int b = d >> g.shift;
        ck[i * 256 + tid] = ((unsigned)(d & dmask) << 16) | (unsigned)s;
        cb[i * 256 + tid] = (unsigned char)b;
        atomicAdd(&lcnt[b], 1);
      } else cb[i * 256 + tid] = 255;
    }
    __syncthreads();
    if (tid < g.nbuck && lcnt[tid] > 0) lcur[tid] = atomicAdd(&cur[g.tb + tid], lcnt[tid]);
    __syncthreads();
    #pragma unroll
    for (int i = 0; i < 16; ++i) {
      int b = cb[i * 256 + tid];
      if (b != 255) {
        int pos = atomicAdd(&lcur[b], 1);
        g.keys[pos] = ck[i * 256 + tid];
      }
    }
    __syncthreads();
  }
}

template <int NV>
__device__ void gemm_bodyT(const GemmDesc& gd, const ushort* __restrict__ Wf, int blk) {
  int tid = threadIdx.x;
  int lane = tid & 63, wv = tid >> 6;
  int x = lane & 15, g = lane >> 4;
  int row = blk * 64 + wv * 16 + x;
  const float* xr = &gd.X[(size_t)(row < gd.n ? row : 0) * 128];
  bf16x8 afrag[4];
  float dacc[NV == 0 ? 1 : NV];
  #pragma unroll
  for (int v = 0; v < NV; ++v) dacc[v] = 0.f;
  #pragma unroll
  for (int kk = 0; kk < 4; ++kk) {
    float4 lo = *(const float4*)&xr[kk * 32 + 4 * g];
    float4 hi = *(const float4*)&xr[kk * 32 + 16 + 4 * g];
    afrag[kk] = packfrag(lo, hi);
    #pragma unroll
    for (int v = 0; v < NV; ++v) {
      const float* vp = gd.dv[v];
      float4 vlo = *(const float4*)&vp[kk * 32 + 4 * g];
      float4 vhi = *(const float4*)&vp[kk * 32 + 16 + 4 * g];
      dacc[v] += lo.x * vlo.x + lo.y * vlo.y + lo.z * vlo.z + lo.w * vlo.w
               + hi.x * vhi.x + hi.y * vhi.y + hi.z * vhi.z + hi.w * vhi.w;
    }
  }
  #pragma unroll
  for (int v = 0; v < NV; ++v) {
    float dsum = dacc[v];
    dsum += __shfl_xor(dsum, 16);
    dsum += __shfl_xor(dsum, 32);
    if (lane < 16 && row < gd.n) gd.dq[v][row] = dsum;
  }
  f32x4 acc[8];
  #pragma unroll
  for (int t = 0; t < 8; ++t) acc[t] = (f32x4){0.f, 0.f, 0.f, 0.f};
  #pragma unroll
  for (int nt = 0; nt < 8; ++nt) {
    #pragma unroll
    for (int kk = 0; kk < 4; ++kk) {
      union { uint4 u; bf16x8 s; } bu;
      bu.u = *(const uint4*)&Wf[(size_t)((nt * 4 + kk) * 64 + lane) * 8];
      acc[nt] = __builtin_amdgcn_mfma_f32_16x16x32_bf16(afrag[kk], bu.s, acc[nt], 0, 0, 0);
    }
  }
  // D layout: col = lane&15, row = (lane>>4)*4 + r
  int orow = blk * 64 + wv * 16 + 4 * g;
  #pragma unroll
  for (int r = 0; r < 4; ++r) {
    int gr = orow + r;
    if (gr < gd.n) {
      #pragma unroll
      for (int nt = 0; nt < 8; ++nt)
        gd.Y[(size_t)gr * 128 + nt * 16 + x] = f2bf(acc[nt][r]);
    }
  }
}

__device__ void rdot_body(const float* __restrict__ x, const float* __restrict__ v,
                          float* __restrict__ o, int n, int blk, int nblk) {
  int lane = threadIdx.x & 63;
  int wid = (blk * 256 + threadIdx.x) >> 6;
  int nw = nblk * 4;
  float va = v[lane], vb = v[64 + lane];
  for (int r = wid; r < n; r += nw) {
    float a = x[r * 128 + lane] * va + x[r * 128 + 64 + lane] * vb;
    #pragma unroll
    for (int of = 32; of; of >>= 1) a += __shfl_xor(a, of);
    if (lane == 0) o[r] = a;
  }
}

__global__ __launch_bounds__(256, 2) void mid2_k(CsrGs G, int* cur, BigC C,
                                                 const ushort* W0, const ushort* W1,
                                                 const ushort* W2, const ushort* W3,
                                                 const ushort* W4) {
  __shared__ __align__(16) unsigned char smem[21504];
  int b = blockIdx.x;
  if (b < 600) {
    partition_body(G, cur, b / 120, b % 120, 120, smem);
    return;
  }
  b -= 600;
  if (b < C.gemm_blocks) {
    if (b < C.g[1].b0)      gemm_bodyT<6>(C.g[0], W0, b - C.g[0].b0);
    else if (b < C.g[2].b0) gemm_bodyT<4>(C.g[1], W1, b - C.g[1].b0);
    else if (b < C.g[3].b0) gemm_bodyT<0>(C.g[2], W2, b - C.g[2].b0);
    else if (b < C.g[4].b0) gemm_bodyT<1>(C.g[3], W3, b - C.g[3].b0);
    else                    gemm_bodyT<0>(C.g[4], W4, b - C.g[4].b0);
  } else {
    rdot_body(C.rx, C.rv, C.ro, STU_N, b - C.gemm_blocks, C.rnb);
  }
}

// ---------------- csr_build ----------------

__global__ __launch_bounds__(256) void csr_build(CsrGs G, const int* __restrict__ bases) {
  int bid = blockIdx.x;
  int gi = 0;
  for (int k = 1; k < 5; ++k) if (bid >= G.g[k].tb) gi = k;
  CsrG g = G.g[gi];
  int b = bid - g.tb;
  int base = bases[g.sb + b];
  int cnt = bases[g.sb + b + 1] - base;
  if (cnt > 16384) cnt = 16384;

  __shared__ unsigned lkeys[16384];
  __shared__ int lh[512], lex[512], lcu[512], wsum[4];
  int tid = threadIdx.x;
  lh[tid] = 0; lh[tid + 256] = 0;
  __syncthreads();
  for (int j = tid; j < cnt; j += 256) {
    unsigned k = g.keys[base + j];
    lkeys[j] = k;
    atomicAdd(&lh[k >> 16], 1);
  }
  __syncthreads();
  int a0 = lh[2 * tid], a1 = lh[2 * tid + 1];
  int pair = a0 + a1;
  int lane = tid & 63, wv = tid >> 6;
  int incl = pair;
  #pragma unroll
  for (int o = 1; o < 64; o <<= 1) {
    int y = __shfl_up(incl, o);
    if (lane >= o) incl += y;
  }
  if (lane == 63) wsum[wv] = incl;
  __syncthreads();
  if (tid == 0) {
    int s = 0;
    #pragma unroll
    for (int w = 0; w < 4; ++w) { int t = wsum[w]; wsum[w] = s; s += t; }
  }
  __syncthreads();
  int ep = wsum[wv] + incl - pair;
  lex[2 * tid] = ep;       lex[2 * tid + 1] = ep + a0;
  lcu[2 * tid] = ep;       lcu[2 * tid + 1] = ep + a0;
  __syncthreads();
  int dst0 = b << g.shift;
  int ndst = min(1 << g.shift, g.n - dst0);
  for (int dl = tid; dl < ndst; dl += 256) g.offs[dst0 + dl] = base + lex[dl];
  for (int j = tid; j < cnt; j += 256) {
    unsigned k = lkeys[j];
    int dl = k >> 16;
    int pos = atomicAdd(&lcu[dl], 1);
    g.srcs[base + pos] = (int)(k & 0xFFFFu);
  }
}

// ---------------- GAT cores ----------------

__device__ __forceinline__ void fma8(float acc[8], float wj, uint4 u) {
  acc[0] += wj * __uint_as_float(u.x << 16);
  acc[1] += wj * __uint_as_float(u.x & 0xFFFF0000u);
  acc[2] += wj * __uint_as_float(u.y << 16);
  acc[3] += wj * __uint_as_float(u.y & 0xFFFF0000u);
  acc[4] += wj * __uint_as_float(u.z << 16);
  acc[5] += wj * __uint_as_float(u.z & 0xFFFF0000u);
  acc[6] += wj * __uint_as_float(u.w << 16);
  acc[7] += wj * __uint_as_float(u.w & 0xFFFF0000u);
}

__device__ void gat_core_bf(const int* __restrict__ offs, const int* __restrict__ srcs,
                            const float* __restrict__ sl, const float* __restrict__ sr,
                            const uint* __restrict__ xl, int t, int lane, float acc[8]) {
  int sbeg = offs[t], send = offs[t + 1];
  float srt = sr[t];
  int i0l = sbeg + lane;
  bool act0 = i0l < send;
  int s0 = act0 ? srcs[i0l] : 0;
  float e0;
  {
    float e = sl[s0] + srt;
    e = e > 0.f ? e : 0.2f * e;
    e0 = act0 ? e : -1e30f;
  }
  float m = e0, se = act0 ? 1.f : 0.f;
  for (int i = i0l + 64; i < send; i += 64) {
    int s = srcs[i];
    float e = sl[s] + srt;
    e = e > 0.f ? e : 0.2f * e;
    float mn = fmaxf(m, e);
    se = se * __expf(m - mn) + __expf(e - mn);
    m = mn;
  }
  #pragma unroll
  for (int o = 32; o; o >>= 1) {
    float m2 = __shfl_xor(m, o), s2 = __shfl_xor(se, o);
    float mn = fmaxf(m, m2);
    se = se * __expf(m - mn) + s2 * __expf(m2 - mn);
    m = mn;
  }
  float inv = 1.f / (se + 1e-16f);

  int g = lane & 15;
  int q = lane >> 4;
  #pragma unroll
  for (int r = 0; r < 8; ++r) acc[r] = 0.f;

  for (int i0 = sbeg; i0 < send; i0 += 64) {
    int cnt = min(64, send - i0);
    int s; float wgt;
    if (i0 == sbeg) {
      s = s0;
      wgt = act0 ? __expf(e0 - m) * inv : 0.f;
    } else {
      s = 0; wgt = 0.f;
      if (lane < cnt) {
        s = srcs[i0 + lane];
        float e = sl[s] + srt;
        e = e > 0.f ? e : 0.2f * e;
        wgt = __expf(e - m) * inv;
      }
    }
    int kmax = (cnt + 3) >> 2;
    int k = 0;
    for (; k + 4 <= kmax; k += 4) {
      int e0i = 4 * k + q;
      int sj0 = __shfl(s, e0i);
      int sj1 = __shfl(s, e0i + 4);
      int sj2 = __shfl(s, e0i + 8);
      int sj3 = __shfl(s, e0i + 12);
      float wj0 = __shfl(wgt, e0i);
      float wj1 = __shfl(wgt, e0i + 4);
      float wj2 = __shfl(wgt, e0i + 8);
      float wj3 = __shfl(wgt, e0i + 12);
      uint4 u0 = *(const uint4*)&xl[(size_t)sj0 * 64 + g * 4];
      uint4 u1 = *(const uint4*)&xl[(size_t)sj1 * 64 + g * 4];
      uint4 u2 = *(const uint4*)&xl[(size_t)sj2 * 64 + g * 4];
      uint4 u3 = *(const uint4*)&xl[(size_t)sj3 * 64 + g * 4];
      fma8(acc, wj0, u0);
      fma8(acc, wj1, u1);
      fma8(acc, wj2, u2);
      fma8(acc, wj3, u3);
    }
    for (; k < kmax; ++k) {
      int ej = 4 * k + q;
      int sj = __shfl(s, ej);
      float wj = __shfl(wgt, ej);
      uint4 u = *(const uint4*)&xl[(size_t)sj * 64 + g * 4];
      fma8(acc, wj, u);
    }
  }
  #pragma unroll
  for (int r = 0; r < 8; ++r) {
    acc[r] += __shfl_xor(acc[r], 16);
    acc[r] += __shfl_xor(acc[r], 32);
  }
}

__device__ __forceinline__ void gat_store(const float acc[8], const float* base0,
                                          float* out, int t, int lane) {
  int g = lane & 15;
  if (lane < 16) {
    int d = t * 128 + g * 8;
    float4 a0 = make_float4(acc[0], acc[1], acc[2], acc[3]);
    float4 a1 = make_float4(acc[4], acc[5], acc[6], acc[7]);
    if (base0) {
      const float4 b0 = *(const float4*)&base0[d];
      const float4 b1 = *(const float4*)&base0[d + 4];
      a0.x += b0.x; a0.y += b0.y; a0.z += b0.z; a0.w += b0.w;
      a1.x += b1.x; a1.y += b1.y; a1.z += b1.z; a1.w += b1.w;
    }
    *(float4*)&out[d] = a0;
    *(float4*)&out[d + 4] = a1;
  }
}

__device__ void c1c2_body(const int* offs, const int* srcs, const float* sl,
                          const float* sr, const uint* xl, const float* al,
                          float* o, float* slo, int t, int lane) {
  float acc[8];
  gat_core_bf(offs, srcs, sl, sr, xl, t, lane, acc);
  int g = lane & 15;
  float4 v0 = *(const float4*)&al[g * 8];
  float4 v1 = *(const float4*)&al[g * 8 + 4];
  float p = acc[0] * v0.x + acc[1] * v0.y + acc[2] * v0.z + acc[3] * v0.w +
            acc[4] * v1.x + acc[5] * v1.y + acc[6] * v1.z + acc[7] * v1.w;
  #pragma unroll
  for (int o2 = 8; o2; o2 >>= 1) p += __shfl_xor(p, o2);
  if (lane == 0) slo[t] = p;
  if (lane < 16) {
    int d = t * 128 + g * 8;
    *(float4*)&o[d] = make_float4(acc[0], acc[1], acc[2], acc[3]);
    *(float4*)&o[d + 4] = make_float4(acc[4], acc[5], acc[6], acc[7]);
  }
}

__device__ void gat_dual_core(const int* __restrict__ offs, const int* __restrict__ srcs,
                              const float* __restrict__ sl1, const float* __restrict__ sr1,
                              const float* __restrict__ xl1,
                              const float* __restrict__ sl2, const float* __restrict__ sr2,
                              const float* __restrict__ xl2,
                              const float* __restrict__ base,
                              float* __restrict__ out, int t, int lane) {
  int sbeg = offs[t], send = offs[t + 1];
  float srt1 = sr1[t], srt2 = sr2[t];
  float m1 = -1e30f, m2 = -1e30f;
  for (int i = sbeg + lane; i < send; i += 64) {
    int s = srcs[i];
    float e1 = sl1[s] + srt1; e1 = e1 > 0.f ? e1 : 0.2f * e1;
    float e2 = sl2[s] + srt2; e2 = e2 > 0.f ? e2 : 0.2f * e2;
    m1 = fmaxf(m1, e1); m2 = fmaxf(m2, e2);
  }
  #pragma unroll
  for (int o = 32; o; o >>= 1) {
    m1 = fmaxf(m1, __shfl_xor(m1, o));
    m2 = fmaxf(m2, __shfl_xor(m2, o));
  }
  float se1 = 0.f, se2 = 0.f;
  for (int i = sbeg + lane; i < send; i += 64) {
    int s = srcs[i];
    float e1 = sl1[s] + srt1; e1 = e1 > 0.f ? e1 : 0.2f * e1;
    float e2 = sl2[s] + srt2; e2 = e2 > 0.f ? e2 : 0.2f * e2;
    se1 += __expf(e1 - m1); se2 += __expf(e2 - m2);
  }
  #pragma unroll
  for (int o = 32; o; o >>= 1) {
    se1 += __shfl_xor(se1, o);
    se2 += __shfl_xor(se2, o);
  }
  float inv1 = 1.f / (se1 + 1e-16f), inv2 = 1.f / (se2 + 1e-16f);
  float ax = 0.f, ay = 0.f;
  for (int i0 = sbeg; i0 < send; i0 += 64) {
    int cnt = min(64, send - i0);
    int s = 0; float w1 = 0.f, w2 = 0.f;
    if (lane < cnt) {
      s = srcs[i0 + lane];
      float e1 = sl1[s] + srt1; e1 = e1 > 0.f ? e1 : 0.2f * e1;
      float e2 = sl2[s] + srt2; e2 = e2 > 0.f ? e2 : 0.2f * e2;
      w1 = __expf(e1 - m1) * inv1;
      w2 = __expf(e2 - m2) * inv2;
    }
    for (int j = 0; j < cnt; ++j) {
      int sj = __shfl(s, j);
      float wj1 = __shfl(w1, j);
      float wj2 = __shfl(w2, j);
      const float2 v1 = *(const float2*)&xl1[sj * 128 + lane * 2];
      const float2 v2 = *(const float2*)&xl2[sj * 128 + lane * 2];
      ax += wj1 * v1.x + wj2 * v2.x;
      ay += wj1 * v1.y + wj2 * v2.y;
    }
  }
  const float2 b = *(const float2*)&base[t * 128 + lane * 2];
  float2 o2; o2.x = ax + b.x; o2.y = ay + b.y;
  *(float2*)&out[t * 128 + lane * 2] = o2;
}

// ---- gats_k: [s1 | i1+i2 merged | c1c2] all-parallel ----------------------

#define NB_S1  12500
#define NB_I12 5000

struct GatsArgs {
  const int *offs4, *srcs4; const float *sl_is, *sr_is; const uint* xl_is;
  const float* stu_raw_x; float* out_stu;
  const int *offs3, *srcs3; const float *sl_si, *sr_si; const uint* xl_si;
  const int *offs2, *srcs2; const float *sl_ci, *sr_ci; const uint* xl_ci;
  const float* item_x; float* out_item;
  const int *offs0, *srcs0; const float *sl_cc, *sr_cc; const uint* xl_cc;
  const float* al_cce; float *c1, *sl_cce;
  const int *offs1, *srcs1; const float *sl_ic, *sr_ic; const uint* xl_ic;
  const float* al_ice; float *c2, *sl_ice;
};

__global__ void gats_k(GatsArgs A) {
  int b = blockIdx.x;
  int lane = threadIdx.x & 63;
  if (b < NB_S1) {
    int t = (b * blockDim.x + threadIdx.x) >> 6;
    if (t >= STU_N) return;
    float acc[8];
    gat_core_bf(A.offs4, A.srcs4, A.sl_is, A.sr_is, A.xl_is, t, lane, acc);
    gat_store(acc, A.stu_raw_x, A.out_stu, t, lane);
  } else if (b < NB_S1 + NB_I12) {
    int t = ((b - NB_S1) * blockDim.x + threadIdx.x) >> 6;
    if (t >= ITEM_N) return;
    float acc1[8], acc2[8];
    gat_core_bf(A.offs2, A.srcs2, A.sl_ci, A.sr_ci, A.xl_ci, t, lane, acc1);
    gat_core_bf(A.offs3, A.srcs3, A.sl_si, A.sr_si, A.xl_si, t, lane, acc2);
    #pragma unroll
    for (int r = 0; r < 8; ++r) acc1[r] += acc2[r];
    gat_store(acc1, A.item_x, A.out_item, t, lane);
  } else {
    int sub = b - NB_S1 - NB_I12;   // 0..999
    int which = sub >= 500;
    int t = ((sub - which * 500) * blockDim.x + threadIdx.x) >> 6;
    if (t >= CONC_N) return;
    if (!which)
      c1c2_body(A.offs0, A.srcs0, A.sl_cc, A.sr_cc, A.xl_cc, A.al_cce, A.c1, A.sl_cce, t, lane);
    else
      c1c2_body(A.offs1, A.srcs1, A.sl_ic, A.sr_ic, A.xl_ic, A.al_ice, A.c2, A.sl_ice, t, lane);
  }
}

// ---- fin_k: dual(conc) only ----------------------------------------------

__global__ void fin_k(const int* offs0, const int* srcs0,
                      const float* sl_cce, const float* sr_cce, const float* c1,
                      const float* sl_ice, const float* sr_ice, const float* c2,
                      const float* conc_x, float* out_conc) {
  int t = (blockIdx.x * blockDim.x + threadIdx.x) >> 6;
  if (t >= CONC_N) return;
  gat_dual_core(offs0, srcs0, sl_cce, sr_cce, c1, sl_ice, sr_ice, c2,
                conc_x, out_conc, t, threadIdx.x & 63);
}

// ---------------- launch ----------------

extern "C" void kernel_launch(void* const* d_in, const int* in_sizes, int n_in,
                              void* d_out, int out_size, void* d_ws, size_t ws_size,
                              hipStream_t stream) {
  const float* stu_x     = (const float*)d_in[0];
  const float* item_x    = (const float*)d_in[1];
  const float* conc_x    = (const float*)d_in[2];
  const float* stu_raw_x = (const float*)d_in[3];
  const float* W_cc  = (const float*)d_in[4];
  const float* al_cc = (const float*)d_in[5];
  const float* ar_cc = (const float*)d_in[6];
  const float* W_ic  = (const float*)d_in[7];
  const float* al_ic = (const float*)d_in[8];
  const float* ar_ic = (const float*)d_in[9];
  const float* al_cce = (const float*)d_in[10];
  const float* ar_cce = (const float*)d_in[11];
  const float* al_ice = (const float*)d_in[12];
  const float* ar_ice = (const float*)d_in[13];
  const float* W_ci  = (const float*)d_in[14];
  const float* al_ci = (const float*)d_in[15];
  const float* ar_ci = (const float*)d_in[16];
  const float* W_si  = (const float*)d_in[17];
  const float* al_si = (const float*)d_in[18];
  const float* ar_si = (const float*)d_in[19];
  const float* W_is  = (const float*)d_in[22];
  const float* al_is = (const float*)d_in[23];
  const float* ar_is = (const float*)d_in[24];
  const int* cc_src  = (const int*)d_in[25];
  const int* cc_dst  = (const int*)d_in[26];
  const int* ic_item = (const int*)d_in[27];
  const int* ic_conc = (const int*)d_in[28];
  const int* si_stu  = (const int*)d_in[29];
  const int* si_item = (const int*)d_in[30];

  char* wsb = (char*)d_ws;
  size_t off = 0;
  auto alloc = [&](size_t bytes) -> void* {
    void* p = wsb + off;
    off = (off + bytes + 255) & ~(size_t)255;
    return p;
  };

  ushort* concWcc = (ushort*)alloc((size_t)CONC_N * 128 * 2);
  ushort* itemWic = (ushort*)alloc((size_t)ITEM_N * 128 * 2);
  ushort* concWci = (ushort*)alloc((size_t)CONC_N * 128 * 2);
  ushort* stuWsi  = (ushort*)alloc((size_t)STU_N  * 128 * 2);
  ushort* itemWis = (ushort*)alloc((size_t)ITEM_N * 128 * 2);
  ushort* Wbf[5];
  for (int i = 0; i < 5; ++i) Wbf[i] = (ushort*)alloc(128 * 128 * 2);
  float* c1buf   = (float*)alloc((size_t)CONC_N * 128 * 4);
  float* c2buf   = (float*)alloc((size_t)CONC_N * 128 * 4);
  float* vecs    = (float*)alloc(10 * 128 * 4);
  float* sl_cc  = (float*)alloc(CONC_N * 4);
  float* sr_cc  = (float*)alloc(CONC_N * 4);
  float* sl_ic  = (float*)alloc(ITEM_N * 4);
  float* sr_ic  = (float*)alloc(CONC_N * 4);
  float* sl_ci  = (float*)alloc(CONC_N * 4);
  float* sr_ci  = (float*)alloc(ITEM_N * 4);
  float* sl_si  = (float*)alloc(STU_N * 4);
  float* sr_si  = (float*)alloc(ITEM_N * 4);
  float* sl_is  = (float*)alloc(ITEM_N * 4);
  float* sr_is  = (float*)alloc(STU_N * 4);
  float* sl_cce = (float*)alloc(CONC_N * 4);
  float* sr_cce = (float*)alloc(CONC_N * 4);
  float* sl_ice = (float*)alloc(CONC_N * 4);
  float* sr_ice = (float*)alloc(CONC_N * 4);

  unsigned* keys0 = (unsigned*)alloc((size_t)NE_CC * 4);
  unsigned* keys1 = (unsigned*)alloc((size_t)NE_IC * 4);
  unsigned* keys2 = (unsigned*)alloc((size_t)NE_IC * 4);
  unsigned* keys3 = (unsigned*)alloc((size_t)NE_SI * 4);
  unsigned* keys4 = (unsigned*)alloc((size_t)NE_SI * 4);
  int* srcs0 = (int*)alloc((size_t)NE_CC * 4);
  int* srcs1 = (int*)alloc((size_t)NE_IC * 4);
  int* srcs2 = (int*)alloc((size_t)NE_IC * 4);
  int* srcs3 = (int*)alloc((size_t)NE_SI * 4);
  int* srcs4 = (int*)alloc((size_t)NE_SI * 4);
  int* offs0 = (int*)alloc((CONC_N + 1) * 4);
  int* offs1 = (int*)alloc((CONC_N + 1) * 4);
  int* offs2 = (int*)alloc((ITEM_N + 1) * 4);
  int* offs3 = (int*)alloc((ITEM_N + 1) * 4);
  int* offs4 = (int*)alloc((STU_N + 1) * 4);
  int* pcnt      = (int*)alloc(5 * 32 * 128 * 4);
  int* cur_all   = (int*)alloc(TBUCK * 4);
  int* bases_all = (int*)alloc((TBUCK + 5) * 4);

  float* out = (float*)d_out;
  float* out_conc = out;
  float* out_item = out + (size_t)CONC_N * 128;
  float* out_stu  = out + (size_t)(CONC_N + ITEM_N) * 128;

  CsrGs G;
  G.g[0] = {cc_dst,  cc_src,  keys0, srcs0, offs0, NE_CC, CONC_N, 5, 63,   0,   0};
  G.g[1] = {ic_conc, ic_item, keys1, srcs1, offs1, NE_IC, CONC_N, 5, 63,  63,  64};
  G.g[2] = {ic_item, ic_conc, keys2, srcs2, offs2, NE_IC, ITEM_N, 8, 79, 126, 128};
  G.g[3] = {si_item, si_stu,  keys3, srcs3, offs3, NE_SI, ITEM_N, 8, 79, 205, 208};
  G.g[4] = {si_stu,  si_item, keys4, srcs4, offs4, NE_SI, STU_N,  9, 98, 284, 288};

  // K1: setup (proj vectors + CSR histograms + W->frag-bf16)
  SetupArgs SA;
  SA.p[0] = {W_cc, al_cc, vecs + 0 * 128};
  SA.p[1] = {W_cc, ar_cc, vecs + 1 * 128};
  SA.p[2] = {W_ic, al_ic, vecs + 2 * 128};
  SA.p[3] = {W_ic, ar_ic, vecs + 3 * 128};
  SA.p[4] = {W_ci, al_ci, vecs + 4 * 128};
  SA.p[5] = {W_ci, ar_ci, vecs + 5 * 128};
  SA.p[6] = {W_si, al_si, vecs + 6 * 128};
  SA.p[7] = {W_si, ar_si, vecs + 7 * 128};
  SA.p[8] = {W_is, al_is, vecs + 8 * 128};
  SA.p[9] = {W_is, ar_is, vecs + 9 * 128};
  SA.G = G;
  SA.pcnt = pcnt;
  SA.wsrc[0] = W_cc; SA.wsrc[1] = W_ic; SA.wsrc[2] = W_ci;
  SA.wsrc[3] = W_si; SA.wsrc[4] = W_is;
  for (int i = 0; i < 5; ++i) SA.wdst[i] = Wbf[i];
  setup_k<<<175, 256, 0, stream>>>(SA);

  // K2: scan
  csr_scan<<<1, 512, 0, stream>>>(G, pcnt, cur_all, bases_all);

  // K3: partition (600) ∥ MFMA gemms (+fused dots) + rdot
  BigC C;
  C.g[0] = {conc_x, concWcc, CONC_N, 0,
            {vecs + 0 * 128, vecs + 1 * 128, vecs + 3 * 128, vecs + 4 * 128, ar_cce, ar_ice},
            {sl_cc, sr_cc, sr_ic, sl_ci, sr_cce, sr_ice}};
  C.g[1] = {item_x, itemWic, ITEM_N, 32,
            {vecs + 2 * 128, vecs + 5 * 128, vecs + 7 * 128, vecs + 8 * 128, nullptr, nullptr},
            {sl_ic, sr_ci, sr_si, sl_is, nullptr, nullptr}};
  C.g[2] = {conc_x, concWci, CONC_N, 345,
            {nullptr, nullptr, nullptr, nullptr, nullptr, nullptr},
            {nullptr, nullptr, nullptr, nullptr, nullptr, nullptr}};
  C.g[3] = {stu_x, stuWsi, STU_N, 377,
            {vecs + 6 * 128, nullptr, nullptr, nullptr, nullptr, nullptr},
            {sl_si, nullptr, nullptr, nullptr, nullptr, nullptr}};
  C.g[4] = {item_x, itemWis, ITEM_N, 1159,
            {nullptr, nullptr, nullptr, nullptr, nullptr, nullptr},
            {nullptr, nullptr, nullptr, nullptr, nullptr, nullptr}};
  C.gemm_blocks = 1472;
  C.rx = stu_raw_x; C.rv = vecs + 9 * 128; C.ro = sr_is; C.rnb = 1024;
  mid2_k<<<600 + 2496, 256, 0, stream>>>(G, cur_all, C, Wbf[0], Wbf[1], Wbf[2], Wbf[3], Wbf[4]);

  // K4: build
  csr_build<<<TBUCK, 256, 0, stream>>>(G, bases_all);

  // K5: all independent GATs in one launch (s1 | i1+i2 | c1c2)
  GatsArgs GA;
  GA.offs4 = offs4; GA.srcs4 = srcs4; GA.sl_is = sl_is; GA.sr_is = sr_is;
  GA.xl_is = (const uint*)itemWis; GA.stu_raw_x = stu_raw_x; GA.out_stu = out_stu;
  GA.offs3 = offs3; GA.srcs3 = srcs3; GA.sl_si = sl_si; GA.sr_si = sr_si;
  GA.xl_si = (const uint*)stuWsi;
  GA.offs2 = offs2; GA.srcs2 = srcs2; GA.sl_ci = sl_ci; GA.sr_ci = sr_ci;
  GA.xl_ci = (const uint*)concWci; GA.item_x = item_x; GA.out_item = out_item;
  GA.offs0 = offs0; GA.srcs0 = srcs0; GA.sl_cc = sl_cc; GA.sr_cc = sr_cc;
  GA.xl_cc = (const uint*)concWcc; GA.al_cce = al_cce; GA.c1 = c1buf; GA.sl_cce = sl_cce;
  GA.offs1 = offs1; GA.srcs1 = srcs1; GA.sl_ic = sl_ic; GA.sr_ic = sr_ic;
  GA.xl_ic = (const uint*)itemWic; GA.al_ice = al_ice; GA.c2 = c2buf; GA.sl_ice = sl_ice;
  gats_k<<<NB_S1 + NB_I12 + 1000, 256, 0, stream>>>(GA);

  // K6: dual (needs c1/c2 + their dots)
  fin_k<<<500, 256, 0, stream>>>(offs0, srcs0, sl_cce, sr_cce, c1buf,
                                 sl_ice, sr_ice, c2buf, conc_x, out_conc);
}

// Round 12
// 207.039 us; speedup vs baseline: 1.1580x; 1.0085x over previous
//
#include <hip/hip_runtime.h>

#define CONC_N 2000
#define ITEM_N 20000
#define STU_N  50000
#define NE_CC  40000
#define NE_IC  80000
#define NE_SI  1000000
#define TBUCK  382   // 63+63+79+79+98

typedef unsigned int uint;
typedef unsigned short ushort;
typedef __attribute__((ext_vector_type(8))) short bf16x8;
typedef __attribute__((ext_vector_type(4))) float f32x4;

__device__ __forceinline__ ushort f2bf(float f) {
  uint u = __float_as_uint(f);
  uint r = (u + 0x7FFFu + ((u >> 16) & 1u)) >> 16;
  return (ushort)r;
}

__device__ __forceinline__ bf16x8 packfrag(float4 lo, float4 hi) {
  union { bf16x8 s; uint u[4]; } p;
  p.u[0] = (uint)f2bf(lo.x) | ((uint)f2bf(lo.y) << 16);
  p.u[1] = (uint)f2bf(lo.z) | ((uint)f2bf(lo.w) << 16);
  p.u[2] = (uint)f2bf(hi.x) | ((uint)f2bf(hi.y) << 16);
  p.u[3] = (uint)f2bf(hi.z) | ((uint)f2bf(hi.w) << 16);
  return p.s;
}

// ---------------- CSR structures ----------------

struct CsrG {
  const int* dst; const int* src;
  unsigned* keys; int* srcs; int* offs;
  int E, n, shift, nbuck, tb, sb;
};
struct CsrGs { CsrG g[5]; };

// ------- setup: proj vectors (LDS-staged) + CSR histograms + W->frag-bf16 --

struct ProjDesc { const float* W; const float* a; float* out; };
struct SetupArgs {
  ProjDesc p[10];
  CsrGs G;
  int* pcnt;                 // [5*32][128]
  const float* wsrc[5];
  ushort* wdst[5];           // fragment-ordered bf16, 2048 recs x 16B
};

__global__ __launch_bounds__(256) void setup_k(SetupArgs A) {
  int b = blockIdx.x;
  int tid = threadIdx.x;
  if (b < 10) {              // proj: out = W^T a, LDS-staged coalesced
    __shared__ float Wl[128 * 132];
    __shared__ float a_s[128];
    ProjDesc d = A.p[b];
    #pragma unroll
    for (int i = 0; i < 16; ++i) {
      int s = tid + i * 256;
      int row = s >> 5, c4 = s & 31;
      float4 w = *(const float4*)&d.W[s * 4];
      float* dst = &Wl[row * 132 + c4 * 4];
      dst[0] = w.x; dst[1] = w.y; dst[2] = w.z; dst[3] = w.w;
    }
    if (tid < 128) a_s[tid] = d.a[tid];
    __syncthreads();
    if (tid < 128) {
      float acc = 0.f;
      #pragma unroll 4
      for (int j = 0; j < 128; ++j) acc += Wl[j * 132 + tid] * a_s[j];
      d.out[tid] = acc;
    }
    return;
  }
  if (b >= 170) {            // W fp32 -> fragment-ordered bf16
    int wi = b - 170;
    const float* Ws = A.wsrc[wi];
    ushort* Wd = A.wdst[wi];
    for (int rec = tid; rec < 2048; rec += 256) {
      int lane = rec & 63;
      int kk = (rec >> 6) & 3;
      int nt = rec >> 8;
      int x = lane & 15, g = lane >> 4;
      const float* src = &Ws[(nt * 16 + x) * 128 + kk * 32 + 4 * g];
      float4 lo = *(const float4*)src;
      float4 hi = *(const float4*)(src + 16);
      bf16x8 pk = packfrag(lo, hi);
      *(bf16x8*)&Wd[rec * 8] = pk;
    }
    return;
  }
  int bsel = b - 10;            // 0..159: histogram
  int gi = bsel >> 5, blk = bsel & 31;
  CsrG g = A.G.g[gi];
  __shared__ int lcnt[128];
  if (tid < 128) lcnt[tid] = 0;
  __syncthreads();
  int chunk = (g.E + 31) >> 5;
  int e0 = blk * chunk, e1 = min(g.E, e0 + chunk);
  for (int e = e0 + tid; e < e1; e += 256)
    atomicAdd(&lcnt[g.dst[e] >> g.shift], 1);
  __syncthreads();
  if (tid < 128) A.pcnt[bsel * 128 + tid] = lcnt[tid];
}

// ---------------- CSR scan ----------------

__global__ __launch_bounds__(512) void csr_scan(CsrGs G, const int* __restrict__ pcnt,
                                                int* __restrict__ cur, int* __restrict__ bases) {
  __shared__ int lc[TBUCK];
  __shared__ int lb[TBUCK + 5];
  int tid = threadIdx.x, lane = tid & 63, wv = tid >> 6;
  if (tid < TBUCK) {
    int gi = 0;
    #pragma unroll
    for (int k = 1; k < 5; ++k) if (tid >= G.g[k].tb) gi = k;
    int b = tid - G.g[gi].tb;
    int s = 0;
    for (int blk = 0; blk < 32; ++blk) s += pcnt[((gi << 5) + blk) * 128 + b];
    lc[tid] = s;
  }
  __syncthreads();
  if (wv < 5) {
    CsrG g = G.g[wv];
    int carry = 0;
    for (int base = 0; base < g.nbuck; base += 64) {
      int idx = base + lane;
      int v = (idx < g.nbuck) ? lc[g.tb + idx] : 0;
      int incl = v;
      #pragma unroll
      for (int o = 1; o < 64; o <<= 1) {
        int y = __shfl_up(incl, o);
        if (lane >= o) incl += y;
      }
      if (idx < g.nbuck) lb[g.sb + idx] = carry + incl - v;
      carry += __shfl(incl, 63);
    }
    if (lane == 0) lb[g.sb + g.nbuck] = carry;
  }
  __syncthreads();
  if (tid < TBUCK + 5) bases[tid] = lb[tid];
  if (tid < TBUCK) {
    int gi = 0;
    for (int k = 1; k < 5; ++k) if (tid >= G.g[k].tb) gi = k;
    cur[tid] = lb[tid + gi];
  }
  if (tid < 5) G.g[tid].offs[G.g[tid].n] = G.g[tid].E;
}

// ------------- mid2_k: csr_partition (600 blks) ∥ MFMA GEMMs + rdot -------

struct GemmDesc { const float* X; ushort* Y; int n, b0; const float* dv[6]; float* dq[6]; };
struct BigC {
  GemmDesc g[5];
  int gemm_blocks;
  const float* rx; const float* rv; float* ro; int rnb;
};

__device__ void partition_body(const CsrGs& G, int* __restrict__ cur, int gi, int bx,
                               int nbx, unsigned char* smem) {
  CsrG g = G.g[gi];
  unsigned* ck = (unsigned*)smem;                 // 16384 B
  unsigned char* cb = smem + 16384;               // 4096 B
  int* lcnt = (int*)(smem + 20480);               // 512 B
  int* lcur = (int*)(smem + 20992);               // 512 B
  int tid = threadIdx.x;
  unsigned dmask = (1u << g.shift) - 1;
  for (int c0 = bx * 4096; c0 < g.E; c0 += nbx * 4096) {
    if (tid < 128) lcnt[tid] = 0;
    __syncthreads();
    #pragma unroll
    for (int i = 0; i < 16; ++i) {
      int e = c0 + i * 256 + tid;
      if (e < g.E) {
        int d = g.dst[e], s = g.src[e];
        int b = d >> g.shift;
        ck[i * 256 + tid] = ((unsigned)(d & dmask) << 16) | (unsigned)s;
        cb[i * 256 + tid] = (unsigned char)b;
        atomicAdd(&lcnt[b], 1);
      } else cb[i * 256 + tid] = 255;
    }
    __syncthreads();
    if (tid < g.nbuck && lcnt[tid] > 0) lcur[tid] = atomicAdd(&cur[g.tb + tid], lcnt[tid]);
    __syncthreads();
    #pragma unroll
    for (int i = 0; i < 16; ++i) {
      int b = cb[i * 256 + tid];
      if (b != 255) {
        int pos = atomicAdd(&lcur[b], 1);
        g.keys[pos] = ck[i * 256 + tid];
      }
    }
    __syncthreads();
  }
}

template <int NV>
__device__ void gemm_bodyT(const GemmDesc& gd, const ushort* __restrict__ Wf, int blk) {
  int tid = threadIdx.x;
  int lane = tid & 63, wv = tid >> 6;
  int x = lane & 15, g = lane >> 4;
  int row = blk * 64 + wv * 16 + x;
  const float* xr = &gd.X[(size_t)(row < gd.n ? row : 0) * 128];
  bf16x8 afrag[4];
  float dacc[NV == 0 ? 1 : NV];
  #pragma unroll
  for (int v = 0; v < NV; ++v) dacc[v] = 0.f;
  #pragma unroll
  for (int kk = 0; kk < 4; ++kk) {
    float4 lo = *(const float4*)&xr[kk * 32 + 4 * g];
    float4 hi = *(const float4*)&xr[kk * 32 + 16 + 4 * g];
    afrag[kk] = packfrag(lo, hi);
    #pragma unroll
    for (int v = 0; v < NV; ++v) {
      const float* vp = gd.dv[v];
      float4 vlo = *(const float4*)&vp[kk * 32 + 4 * g];
      float4 vhi = *(const float4*)&vp[kk * 32 + 16 + 4 * g];
      dacc[v] += lo.x * vlo.x + lo.y * vlo.y + lo.z * vlo.z + lo.w * vlo.w
               + hi.x * vhi.x + hi.y * vhi.y + hi.z * vhi.z + hi.w * vhi.w;
    }
  }
  #pragma unroll
  for (int v = 0; v < NV; ++v) {
    float dsum = dacc[v];
    dsum += __shfl_xor(dsum, 16);
    dsum += __shfl_xor(dsum, 32);
    if (lane < 16 && row < gd.n) gd.dq[v][row] = dsum;
  }
  f32x4 acc[8];
  #pragma unroll
  for (int t = 0; t < 8; ++t) acc[t] = (f32x4){0.f, 0.f, 0.f, 0.f};
  #pragma unroll
  for (int nt = 0; nt < 8; ++nt) {
    #pragma unroll
    for (int kk = 0; kk < 4; ++kk) {
      union { uint4 u; bf16x8 s; } bu;
      bu.u = *(const uint4*)&Wf[(size_t)((nt * 4 + kk) * 64 + lane) * 8];
      acc[nt] = __builtin_amdgcn_mfma_f32_16x16x32_bf16(afrag[kk], bu.s, acc[nt], 0, 0, 0);
    }
  }
  // D layout: col = lane&15, row = (lane>>4)*4 + r
  int orow = blk * 64 + wv * 16 + 4 * g;
  #pragma unroll
  for (int r = 0; r < 4; ++r) {
    int gr = orow + r;
    if (gr < gd.n) {
      #pragma unroll
      for (int nt = 0; nt < 8; ++nt)
        gd.Y[(size_t)gr * 128 + nt * 16 + x] = f2bf(acc[nt][r]);
    }
  }
}

__device__ void rdot_body(const float* __restrict__ x, const float* __restrict__ v,
                          float* __restrict__ o, int n, int blk, int nblk) {
  int lane = threadIdx.x & 63;
  int wid = (blk * 256 + threadIdx.x) >> 6;
  int nw = nblk * 4;
  float va = v[lane], vb = v[64 + lane];
  for (int r = wid; r < n; r += nw) {
    float a = x[r * 128 + lane] * va + x[r * 128 + 64 + lane] * vb;
    #pragma unroll
    for (int of = 32; of; of >>= 1) a += __shfl_xor(a, of);
    if (lane == 0) o[r] = a;
  }
}

__global__ __launch_bounds__(256, 2) void mid2_k(CsrGs G, int* cur, BigC C,
                                                 const ushort* W0, const ushort* W1,
                                                 const ushort* W2, const ushort* W3,
                                                 const ushort* W4) {
  __shared__ __align__(16) unsigned char smem[21504];
  int b = blockIdx.x;
  if (b < 600) {
    partition_body(G, cur, b / 120, b % 120, 120, smem);
    return;
  }
  b -= 600;
  if (b < C.gemm_blocks) {
    if (b < C.g[1].b0)      gemm_bodyT<6>(C.g[0], W0, b - C.g[0].b0);
    else if (b < C.g[2].b0) gemm_bodyT<4>(C.g[1], W1, b - C.g[1].b0);
    else if (b < C.g[3].b0) gemm_bodyT<0>(C.g[2], W2, b - C.g[2].b0);
    else if (b < C.g[4].b0) gemm_bodyT<1>(C.g[3], W3, b - C.g[3].b0);
    else                    gemm_bodyT<0>(C.g[4], W4, b - C.g[4].b0);
  } else {
    rdot_body(C.rx, C.rv, C.ro, STU_N, b - C.gemm_blocks, C.rnb);
  }
}

// ---------------- csr_build ----------------

__global__ __launch_bounds__(256) void csr_build(CsrGs G, const int* __restrict__ bases) {
  int bid = blockIdx.x;
  int gi = 0;
  for (int k = 1; k < 5; ++k) if (bid >= G.g[k].tb) gi = k;
  CsrG g = G.g[gi];
  int b = bid - g.tb;
  int base = bases[g.sb + b];
  int cnt = bases[g.sb + b + 1] - base;
  if (cnt > 16384) cnt = 16384;

  __shared__ unsigned lkeys[16384];
  __shared__ int lh[512], lex[512], lcu[512], wsum[4];
  int tid = threadIdx.x;
  lh[tid] = 0; lh[tid + 256] = 0;
  __syncthreads();
  for (int j = tid; j < cnt; j += 256) {
    unsigned k = g.keys[base + j];
    lkeys[j] = k;
    atomicAdd(&lh[k >> 16], 1);
  }
  __syncthreads();
  int a0 = lh[2 * tid], a1 = lh[2 * tid + 1];
  int pair = a0 + a1;
  int lane = tid & 63, wv = tid >> 6;
  int incl = pair;
  #pragma unroll
  for (int o = 1; o < 64; o <<= 1) {
    int y = __shfl_up(incl, o);
    if (lane >= o) incl += y;
  }
  if (lane == 63) wsum[wv] = incl;
  __syncthreads();
  if (tid == 0) {
    int s = 0;
    #pragma unroll
    for (int w = 0; w < 4; ++w) { int t = wsum[w]; wsum[w] = s; s += t; }
  }
  __syncthreads();
  int ep = wsum[wv] + incl - pair;
  lex[2 * tid] = ep;       lex[2 * tid + 1] = ep + a0;
  lcu[2 * tid] = ep;       lcu[2 * tid + 1] = ep + a0;
  __syncthreads();
  int dst0 = b << g.shift;
  int ndst = min(1 << g.shift, g.n - dst0);
  for (int dl = tid; dl < ndst; dl += 256) g.offs[dst0 + dl] = base + lex[dl];
  for (int j = tid; j < cnt; j += 256) {
    unsigned k = lkeys[j];
    int dl = k >> 16;
    int pos = atomicAdd(&lcu[dl], 1);
    g.srcs[base + pos] = (int)(k & 0xFFFFu);
  }
}

// ---------------- GAT core: 16-lane group per target ----------------------

__device__ __forceinline__ void fma8(float acc[8], float wj, uint4 u) {
  acc[0] += wj * __uint_as_float(u.x << 16);
  acc[1] += wj * __uint_as_float(u.x & 0xFFFF0000u);
  acc[2] += wj * __uint_as_float(u.y << 16);
  acc[3] += wj * __uint_as_float(u.y & 0xFFFF0000u);
  acc[4] += wj * __uint_as_float(u.z << 16);
  acc[5] += wj * __uint_as_float(u.z & 0xFFFF0000u);
  acc[6] += wj * __uint_as_float(u.w << 16);
  acc[7] += wj * __uint_as_float(u.w & 0xFFFF0000u);
}

// t = t4 + (lane>>4); lane il = lane&15 owns dims il*8..il*8+7.
__device__ void gat_core16(const int* __restrict__ offs, const int* __restrict__ srcs,
                           const float* __restrict__ sl, const float* __restrict__ sr,
                           const uint* __restrict__ xl, int t4, int n_tgt, int lane,
                           float acc[8]) {
  int q = lane >> 4, il = lane & 15;
  int t = t4 + q;
  bool tv = t < n_tgt;
  int sbeg = tv ? offs[t] : 0;
  int send = tv ? offs[t + 1] : 0;
  float srt = tv ? sr[t] : 0.f;

  // first chunk cached (16 edges)
  int i0l = sbeg + il;
  bool act0 = i0l < send;
  int s0 = act0 ? srcs[i0l] : 0;
  float e0;
  {
    float e = sl[s0] + srt;
    e = e > 0.f ? e : 0.2f * e;
    e0 = act0 ? e : -1e30f;
  }
  float m = e0, se = act0 ? 1.f : 0.f;
  for (int i = i0l + 16; i < send; i += 16) {
    int s = srcs[i];
    float e = sl[s] + srt;
    e = e > 0.f ? e : 0.2f * e;
    float mn = fmaxf(m, e);
    se = se * __expf(m - mn) + __expf(e - mn);
    m = mn;
  }
  #pragma unroll
  for (int o = 8; o; o >>= 1) {
    float m2 = __shfl_xor(m, o), s2 = __shfl_xor(se, o);
    float mn = fmaxf(m, m2);
    se = se * __expf(m - mn) + s2 * __expf(m2 - mn);
    m = mn;
  }
  float inv = 1.f / (se + 1e-16f);

  #pragma unroll
  for (int r = 0; r < 8; ++r) acc[r] = 0.f;

  int qb = q << 4;
  for (int i0 = sbeg; i0 < send; i0 += 16) {
    int cnt = min(16, send - i0);
    int s; float wgt;
    if (i0 == sbeg) {
      s = s0;
      wgt = act0 ? __expf(e0 - m) * inv : 0.f;
    } else {
      s = 0; wgt = 0.f;
      if (il < cnt) {
        s = srcs[i0 + il];
        float e = sl[s] + srt;
        e = e > 0.f ? e : 0.2f * e;
        wgt = __expf(e - m) * inv;
      }
    }
    #pragma unroll 2
    for (int j = 0; j < cnt; ++j) {
      int sj = __shfl(s, qb + j);
      float wj = __shfl(wgt, qb + j);
      uint4 u = *(const uint4*)&xl[(size_t)sj * 64 + il * 4];
      fma8(acc, wj, u);
    }
  }
}

__device__ __forceinline__ void gat_store16(const float acc[8], const float* base0,
                                            float* out, int t4, int n_tgt, int lane) {
  int q = lane >> 4, il = lane & 15;
  int t = t4 + q;
  if (t >= n_tgt) return;
  int d = t * 128 + il * 8;
  float4 a0 = make_float4(acc[0], acc[1], acc[2], acc[3]);
  float4 a1 = make_float4(acc[4], acc[5], acc[6], acc[7]);
  if (base0) {
    const float4 b0 = *(const float4*)&base0[d];
    const float4 b1 = *(const float4*)&base0[d + 4];
    a0.x += b0.x; a0.y += b0.y; a0.z += b0.z; a0.w += b0.w;
    a1.x += b1.x; a1.y += b1.y; a1.z += b1.z; a1.w += b1.w;
  }
  *(float4*)&out[d] = a0;
  *(float4*)&out[d + 4] = a1;
}

__device__ void c1c2_body16(const int* offs, const int* srcs, const float* sl,
                            const float* sr, const uint* xl, const float* al,
                            float* o, float* slo, int t4, int n_tgt, int lane) {
  float acc[8];
  gat_core16(offs, srcs, sl, sr, xl, t4, n_tgt, lane, acc);
  int q = lane >> 4, il = lane & 15;
  int t = t4 + q;
  float4 v0 = *(const float4*)&al[il * 8];
  float4 v1 = *(const float4*)&al[il * 8 + 4];
  float p = acc[0] * v0.x + acc[1] * v0.y + acc[2] * v0.z + acc[3] * v0.w +
            acc[4] * v1.x + acc[5] * v1.y + acc[6] * v1.z + acc[7] * v1.w;
  #pragma unroll
  for (int o2 = 8; o2; o2 >>= 1) p += __shfl_xor(p, o2);
  if (t < n_tgt) {
    if (il == 0) slo[t] = p;
    int d = t * 128 + il * 8;
    *(float4*)&o[d] = make_float4(acc[0], acc[1], acc[2], acc[3]);
    *(float4*)&o[d + 4] = make_float4(acc[4], acc[5], acc[6], acc[7]);
  }
}

// dual (fp32 gather of c1/c2 on cc graph), wave per target (small)
__device__ void gat_dual_core(const int* __restrict__ offs, const int* __restrict__ srcs,
                              const float* __restrict__ sl1, const float* __restrict__ sr1,
                              const float* __restrict__ xl1,
                              const float* __restrict__ sl2, const float* __restrict__ sr2,
                              const float* __restrict__ xl2,
                              const float* __restrict__ base,
                              float* __restrict__ out, int t, int lane) {
  int sbeg = offs[t], send = offs[t + 1];
  float srt1 = sr1[t], srt2 = sr2[t];
  float m1 = -1e30f, m2 = -1e30f;
  for (int i = sbeg + lane; i < send; i += 64) {
    int s = srcs[i];
    float e1 = sl1[s] + srt1; e1 = e1 > 0.f ? e1 : 0.2f * e1;
    float e2 = sl2[s] + srt2; e2 = e2 > 0.f ? e2 : 0.2f * e2;
    m1 = fmaxf(m1, e1); m2 = fmaxf(m2, e2);
  }
  #pragma unroll
  for (int o = 32; o; o >>= 1) {
    m1 = fmaxf(m1, __shfl_xor(m1, o));
    m2 = fmaxf(m2, __shfl_xor(m2, o));
  }
  float se1 = 0.f, se2 = 0.f;
  for (int i = sbeg + lane; i < send; i += 64) {
    int s = srcs[i];
    float e1 = sl1[s] + srt1; e1 = e1 > 0.f ? e1 : 0.2f * e1;
    float e2 = sl2[s] + srt2; e2 = e2 > 0.f ? e2 : 0.2f * e2;
    se1 += __expf(e1 - m1); se2 += __expf(e2 - m2);
  }
  #pragma unroll
  for (int o = 32; o; o >>= 1) {
    se1 += __shfl_xor(se1, o);
    se2 += __shfl_xor(se2, o);
  }
  float inv1 = 1.f / (se1 + 1e-16f), inv2 = 1.f / (se2 + 1e-16f);
  float ax = 0.f, ay = 0.f;
  for (int i0 = sbeg; i0 < send; i0 += 64) {
    int cnt = min(64, send - i0);
    int s = 0; float w1 = 0.f, w2 = 0.f;
    if (lane < cnt) {
      s = srcs[i0 + lane];
      float e1 = sl1[s] + srt1; e1 = e1 > 0.f ? e1 : 0.2f * e1;
      float e2 = sl2[s] + srt2; e2 = e2 > 0.f ? e2 : 0.2f * e2;
      w1 = __expf(e1 - m1) * inv1;
      w2 = __expf(e2 - m2) * inv2;
    }
    for (int j = 0; j < cnt; ++j) {
      int sj = __shfl(s, j);
      float wj1 = __shfl(w1, j);
      float wj2 = __shfl(w2, j);
      const float2 v1 = *(const float2*)&xl1[sj * 128 + lane * 2];
      const float2 v2 = *(const float2*)&xl2[sj * 128 + lane * 2];
      ax += wj1 * v1.x + wj2 * v2.x;
      ay += wj1 * v1.y + wj2 * v2.y;
    }
  }
  const float2 b = *(const float2*)&base[t * 128 + lane * 2];
  float2 o2; o2.x = ax + b.x; o2.y = ay + b.y;
  *(float2*)&out[t * 128 + lane * 2] = o2;
}

// ---- gats_k: [s1 | i1+i2 merged | c1c2], 16 targets per block -------------

#define NB_S1  3125   // ceil(50000/16)
#define NB_I12 1250   // ceil(20000/16)
#define NB_CC  125    // ceil(2000/16)

struct GatsArgs {
  const int *offs4, *srcs4; const float *sl_is, *sr_is; const uint* xl_is;
  const float* stu_raw_x; float* out_stu;
  const int *offs3, *srcs3; const float *sl_si, *sr_si; const uint* xl_si;
  const int *offs2, *srcs2; const float *sl_ci, *sr_ci; const uint* xl_ci;
  const float* item_x; float* out_item;
  const int *offs0, *srcs0; const float *sl_cc, *sr_cc; const uint* xl_cc;
  const float* al_cce; float *c1, *sl_cce;
  const int *offs1, *srcs1; const float *sl_ic, *sr_ic; const uint* xl_ic;
  const float* al_ice; float *c2, *sl_ice;
};

__global__ void gats_k(GatsArgs A) {
  int b = blockIdx.x;
  int lane = threadIdx.x & 63;
  int wv = threadIdx.x >> 6;
  if (b < NB_S1) {
    int t4 = b * 16 + wv * 4;
    float acc[8];
    gat_core16(A.offs4, A.srcs4, A.sl_is, A.sr_is, A.xl_is, t4, STU_N, lane, acc);
    gat_store16(acc, A.stu_raw_x, A.out_stu, t4, STU_N, lane);
  } else if (b < NB_S1 + NB_I12) {
    int t4 = (b - NB_S1) * 16 + wv * 4;
    float acc1[8], acc2[8];
    gat_core16(A.offs2, A.srcs2, A.sl_ci, A.sr_ci, A.xl_ci, t4, ITEM_N, lane, acc1);
    gat_core16(A.offs3, A.srcs3, A.sl_si, A.sr_si, A.xl_si, t4, ITEM_N, lane, acc2);
    #pragma unroll
    for (int r = 0; r < 8; ++r) acc1[r] += acc2[r];
    gat_store16(acc1, A.item_x, A.out_item, t4, ITEM_N, lane);
  } else {
    int sub = b - NB_S1 - NB_I12;   // 0..2*NB_CC-1
    int which = sub >= NB_CC;
    int t4 = (sub - which * NB_CC) * 16 + wv * 4;
    if (!which)
      c1c2_body16(A.offs0, A.srcs0, A.sl_cc, A.sr_cc, A.xl_cc, A.al_cce,
                  A.c1, A.sl_cce, t4, CONC_N, lane);
    else
      c1c2_body16(A.offs1, A.srcs1, A.sl_ic, A.sr_ic, A.xl_ic, A.al_ice,
                  A.c2, A.sl_ice, t4, CONC_N, lane);
  }
}

// ---- fin_k: dual(conc) only ----------------------------------------------

__global__ void fin_k(const int* offs0, const int* srcs0,
                      const float* sl_cce, const float* sr_cce, const float* c1,
                      const float* sl_ice, const float* sr_ice, const float* c2,
                      const float* conc_x, float* out_conc) {
  int t = (blockIdx.x * blockDim.x + threadIdx.x) >> 6;
  if (t >= CONC_N) return;
  gat_dual_core(offs0, srcs0, sl_cce, sr_cce, c1, sl_ice, sr_ice, c2,
                conc_x, out_conc, t, threadIdx.x & 63);
}

// ---------------- launch ----------------

extern "C" void kernel_launch(void* const* d_in, const int* in_sizes, int n_in,
                              void* d_out, int out_size, void* d_ws, size_t ws_size,
                              hipStream_t stream) {
  const float* stu_x     = (const float*)d_in[0];
  const float* item_x    = (const float*)d_in[1];
  const float* conc_x    = (const float*)d_in[2];
  const float* stu_raw_x = (const float*)d_in[3];
  const float* W_cc  = (const float*)d_in[4];
  const float* al_cc = (const float*)d_in[5];
  const float* ar_cc = (const float*)d_in[6];
  const float* W_ic  = (const float*)d_in[7];
  const float* al_ic = (const float*)d_in[8];
  const float* ar_ic = (const float*)d_in[9];
  const float* al_cce = (const float*)d_in[10];
  const float* ar_cce = (const float*)d_in[11];
  const float* al_ice = (const float*)d_in[12];
  const float* ar_ice = (const float*)d_in[13];
  const float* W_ci  = (const float*)d_in[14];
  const float* al_ci = (const float*)d_in[15];
  const float* ar_ci = (const float*)d_in[16];
  const float* W_si  = (const float*)d_in[17];
  const float* al_si = (const float*)d_in[18];
  const float* ar_si = (const float*)d_in[19];
  const float* W_is  = (const float*)d_in[22];
  const float* al_is = (const float*)d_in[23];
  const float* ar_is = (const float*)d_in[24];
  const int* cc_src  = (const int*)d_in[25];
  const int* cc_dst  = (const int*)d_in[26];
  const int* ic_item = (const int*)d_in[27];
  const int* ic_conc = (const int*)d_in[28];
  const int* si_stu  = (const int*)d_in[29];
  const int* si_item = (const int*)d_in[30];

  char* wsb = (char*)d_ws;
  size_t off = 0;
  auto alloc = [&](size_t bytes) -> void* {
    void* p = wsb + off;
    off = (off + bytes + 255) & ~(size_t)255;
    return p;
  };

  ushort* concWcc = (ushort*)alloc((size_t)CONC_N * 128 * 2);
  ushort* itemWic = (ushort*)alloc((size_t)ITEM_N * 128 * 2);
  ushort* concWci = (ushort*)alloc((size_t)CONC_N * 128 * 2);
  ushort* stuWsi  = (ushort*)alloc((size_t)STU_N  * 128 * 2);
  ushort* itemWis = (ushort*)alloc((size_t)ITEM_N * 128 * 2);
  ushort* Wbf[5];
  for (int i = 0; i < 5; ++i) Wbf[i] = (ushort*)alloc(128 * 128 * 2);
  float* c1buf   = (float*)alloc((size_t)CONC_N * 128 * 4);
  float* c2buf   = (float*)alloc((size_t)CONC_N * 128 * 4);
  float* vecs    = (float*)alloc(10 * 128 * 4);
  float* sl_cc  = (float*)alloc(CONC_N * 4);
  float* sr_cc  = (float*)alloc(CONC_N * 4);
  float* sl_ic  = (float*)alloc(ITEM_N * 4);
  float* sr_ic  = (float*)alloc(CONC_N * 4);
  float* sl_ci  = (float*)alloc(CONC_N * 4);
  float* sr_ci  = (float*)alloc(ITEM_N * 4);
  float* sl_si  = (float*)alloc(STU_N * 4);
  float* sr_si  = (float*)alloc(ITEM_N * 4);
  float* sl_is  = (float*)alloc(ITEM_N * 4);
  float* sr_is  = (float*)alloc(STU_N * 4);
  float* sl_cce = (float*)alloc(CONC_N * 4);
  float* sr_cce = (float*)alloc(CONC_N * 4);
  float* sl_ice = (float*)alloc(CONC_N * 4);
  float* sr_ice = (float*)alloc(CONC_N * 4);

  unsigned* keys0 = (unsigned*)alloc((size_t)NE_CC * 4);
  unsigned* keys1 = (unsigned*)alloc((size_t)NE_IC * 4);
  unsigned* keys2 = (unsigned*)alloc((size_t)NE_IC * 4);
  unsigned* keys3 = (unsigned*)alloc((size_t)NE_SI * 4);
  unsigned* keys4 = (unsigned*)alloc((size_t)NE_SI * 4);
  int* srcs0 = (int*)alloc((size_t)NE_CC * 4);
  int* srcs1 = (int*)alloc((size_t)NE_IC * 4);
  int* srcs2 = (int*)alloc((size_t)NE_IC * 4);
  int* srcs3 = (int*)alloc((size_t)NE_SI * 4);
  int* srcs4 = (int*)alloc((size_t)NE_SI * 4);
  int* offs0 = (int*)alloc((CONC_N + 1) * 4);
  int* offs1 = (int*)alloc((CONC_N + 1) * 4);
  int* offs2 = (int*)alloc((ITEM_N + 1) * 4);
  int* offs3 = (int*)alloc((ITEM_N + 1) * 4);
  int* offs4 = (int*)alloc((STU_N + 1) * 4);
  int* pcnt      = (int*)alloc(5 * 32 * 128 * 4);
  int* cur_all   = (int*)alloc(TBUCK * 4);
  int* bases_all = (int*)alloc((TBUCK + 5) * 4);

  float* out = (float*)d_out;
  float* out_conc = out;
  float* out_item = out + (size_t)CONC_N * 128;
  float* out_stu  = out + (size_t)(CONC_N + ITEM_N) * 128;

  CsrGs G;
  G.g[0] = {cc_dst,  cc_src,  keys0, srcs0, offs0, NE_CC, CONC_N, 5, 63,   0,   0};
  G.g[1] = {ic_conc, ic_item, keys1, srcs1, offs1, NE_IC, CONC_N, 5, 63,  63,  64};
  G.g[2] = {ic_item, ic_conc, keys2, srcs2, offs2, NE_IC, ITEM_N, 8, 79, 126, 128};
  G.g[3] = {si_item, si_stu,  keys3, srcs3, offs3, NE_SI, ITEM_N, 8, 79, 205, 208};
  G.g[4] = {si_stu,  si_item, keys4, srcs4, offs4, NE_SI, STU_N,  9, 98, 284, 288};

  // K1: setup (proj vectors + CSR histograms + W->frag-bf16)
  SetupArgs SA;
  SA.p[0] = {W_cc, al_cc, vecs + 0 * 128};
  SA.p[1] = {W_cc, ar_cc, vecs + 1 * 128};
  SA.p[2] = {W_ic, al_ic, vecs + 2 * 128};
  SA.p[3] = {W_ic, ar_ic, vecs + 3 * 128};
  SA.p[4] = {W_ci, al_ci, vecs + 4 * 128};
  SA.p[5] = {W_ci, ar_ci, vecs + 5 * 128};
  SA.p[6] = {W_si, al_si, vecs + 6 * 128};
  SA.p[7] = {W_si, ar_si, vecs + 7 * 128};
  SA.p[8] = {W_is, al_is, vecs + 8 * 128};
  SA.p[9] = {W_is, ar_is, vecs + 9 * 128};
  SA.G = G;
  SA.pcnt = pcnt;
  SA.wsrc[0] = W_cc; SA.wsrc[1] = W_ic; SA.wsrc[2] = W_ci;
  SA.wsrc[3] = W_si; SA.wsrc[4] = W_is;
  for (int i = 0; i < 5; ++i) SA.wdst[i] = Wbf[i];
  setup_k<<<175, 256, 0, stream>>>(SA);

  // K2: scan
  csr_scan<<<1, 512, 0, stream>>>(G, pcnt, cur_all, bases_all);

  // K3: partition (600) ∥ MFMA gemms (+fused dots) + rdot
  BigC C;
  C.g[0] = {conc_x, concWcc, CONC_N, 0,
            {vecs + 0 * 128, vecs + 1 * 128, vecs + 3 * 128, vecs + 4 * 128, ar_cce, ar_ice},
            {sl_cc, sr_cc, sr_ic, sl_ci, sr_cce, sr_ice}};
  C.g[1] = {item_x, itemWic, ITEM_N, 32,
            {vecs + 2 * 128, vecs + 5 * 128, vecs + 7 * 128, vecs + 8 * 128, nullptr, nullptr},
            {sl_ic, sr_ci, sr_si, sl_is, nullptr, nullptr}};
  C.g[2] = {conc_x, concWci, CONC_N, 345,
            {nullptr, nullptr, nullptr, nullptr, nullptr, nullptr},
            {nullptr, nullptr, nullptr, nullptr, nullptr, nullptr}};
  C.g[3] = {stu_x, stuWsi, STU_N, 377,
            {vecs + 6 * 128, nullptr, nullptr, nullptr, nullptr, nullptr},
            {sl_si, nullptr, nullptr, nullptr, nullptr, nullptr}};
  C.g[4] = {item_x, itemWis, ITEM_N, 1159,
            {nullptr, nullptr, nullptr, nullptr, nullptr, nullptr},
            {nullptr, nullptr, nullptr, nullptr, nullptr, nullptr}};
  C.gemm_blocks = 1472;
  C.rx = stu_raw_x; C.rv = vecs + 9 * 128; C.ro = sr_is; C.rnb = 1024;
  mid2_k<<<600 + 2496, 256, 0, stream>>>(G, cur_all, C, Wbf[0], Wbf[1], Wbf[2], Wbf[3], Wbf[4]);

  // K4: build
  csr_build<<<TBUCK, 256, 0, stream>>>(G, bases_all);

  // K5: all independent GATs in one launch (s1 | i1+i2 | c1c2), 16 tgt/block
  GatsArgs GA;
  GA.offs4 = offs4; GA.srcs4 = srcs4; GA.sl_is = sl_is; GA.sr_is = sr_is;
  GA.xl_is = (const uint*)itemWis; GA.stu_raw_x = stu_raw_x; GA.out_stu = out_stu;
  GA.offs3 = offs3; GA.srcs3 = srcs3; GA.sl_si = sl_si; GA.sr_si = sr_si;
  GA.xl_si = (const uint*)stuWsi;
  GA.offs2 = offs2; GA.srcs2 = srcs2; GA.sl_ci = sl_ci; GA.sr_ci = sr_ci;
  GA.xl_ci = (const uint*)concWci; GA.item_x = item_x; GA.out_item = out_item;
  GA.offs0 = offs0; GA.srcs0 = srcs0; GA.sl_cc = sl_cc; GA.sr_cc = sr_cc;
  GA.xl_cc = (const uint*)concWcc; GA.al_cce = al_cce; GA.c1 = c1buf; GA.sl_cce = sl_cce;
  GA.offs1 = offs1; GA.srcs1 = srcs1; GA.sl_ic = sl_ic; GA.sr_ic = sr_ic;
  GA.xl_ic = (const uint*)itemWic; GA.al_ice = al_ice; GA.c2 = c2buf; GA.sl_ice = sl_ice;
  gats_k<<<NB_S1 + NB_I12 + 2 * NB_CC, 256, 0, stream>>>(GA);

  // K6: dual (needs c1/c2 + their dots)
  fin_k<<<500, 256, 0, stream>>>(offs0, srcs0, sl_cce, sr_cce, c1buf,
                                 sl_ice, sr_ice, c2buf, conc_x, out_conc);
}

// Round 13
// 204.712 us; speedup vs baseline: 1.1712x; 1.0114x over previous
//
#include <hip/hip_runtime.h>

#define CONC_N 2000
#define ITEM_N 20000
#define STU_N  50000
#define NE_CC  40000
#define NE_IC  80000
#define NE_SI  1000000
#define TBUCK  382   // 63+63+79+79+98

typedef unsigned int uint;
typedef unsigned short ushort;
typedef signed char s8;
typedef __attribute__((ext_vector_type(8))) short bf16x8;
typedef __attribute__((ext_vector_type(4))) float f32x4;

__device__ __forceinline__ ushort f2bf(float f) {
  uint u = __float_as_uint(f);
  uint r = (u + 0x7FFFu + ((u >> 16) & 1u)) >> 16;
  return (ushort)r;
}

__device__ __forceinline__ bf16x8 packfrag(float4 lo, float4 hi) {
  union { bf16x8 s; uint u[4]; } p;
  p.u[0] = (uint)f2bf(lo.x) | ((uint)f2bf(lo.y) << 16);
  p.u[1] = (uint)f2bf(lo.z) | ((uint)f2bf(lo.w) << 16);
  p.u[2] = (uint)f2bf(hi.x) | ((uint)f2bf(hi.y) << 16);
  p.u[3] = (uint)f2bf(hi.z) | ((uint)f2bf(hi.w) << 16);
  return p.s;
}

// ---------------- CSR structures ----------------

struct CsrG {
  const int* dst; const int* src;
  unsigned* keys; int* srcs; int* offs;
  int E, n, shift, nbuck, tb, sb;
};
struct CsrGs { CsrG g[5]; };

// ------- setup: proj vectors (LDS-staged) + CSR histograms + W->frag-bf16 --

struct ProjDesc { const float* W; const float* a; float* out; };
struct SetupArgs {
  ProjDesc p[10];
  CsrGs G;
  int* pcnt;                 // [5*32][128]
  const float* wsrc[5];
  ushort* wdst[5];           // fragment-ordered bf16, 2048 recs x 16B
};

__global__ __launch_bounds__(256) void setup_k(SetupArgs A) {
  int b = blockIdx.x;
  int tid = threadIdx.x;
  if (b < 10) {              // proj: out = W^T a, LDS-staged coalesced
    __shared__ float Wl[128 * 132];
    __shared__ float a_s[128];
    ProjDesc d = A.p[b];
    #pragma unroll
    for (int i = 0; i < 16; ++i) {
      int s = tid + i * 256;
      int row = s >> 5, c4 = s & 31;
      float4 w = *(const float4*)&d.W[s * 4];
      float* dst = &Wl[row * 132 + c4 * 4];
      dst[0] = w.x; dst[1] = w.y; dst[2] = w.z; dst[3] = w.w;
    }
    if (tid < 128) a_s[tid] = d.a[tid];
    __syncthreads();
    if (tid < 128) {
      float acc = 0.f;
      #pragma unroll 4
      for (int j = 0; j < 128; ++j) acc += Wl[j * 132 + tid] * a_s[j];
      d.out[tid] = acc;
    }
    return;
  }
  if (b >= 170) {            // W fp32 -> fragment-ordered bf16
    int wi = b - 170;
    const float* Ws = A.wsrc[wi];
    ushort* Wd = A.wdst[wi];
    for (int rec = tid; rec < 2048; rec += 256) {
      int lane = rec & 63;
      int kk = (rec >> 6) & 3;
      int nt = rec >> 8;
      int x = lane & 15, g = lane >> 4;
      const float* src = &Ws[(nt * 16 + x) * 128 + kk * 32 + 4 * g];
      float4 lo = *(const float4*)src;
      float4 hi = *(const float4*)(src + 16);
      bf16x8 pk = packfrag(lo, hi);
      *(bf16x8*)&Wd[rec * 8] = pk;
    }
    return;
  }
  int bsel = b - 10;            // 0..159: histogram
  int gi = bsel >> 5, blk = bsel & 31;
  CsrG g = A.G.g[gi];
  __shared__ int lcnt[128];
  if (tid < 128) lcnt[tid] = 0;
  __syncthreads();
  int chunk = (g.E + 31) >> 5;
  int e0 = blk * chunk, e1 = min(g.E, e0 + chunk);
  for (int e = e0 + tid; e < e1; e += 256)
    atomicAdd(&lcnt[g.dst[e] >> g.shift], 1);
  __syncthreads();
  if (tid < 128) A.pcnt[bsel * 128 + tid] = lcnt[tid];
}

// ---------------- CSR scan ----------------

__global__ __launch_bounds__(512) void csr_scan(CsrGs G, const int* __restrict__ pcnt,
                                                int* __restrict__ cur, int* __restrict__ bases) {
  __shared__ int lc[TBUCK];
  __shared__ int lb[TBUCK + 5];
  int tid = threadIdx.x, lane = tid & 63, wv = tid >> 6;
  if (tid < TBUCK) {
    int gi = 0;
    #pragma unroll
    for (int k = 1; k < 5; ++k) if (tid >= G.g[k].tb) gi = k;
    int b = tid - G.g[gi].tb;
    int s = 0;
    for (int blk = 0; blk < 32; ++blk) s += pcnt[((gi << 5) + blk) * 128 + b];
    lc[tid] = s;
  }
  __syncthreads();
  if (wv < 5) {
    CsrG g = G.g[wv];
    int carry = 0;
    for (int base = 0; base < g.nbuck; base += 64) {
      int idx = base + lane;
      int v = (idx < g.nbuck) ? lc[g.tb + idx] : 0;
      int incl = v;
      #pragma unroll
      for (int o = 1; o < 64; o <<= 1) {
        int y = __shfl_up(incl, o);
        if (lane >= o) incl += y;
      }
      if (idx < g.nbuck) lb[g.sb + idx] = carry + incl - v;
      carry += __shfl(incl, 63);
    }
    if (lane == 0) lb[g.sb + g.nbuck] = carry;
  }
  __syncthreads();
  if (tid < TBUCK + 5) bases[tid] = lb[tid];
  if (tid < TBUCK) {
    int gi = 0;
    for (int k = 1; k < 5; ++k) if (tid >= G.g[k].tb) gi = k;
    cur[tid] = lb[tid + gi];
  }
  if (tid < 5) G.g[tid].offs[G.g[tid].n] = G.g[tid].E;
}

// ------------- mid2_k: csr_partition (600 blks) ∥ MFMA GEMMs + rdot -------
// GEMM now emits per-row-scaled int8 tables (s8 codes + fp32 scale/row).

struct GemmDesc { const float* X; s8* Y8; float* S; int n, b0;
                  const float* dv[6]; float* dq[6]; };
struct BigC {
  GemmDesc g[5];
  int gemm_blocks;
  const float* rx; const float* rv; float* ro; int rnb;
};

__device__ void partition_body(const CsrGs& G, int* __restrict__ cur, int gi, int bx,
                               int nbx, unsigned char* smem) {
  CsrG g = G.g[gi];
  unsigned* ck = (unsigned*)smem;                 // 16384 B
  unsigned char* cb = smem + 16384;               // 4096 B
  int* lcnt = (int*)(smem + 20480);               // 512 B
  int* lcur = (int*)(smem + 20992);               // 512 B
  int tid = threadIdx.x;
  unsigned dmask = (1u << g.shift) - 1;
  for (int c0 = bx * 4096; c0 < g.E; c0 += nbx * 4096) {
    if (tid < 128) lcnt[tid] = 0;
    __syncthreads();
    #pragma unroll
    for (int i = 0; i < 16; ++i) {
      int e = c0 + i * 256 + tid;
      if (e < g.E) {
        int d = g.dst[e], s = g.src[e];
        int b = d >> g.shift;
        ck[i * 256 + tid] = ((unsigned)(d & dmask) << 16) | (unsigned)s;
        cb[i * 256 + tid] = (unsigned char)b;
        atomicAdd(&lcnt[b], 1);
      } else cb[i * 256 + tid] = 255;
    }
    __syncthreads();
    if (tid < g.nbuck && lcnt[tid] > 0) lcur[tid] = atomicAdd(&cur[g.tb + tid], lcnt[tid]);
    __syncthreads();
    #pragma unroll
    for (int i = 0; i < 16; ++i) {
      int b = cb[i * 256 + tid];
      if (b != 255) {
        int pos = atomicAdd(&lcur[b], 1);
        g.keys[pos] = ck[i * 256 + tid];
      }
    }
    __syncthreads();
  }
}

template <int NV>
__device__ void gemm_bodyT(const GemmDesc& gd, const ushort* __restrict__ Wf, int blk) {
  int tid = threadIdx.x;
  int lane = tid & 63, wv = tid >> 6;
  int x = lane & 15, g = lane >> 4;
  int row = blk * 64 + wv * 16 + x;
  const float* xr = &gd.X[(size_t)(row < gd.n ? row : 0) * 128];
  bf16x8 afrag[4];
  float dacc[NV == 0 ? 1 : NV];
  #pragma unroll
  for (int v = 0; v < NV; ++v) dacc[v] = 0.f;
  #pragma unroll
  for (int kk = 0; kk < 4; ++kk) {
    float4 lo = *(const float4*)&xr[kk * 32 + 4 * g];
    float4 hi = *(const float4*)&xr[kk * 32 + 16 + 4 * g];
    afrag[kk] = packfrag(lo, hi);
    #pragma unroll
    for (int v = 0; v < NV; ++v) {
      const float* vp = gd.dv[v];
      float4 vlo = *(const float4*)&vp[kk * 32 + 4 * g];
      float4 vhi = *(const float4*)&vp[kk * 32 + 16 + 4 * g];
      dacc[v] += lo.x * vlo.x + lo.y * vlo.y + lo.z * vlo.z + lo.w * vlo.w
               + hi.x * vhi.x + hi.y * vhi.y + hi.z * vhi.z + hi.w * vhi.w;
    }
  }
  #pragma unroll
  for (int v = 0; v < NV; ++v) {
    float dsum = dacc[v];
    dsum += __shfl_xor(dsum, 16);
    dsum += __shfl_xor(dsum, 32);
    if (lane < 16 && row < gd.n) gd.dq[v][row] = dsum;
  }
  f32x4 acc[8];
  #pragma unroll
  for (int t = 0; t < 8; ++t) acc[t] = (f32x4){0.f, 0.f, 0.f, 0.f};
  #pragma unroll
  for (int nt = 0; nt < 8; ++nt) {
    #pragma unroll
    for (int kk = 0; kk < 4; ++kk) {
      union { uint4 u; bf16x8 s; } bu;
      bu.u = *(const uint4*)&Wf[(size_t)((nt * 4 + kk) * 64 + lane) * 8];
      acc[nt] = __builtin_amdgcn_mfma_f32_16x16x32_bf16(afrag[kk], bu.s, acc[nt], 0, 0, 0);
    }
  }
  // D layout: col = lane&15, row = (lane>>4)*4 + r. Quantize per row to s8.
  int orow = blk * 64 + wv * 16 + 4 * g;
  #pragma unroll
  for (int r = 0; r < 4; ++r) {
    float m8 = 0.f;
    #pragma unroll
    for (int nt = 0; nt < 8; ++nt) m8 = fmaxf(m8, fabsf(acc[nt][r]));
    #pragma unroll
    for (int msk = 1; msk < 16; msk <<= 1) m8 = fmaxf(m8, __shfl_xor(m8, msk));
    int gr = orow + r;
    if (gr < gd.n) {
      float invs = (m8 > 0.f) ? 127.f / m8 : 0.f;
      if (x == 0) gd.S[gr] = m8 * (1.f / 127.f);
      #pragma unroll
      for (int nt = 0; nt < 8; ++nt) {
        int q = (int)rintf(acc[nt][r] * invs);
        gd.Y8[(size_t)gr * 128 + nt * 16 + x] = (s8)q;
      }
    }
  }
}

__device__ void rdot_body(const float* __restrict__ x, const float* __restrict__ v,
                          float* __restrict__ o, int n, int blk, int nblk) {
  int lane = threadIdx.x & 63;
  int wid = (blk * 256 + threadIdx.x) >> 6;
  int nw = nblk * 4;
  float va = v[lane], vb = v[64 + lane];
  for (int r = wid; r < n; r += nw) {
    float a = x[r * 128 + lane] * va + x[r * 128 + 64 + lane] * vb;
    #pragma unroll
    for (int of = 32; of; of >>= 1) a += __shfl_xor(a, of);
    if (lane == 0) o[r] = a;
  }
}

__global__ __launch_bounds__(256, 2) void mid2_k(CsrGs G, int* cur, BigC C,
                                                 const ushort* W0, const ushort* W1,
                                                 const ushort* W2, const ushort* W3,
                                                 const ushort* W4) {
  __shared__ __align__(16) unsigned char smem[21504];
  int b = blockIdx.x;
  if (b < 600) {
    partition_body(G, cur, b / 120, b % 120, 120, smem);
    return;
  }
  b -= 600;
  if (b < C.gemm_blocks) {
    if (b < C.g[1].b0)      gemm_bodyT<6>(C.g[0], W0, b - C.g[0].b0);
    else if (b < C.g[2].b0) gemm_bodyT<4>(C.g[1], W1, b - C.g[1].b0);
    else if (b < C.g[3].b0) gemm_bodyT<0>(C.g[2], W2, b - C.g[2].b0);
    else if (b < C.g[4].b0) gemm_bodyT<1>(C.g[3], W3, b - C.g[3].b0);
    else                    gemm_bodyT<0>(C.g[4], W4, b - C.g[4].b0);
  } else {
    rdot_body(C.rx, C.rv, C.ro, STU_N, b - C.gemm_blocks, C.rnb);
  }
}

// ---------------- csr_build ----------------

__global__ __launch_bounds__(256) void csr_build(CsrGs G, const int* __restrict__ bases) {
  int bid = blockIdx.x;
  int gi = 0;
  for (int k = 1; k < 5; ++k) if (bid >= G.g[k].tb) gi = k;
  CsrG g = G.g[gi];
  int b = bid - g.tb;
  int base = bases[g.sb + b];
  int cnt = bases[g.sb + b + 1] - base;
  if (cnt > 16384) cnt = 16384;

  __shared__ unsigned lkeys[16384];
  __shared__ int lh[512], lex[512], lcu[512], wsum[4];
  int tid = threadIdx.x;
  lh[tid] = 0; lh[tid + 256] = 0;
  __syncthreads();
  for (int j = tid; j < cnt; j += 256) {
    unsigned k = g.keys[base + j];
    lkeys[j] = k;
    atomicAdd(&lh[k >> 16], 1);
  }
  __syncthreads();
  int a0 = lh[2 * tid], a1 = lh[2 * tid + 1];
  int pair = a0 + a1;
  int lane = tid & 63, wv = tid >> 6;
  int incl = pair;
  #pragma unroll
  for (int o = 1; o < 64; o <<= 1) {
    int y = __shfl_up(incl, o);
    if (lane >= o) incl += y;
  }
  if (lane == 63) wsum[wv] = incl;
  __syncthreads();
  if (tid == 0) {
    int s = 0;
    #pragma unroll
    for (int w = 0; w < 4; ++w) { int t = wsum[w]; wsum[w] = s; s += t; }
  }
  __syncthreads();
  int ep = wsum[wv] + incl - pair;
  lex[2 * tid] = ep;       lex[2 * tid + 1] = ep + a0;
  lcu[2 * tid] = ep;       lcu[2 * tid + 1] = ep + a0;
  __syncthreads();
  int dst0 = b << g.shift;
  int ndst = min(1 << g.shift, g.n - dst0);
  for (int dl = tid; dl < ndst; dl += 256) g.offs[dst0 + dl] = base + lex[dl];
  for (int j = tid; j < cnt; j += 256) {
    unsigned k = lkeys[j];
    int dl = k >> 16;
    int pos = atomicAdd(&lcu[dl], 1);
    g.srcs[base + pos] = (int)(k & 0xFFFFu);
  }
}

// ---------------- GAT core: 16-lane group per target, int8 gather ---------

__device__ __forceinline__ void fma8q(float acc[8], float wj, uint2 u) {
  int lo = (int)u.x, hi = (int)u.y;
  acc[0] += wj * (float)((lo << 24) >> 24);
  acc[1] += wj * (float)((lo << 16) >> 24);
  acc[2] += wj * (float)((lo << 8) >> 24);
  acc[3] += wj * (float)(lo >> 24);
  acc[4] += wj * (float)((hi << 24) >> 24);
  acc[5] += wj * (float)((hi << 16) >> 24);
  acc[6] += wj * (float)((hi << 8) >> 24);
  acc[7] += wj * (float)(hi >> 24);
}

// t = t4 + (lane>>4); lane il = lane&15 owns dims il*8..il*8+7 (s8 codes).
__device__ void gat_core16(const int* __restrict__ offs, const int* __restrict__ srcs,
                           const float* __restrict__ sl, const float* __restrict__ sr,
                           const s8* __restrict__ x8, const float* __restrict__ sc,
                           int t4, int n_tgt, int lane, float acc[8]) {
  int q = lane >> 4, il = lane & 15;
  int t = t4 + q;
  bool tv = t < n_tgt;
  int sbeg = tv ? offs[t] : 0;
  int send = tv ? offs[t + 1] : 0;
  float srt = tv ? sr[t] : 0.f;

  int i0l = sbeg + il;
  bool act0 = i0l < send;
  int s0 = act0 ? srcs[i0l] : 0;
  float sc0 = act0 ? sc[s0] : 0.f;
  float e0;
  {
    float e = sl[s0] + srt;
    e = e > 0.f ? e : 0.2f * e;
    e0 = act0 ? e : -1e30f;
  }
  float m = e0, se = act0 ? 1.f : 0.f;
  for (int i = i0l + 16; i < send; i += 16) {
    int s = srcs[i];
    float e = sl[s] + srt;
    e = e > 0.f ? e : 0.2f * e;
    float mn = fmaxf(m, e);
    se = se * __expf(m - mn) + __expf(e - mn);
    m = mn;
  }
  #pragma unroll
  for (int o = 8; o; o >>= 1) {
    float m2 = __shfl_xor(m, o), s2 = __shfl_xor(se, o);
    float mn = fmaxf(m, m2);
    se = se * __expf(m - mn) + s2 * __expf(m2 - mn);
    m = mn;
  }
  float inv = 1.f / (se + 1e-16f);

  #pragma unroll
  for (int r = 0; r < 8; ++r) acc[r] = 0.f;

  int qb = q << 4;
  for (int i0 = sbeg; i0 < send; i0 += 16) {
    int cnt = min(16, send - i0);
    int s; float wgt;
    if (i0 == sbeg) {
      s = s0;
      wgt = act0 ? __expf(e0 - m) * inv * sc0 : 0.f;
    } else {
      s = 0; wgt = 0.f;
      if (il < cnt) {
        s = srcs[i0 + il];
        float e = sl[s] + srt;
        e = e > 0.f ? e : 0.2f * e;
        wgt = __expf(e - m) * inv * sc[s];
      }
    }
    #pragma unroll 2
    for (int j = 0; j < cnt; ++j) {
      int sj = __shfl(s, qb + j);
      float wj = __shfl(wgt, qb + j);
      uint2 u = *(const uint2*)&x8[(size_t)sj * 128 + il * 8];
      fma8q(acc, wj, u);
    }
  }
}

__device__ __forceinline__ void gat_store16(const float acc[8], const float* base0,
                                            float* out, int t4, int n_tgt, int lane) {
  int q = lane >> 4, il = lane & 15;
  int t = t4 + q;
  if (t >= n_tgt) return;
  int d = t * 128 + il * 8;
  float4 a0 = make_float4(acc[0], acc[1], acc[2], acc[3]);
  float4 a1 = make_float4(acc[4], acc[5], acc[6], acc[7]);
  if (base0) {
    const float4 b0 = *(const float4*)&base0[d];
    const float4 b1 = *(const float4*)&base0[d + 4];
    a0.x += b0.x; a0.y += b0.y; a0.z += b0.z; a0.w += b0.w;
    a1.x += b1.x; a1.y += b1.y; a1.z += b1.z; a1.w += b1.w;
  }
  *(float4*)&out[d] = a0;
  *(float4*)&out[d + 4] = a1;
}

__device__ void c1c2_body16(const int* offs, const int* srcs, const float* sl,
                            const float* sr, const s8* x8, const float* sc,
                            const float* al, float* o, float* slo,
                            int t4, int n_tgt, int lane) {
  float acc[8];
  gat_core16(offs, srcs, sl, sr, x8, sc, t4, n_tgt, lane, acc);
  int q = lane >> 4, il = lane & 15;
  int t = t4 + q;
  float4 v0 = *(const float4*)&al[il * 8];
  float4 v1 = *(const float4*)&al[il * 8 + 4];
  float p = acc[0] * v0.x + acc[1] * v0.y + acc[2] * v0.z + acc[3] * v0.w +
            acc[4] * v1.x + acc[5] * v1.y + acc[6] * v1.z + acc[7] * v1.w;
  #pragma unroll
  for (int o2 = 8; o2; o2 >>= 1) p += __shfl_xor(p, o2);
  if (t < n_tgt) {
    if (il == 0) slo[t] = p;
    int d = t * 128 + il * 8;
    *(float4*)&o[d] = make_float4(acc[0], acc[1], acc[2], acc[3]);
    *(float4*)&o[d + 4] = make_float4(acc[4], acc[5], acc[6], acc[7]);
  }
}

// dual (fp32 gather of c1/c2 on cc graph), wave per target (small)
__device__ void gat_dual_core(const int* __restrict__ offs, const int* __restrict__ srcs,
                              const float* __restrict__ sl1, const float* __restrict__ sr1,
                              const float* __restrict__ xl1,
                              const float* __restrict__ sl2, const float* __restrict__ sr2,
                              const float* __restrict__ xl2,
                              const float* __restrict__ base,
                              float* __restrict__ out, int t, int lane) {
  int sbeg = offs[t], send = offs[t + 1];
  float srt1 = sr1[t], srt2 = sr2[t];
  float m1 = -1e30f, m2 = -1e30f;
  for (int i = sbeg + lane; i < send; i += 64) {
    int s = srcs[i];
    float e1 = sl1[s] + srt1; e1 = e1 > 0.f ? e1 : 0.2f * e1;
    float e2 = sl2[s] + srt2; e2 = e2 > 0.f ? e2 : 0.2f * e2;
    m1 = fmaxf(m1, e1); m2 = fmaxf(m2, e2);
  }
  #pragma unroll
  for (int o = 32; o; o >>= 1) {
    m1 = fmaxf(m1, __shfl_xor(m1, o));
    m2 = fmaxf(m2, __shfl_xor(m2, o));
  }
  float se1 = 0.f, se2 = 0.f;
  for (int i = sbeg + lane; i < send; i += 64) {
    int s = srcs[i];
    float e1 = sl1[s] + srt1; e1 = e1 > 0.f ? e1 : 0.2f * e1;
    float e2 = sl2[s] + srt2; e2 = e2 > 0.f ? e2 : 0.2f * e2;
    se1 += __expf(e1 - m1); se2 += __expf(e2 - m2);
  }
  #pragma unroll
  for (int o = 32; o; o >>= 1) {
    se1 += __shfl_xor(se1, o);
    se2 += __shfl_xor(se2, o);
  }
  float inv1 = 1.f / (se1 + 1e-16f), inv2 = 1.f / (se2 + 1e-16f);
  float ax = 0.f, ay = 0.f;
  for (int i0 = sbeg; i0 < send; i0 += 64) {
    int cnt = min(64, send - i0);
    int s = 0; float w1 = 0.f, w2 = 0.f;
    if (lane < cnt) {
      s = srcs[i0 + lane];
      float e1 = sl1[s] + srt1; e1 = e1 > 0.f ? e1 : 0.2f * e1;
      float e2 = sl2[s] + srt2; e2 = e2 > 0.f ? e2 : 0.2f * e2;
      w1 = __expf(e1 - m1) * inv1;
      w2 = __expf(e2 - m2) * inv2;
    }
    for (int j = 0; j < cnt; ++j) {
      int sj = __shfl(s, j);
      float wj1 = __shfl(w1, j);
      float wj2 = __shfl(w2, j);
      const float2 v1 = *(const float2*)&xl1[sj * 128 + lane * 2];
      const float2 v2 = *(const float2*)&xl2[sj * 128 + lane * 2];
      ax += wj1 * v1.x + wj2 * v2.x;
      ay += wj1 * v1.y + wj2 * v2.y;
    }
  }
  const float2 b = *(const float2*)&base[t * 128 + lane * 2];
  float2 o2; o2.x = ax + b.x; o2.y = ay + b.y;
  *(float2*)&out[t * 128 + lane * 2] = o2;
}

// ---- gats_k: [s1 | i1+i2 merged | c1c2], 16 targets per block -------------

#define NB_S1  3125   // ceil(50000/16)
#define NB_I12 1250   // ceil(20000/16)
#define NB_CC  125    // ceil(2000/16)

struct GatsArgs {
  const int *offs4, *srcs4; const float *sl_is, *sr_is; const s8* x_is; const float* sc_is;
  const float* stu_raw_x; float* out_stu;
  const int *offs3, *srcs3; const float *sl_si, *sr_si; const s8* x_si; const float* sc_si;
  const int *offs2, *srcs2; const float *sl_ci, *sr_ci; const s8* x_ci; const float* sc_ci;
  const float* item_x; float* out_item;
  const int *offs0, *srcs0; const float *sl_cc, *sr_cc; const s8* x_cc; const float* sc_cc;
  const float* al_cce; float *c1, *sl_cce;
  const int *offs1, *srcs1; const float *sl_ic, *sr_ic; const s8* x_ic; const float* sc_ic;
  const float* al_ice; float *c2, *sl_ice;
};

__global__ void gats_k(GatsArgs A) {
  int b = blockIdx.x;
  int lane = threadIdx.x & 63;
  int wv = threadIdx.x >> 6;
  if (b < NB_S1) {
    int t4 = b * 16 + wv * 4;
    float acc[8];
    gat_core16(A.offs4, A.srcs4, A.sl_is, A.sr_is, A.x_is, A.sc_is, t4, STU_N, lane, acc);
    gat_store16(acc, A.stu_raw_x, A.out_stu, t4, STU_N, lane);
  } else if (b < NB_S1 + NB_I12) {
    int t4 = (b - NB_S1) * 16 + wv * 4;
    float acc1[8], acc2[8];
    gat_core16(A.offs2, A.srcs2, A.sl_ci, A.sr_ci, A.x_ci, A.sc_ci, t4, ITEM_N, lane, acc1);
    gat_core16(A.offs3, A.srcs3, A.sl_si, A.sr_si, A.x_si, A.sc_si, t4, ITEM_N, lane, acc2);
    #pragma unroll
    for (int r = 0; r < 8; ++r) acc1[r] += acc2[r];
    gat_store16(acc1, A.item_x, A.out_item, t4, ITEM_N, lane);
  } else {
    int sub = b - NB_S1 - NB_I12;   // 0..2*NB_CC-1
    int which = sub >= NB_CC;
    int t4 = (sub - which * NB_CC) * 16 + wv * 4;
    if (!which)
      c1c2_body16(A.offs0, A.srcs0, A.sl_cc, A.sr_cc, A.x_cc, A.sc_cc, A.al_cce,
                  A.c1, A.sl_cce, t4, CONC_N, lane);
    else
      c1c2_body16(A.offs1, A.srcs1, A.sl_ic, A.sr_ic, A.x_ic, A.sc_ic, A.al_ice,
                  A.c2, A.sl_ice, t4, CONC_N, lane);
  }
}

// ---- fin_k: dual(conc) only ----------------------------------------------

__global__ void fin_k(const int* offs0, const int* srcs0,
                      const float* sl_cce, const float* sr_cce, const float* c1,
                      const float* sl_ice, const float* sr_ice, const float* c2,
                      const float* conc_x, float* out_conc) {
  int t = (blockIdx.x * blockDim.x + threadIdx.x) >> 6;
  if (t >= CONC_N) return;
  gat_dual_core(offs0, srcs0, sl_cce, sr_cce, c1, sl_ice, sr_ice, c2,
                conc_x, out_conc, t, threadIdx.x & 63);
}

// ---------------- launch ----------------

extern "C" void kernel_launch(void* const* d_in, const int* in_sizes, int n_in,
                              void* d_out, int out_size, void* d_ws, size_t ws_size,
                              hipStream_t stream) {
  const float* stu_x     = (const float*)d_in[0];
  const float* item_x    = (const float*)d_in[1];
  const float* conc_x    = (const float*)d_in[2];
  const float* stu_raw_x = (const float*)d_in[3];
  const float* W_cc  = (const float*)d_in[4];
  const float* al_cc = (const float*)d_in[5];
  const float* ar_cc = (const float*)d_in[6];
  const float* W_ic  = (const float*)d_in[7];
  const float* al_ic = (const float*)d_in[8];
  const float* ar_ic = (const float*)d_in[9];
  const float* al_cce = (const float*)d_in[10];
  const float* ar_cce = (const float*)d_in[11];
  const float* al_ice = (const float*)d_in[12];
  const float* ar_ice = (const float*)d_in[13];
  const float* W_ci  = (const float*)d_in[14];
  const float* al_ci = (const float*)d_in[15];
  const float* ar_ci = (const float*)d_in[16];
  const float* W_si  = (const float*)d_in[17];
  const float* al_si = (const float*)d_in[18];
  const float* ar_si = (const float*)d_in[19];
  const float* W_is  = (const float*)d_in[22];
  const float* al_is = (const float*)d_in[23];
  const float* ar_is = (const float*)d_in[24];
  const int* cc_src  = (const int*)d_in[25];
  const int* cc_dst  = (const int*)d_in[26];
  const int* ic_item = (const int*)d_in[27];
  const int* ic_conc = (const int*)d_in[28];
  const int* si_stu  = (const int*)d_in[29];
  const int* si_item = (const int*)d_in[30];

  char* wsb = (char*)d_ws;
  size_t off = 0;
  auto alloc = [&](size_t bytes) -> void* {
    void* p = wsb + off;
    off = (off + bytes + 255) & ~(size_t)255;
    return p;
  };

  // int8 W-product tables (gather sources), 128 B/row + fp32 scale/row
  s8* concWcc = (s8*)alloc((size_t)CONC_N * 128);
  s8* itemWic = (s8*)alloc((size_t)ITEM_N * 128);
  s8* concWci = (s8*)alloc((size_t)CONC_N * 128);
  s8* stuWsi  = (s8*)alloc((size_t)STU_N  * 128);
  s8* itemWis = (s8*)alloc((size_t)ITEM_N * 128);
  float* scCcc = (float*)alloc(CONC_N * 4);
  float* scIic = (float*)alloc(ITEM_N * 4);
  float* scCci = (float*)alloc(CONC_N * 4);
  float* scSsi = (float*)alloc(STU_N * 4);
  float* scIis = (float*)alloc(ITEM_N * 4);
  ushort* Wbf[5];
  for (int i = 0; i < 5; ++i) Wbf[i] = (ushort*)alloc(128 * 128 * 2);
  float* c1buf   = (float*)alloc((size_t)CONC_N * 128 * 4);
  float* c2buf   = (float*)alloc((size_t)CONC_N * 128 * 4);
  float* vecs    = (float*)alloc(10 * 128 * 4);
  float* sl_cc  = (float*)alloc(CONC_N * 4);
  float* sr_cc  = (float*)alloc(CONC_N * 4);
  float* sl_ic  = (float*)alloc(ITEM_N * 4);
  float* sr_ic  = (float*)alloc(CONC_N * 4);
  float* sl_ci  = (float*)alloc(CONC_N * 4);
  float* sr_ci  = (float*)alloc(ITEM_N * 4);
  float* sl_si  = (float*)alloc(STU_N * 4);
  float* sr_si  = (float*)alloc(ITEM_N * 4);
  float* sl_is  = (float*)alloc(ITEM_N * 4);
  float* sr_is  = (float*)alloc(STU_N * 4);
  float* sl_cce = (float*)alloc(CONC_N * 4);
  float* sr_cce = (float*)alloc(CONC_N * 4);
  float* sl_ice = (float*)alloc(CONC_N * 4);
  float* sr_ice = (float*)alloc(CONC_N * 4);

  unsigned* keys0 = (unsigned*)alloc((size_t)NE_CC * 4);
  unsigned* keys1 = (unsigned*)alloc((size_t)NE_IC * 4);
  unsigned* keys2 = (unsigned*)alloc((size_t)NE_IC * 4);
  unsigned* keys3 = (unsigned*)alloc((size_t)NE_SI * 4);
  unsigned* keys4 = (unsigned*)alloc((size_t)NE_SI * 4);
  int* srcs0 = (int*)alloc((size_t)NE_CC * 4);
  int* srcs1 = (int*)alloc((size_t)NE_IC * 4);
  int* srcs2 = (int*)alloc((size_t)NE_IC * 4);
  int* srcs3 = (int*)alloc((size_t)NE_SI * 4);
  int* srcs4 = (int*)alloc((size_t)NE_SI * 4);
  int* offs0 = (int*)alloc((CONC_N + 1) * 4);
  int* offs1 = (int*)alloc((CONC_N + 1) * 4);
  int* offs2 = (int*)alloc((ITEM_N + 1) * 4);
  int* offs3 = (int*)alloc((ITEM_N + 1) * 4);
  int* offs4 = (int*)alloc((STU_N + 1) * 4);
  int* pcnt      = (int*)alloc(5 * 32 * 128 * 4);
  int* cur_all   = (int*)alloc(TBUCK * 4);
  int* bases_all = (int*)alloc((TBUCK + 5) * 4);

  float* out = (float*)d_out;
  float* out_conc = out;
  float* out_item = out + (size_t)CONC_N * 128;
  float* out_stu  = out + (size_t)(CONC_N + ITEM_N) * 128;

  CsrGs G;
  G.g[0] = {cc_dst,  cc_src,  keys0, srcs0, offs0, NE_CC, CONC_N, 5, 63,   0,   0};
  G.g[1] = {ic_conc, ic_item, keys1, srcs1, offs1, NE_IC, CONC_N, 5, 63,  63,  64};
  G.g[2] = {ic_item, ic_conc, keys2, srcs2, offs2, NE_IC, ITEM_N, 8, 79, 126, 128};
  G.g[3] = {si_item, si_stu,  keys3, srcs3, offs3, NE_SI, ITEM_N, 8, 79, 205, 208};
  G.g[4] = {si_stu,  si_item, keys4, srcs4, offs4, NE_SI, STU_N,  9, 98, 284, 288};

  // K1: setup (proj vectors + CSR histograms + W->frag-bf16)
  SetupArgs SA;
  SA.p[0] = {W_cc, al_cc, vecs + 0 * 128};
  SA.p[1] = {W_cc, ar_cc, vecs + 1 * 128};
  SA.p[2] = {W_ic, al_ic, vecs + 2 * 128};
  SA.p[3] = {W_ic, ar_ic, vecs + 3 * 128};
  SA.p[4] = {W_ci, al_ci, vecs + 4 * 128};
  SA.p[5] = {W_ci, ar_ci, vecs + 5 * 128};
  SA.p[6] = {W_si, al_si, vecs + 6 * 128};
  SA.p[7] = {W_si, ar_si, vecs + 7 * 128};
  SA.p[8] = {W_is, al_is, vecs + 8 * 128};
  SA.p[9] = {W_is, ar_is, vecs + 9 * 128};
  SA.G = G;
  SA.pcnt = pcnt;
  SA.wsrc[0] = W_cc; SA.wsrc[1] = W_ic; SA.wsrc[2] = W_ci;
  SA.wsrc[3] = W_si; SA.wsrc[4] = W_is;
  for (int i = 0; i < 5; ++i) SA.wdst[i] = Wbf[i];
  setup_k<<<175, 256, 0, stream>>>(SA);

  // K2: scan
  csr_scan<<<1, 512, 0, stream>>>(G, pcnt, cur_all, bases_all);

  // K3: partition (600) ∥ MFMA gemms (+fused dots, s8 output) + rdot
  BigC C;
  C.g[0] = {conc_x, concWcc, scCcc, CONC_N, 0,
            {vecs + 0 * 128, vecs + 1 * 128, vecs + 3 * 128, vecs + 4 * 128, ar_cce, ar_ice},
            {sl_cc, sr_cc, sr_ic, sl_ci, sr_cce, sr_ice}};
  C.g[1] = {item_x, itemWic, scIic, ITEM_N, 32,
            {vecs + 2 * 128, vecs + 5 * 128, vecs + 7 * 128, vecs + 8 * 128, nullptr, nullptr},
            {sl_ic, sr_ci, sr_si, sl_is, nullptr, nullptr}};
  C.g[2] = {conc_x, concWci, scCci, CONC_N, 345,
            {nullptr, nullptr, nullptr, nullptr, nullptr, nullptr},
            {nullptr, nullptr, nullptr, nullptr, nullptr, nullptr}};
  C.g[3] = {stu_x, stuWsi, scSsi, STU_N, 377,
            {vecs + 6 * 128, nullptr, nullptr, nullptr, nullptr, nullptr},
            {sl_si, nullptr, nullptr, nullptr, nullptr, nullptr}};
  C.g[4] = {item_x, itemWis, scIis, ITEM_N, 1159,
            {nullptr, nullptr, nullptr, nullptr, nullptr, nullptr},
            {nullptr, nullptr, nullptr, nullptr, nullptr, nullptr}};
  C.gemm_blocks = 1472;
  C.rx = stu_raw_x; C.rv = vecs + 9 * 128; C.ro = sr_is; C.rnb = 1024;
  mid2_k<<<600 + 2496, 256, 0, stream>>>(G, cur_all, C, Wbf[0], Wbf[1], Wbf[2], Wbf[3], Wbf[4]);

  // K4: build
  csr_build<<<TBUCK, 256, 0, stream>>>(G, bases_all);

  // K5: all independent GATs in one launch (s1 | i1+i2 | c1c2), 16 tgt/block
  GatsArgs GA;
  GA.offs4 = offs4; GA.srcs4 = srcs4; GA.sl_is = sl_is; GA.sr_is = sr_is;
  GA.x_is = itemWis; GA.sc_is = scIis; GA.stu_raw_x = stu_raw_x; GA.out_stu = out_stu;
  GA.offs3 = offs3; GA.srcs3 = srcs3; GA.sl_si = sl_si; GA.sr_si = sr_si;
  GA.x_si = stuWsi; GA.sc_si = scSsi;
  GA.offs2 = offs2; GA.srcs2 = srcs2; GA.sl_ci = sl_ci; GA.sr_ci = sr_ci;
  GA.x_ci = concWci; GA.sc_ci = scCci; GA.item_x = item_x; GA.out_item = out_item;
  GA.offs0 = offs0; GA.srcs0 = srcs0; GA.sl_cc = sl_cc; GA.sr_cc = sr_cc;
  GA.x_cc = concWcc; GA.sc_cc = scCcc; GA.al_cce = al_cce; GA.c1 = c1buf; GA.sl_cce = sl_cce;
  GA.offs1 = offs1; GA.srcs1 = srcs1; GA.sl_ic = sl_ic; GA.sr_ic = sr_ic;
  GA.x_ic = itemWic; GA.sc_ic = scIic; GA.al_ice = al_ice; GA.c2 = c2buf; GA.sl_ice = sl_ice;
  gats_k<<<NB_S1 + NB_I12 + 2 * NB_CC, 256, 0, stream>>>(GA);

  // K6: dual (needs c1/c2 + their dots)
  fin_k<<<500, 256, 0, stream>>>(offs0, srcs0, sl_cce, sr_cce, c1buf,
                                 sl_ice, sr_ice, c2buf, conc_x, out_conc);
}

// Round 14
// 200.686 us; speedup vs baseline: 1.1947x; 1.0201x over previous
//
#include <hip/hip_runtime.h>

#define CONC_N 2000
#define ITEM_N 20000
#define STU_N  50000
#define NE_CC  40000
#define NE_IC  80000
#define NE_SI  1000000
#define TBUCK  382   // 63+63+79+79+98

typedef unsigned int uint;
typedef unsigned short ushort;
typedef signed char s8;
typedef __attribute__((ext_vector_type(8))) short bf16x8;
typedef __attribute__((ext_vector_type(4))) float f32x4;

__device__ __forceinline__ ushort f2bf(float f) {
  uint u = __float_as_uint(f);
  uint r = (u + 0x7FFFu + ((u >> 16) & 1u)) >> 16;
  return (ushort)r;
}

__device__ __forceinline__ bf16x8 packfrag(float4 lo, float4 hi) {
  union { bf16x8 s; uint u[4]; } p;
  p.u[0] = (uint)f2bf(lo.x) | ((uint)f2bf(lo.y) << 16);
  p.u[1] = (uint)f2bf(lo.z) | ((uint)f2bf(lo.w) << 16);
  p.u[2] = (uint)f2bf(hi.x) | ((uint)f2bf(hi.y) << 16);
  p.u[3] = (uint)f2bf(hi.z) | ((uint)f2bf(hi.w) << 16);
  return p.s;
}

// ---------------- CSR structures ----------------

struct CsrG {
  const int* dst; const int* src;
  unsigned* keys; int* srcs; int* offs;
  int E, n, shift, nbuck, tb, sb;
};
struct CsrGs { CsrG g[5]; };

// ------- setup: proj vectors (LDS-staged) + CSR histograms + W->frag-bf16 --

struct ProjDesc { const float* W; const float* a; float* out; };
struct SetupArgs {
  ProjDesc p[10];
  CsrGs G;
  int* pcnt;                 // [5*32][128]
  const float* wsrc[5];
  ushort* wdst[5];           // fragment-ordered bf16, 2048 recs x 16B
};

__global__ __launch_bounds__(256) void setup_k(SetupArgs A) {
  int b = blockIdx.x;
  int tid = threadIdx.x;
  if (b < 10) {              // proj: out = W^T a, LDS-staged coalesced
    __shared__ float Wl[128 * 132];
    __shared__ float a_s[128];
    ProjDesc d = A.p[b];
    #pragma unroll
    for (int i = 0; i < 16; ++i) {
      int s = tid + i * 256;
      int row = s >> 5, c4 = s & 31;
      float4 w = *(const float4*)&d.W[s * 4];
      float* dst = &Wl[row * 132 + c4 * 4];
      dst[0] = w.x; dst[1] = w.y; dst[2] = w.z; dst[3] = w.w;
    }
    if (tid < 128) a_s[tid] = d.a[tid];
    __syncthreads();
    if (tid < 128) {
      float acc = 0.f;
      #pragma unroll 4
      for (int j = 0; j < 128; ++j) acc += Wl[j * 132 + tid] * a_s[j];
      d.out[tid] = acc;
    }
    return;
  }
  if (b >= 170) {            // W fp32 -> fragment-ordered bf16
    int wi = b - 170;
    const float* Ws = A.wsrc[wi];
    ushort* Wd = A.wdst[wi];
    for (int rec = tid; rec < 2048; rec += 256) {
      int lane = rec & 63;
      int kk = (rec >> 6) & 3;
      int nt = rec >> 8;
      int x = lane & 15, g = lane >> 4;
      const float* src = &Ws[(nt * 16 + x) * 128 + kk * 32 + 4 * g];
      float4 lo = *(const float4*)src;
      float4 hi = *(const float4*)(src + 16);
      bf16x8 pk = packfrag(lo, hi);
      *(bf16x8*)&Wd[rec * 8] = pk;
    }
    return;
  }
  int bsel = b - 10;            // 0..159: histogram
  int gi = bsel >> 5, blk = bsel & 31;
  CsrG g = A.G.g[gi];
  __shared__ int lcnt[128];
  if (tid < 128) lcnt[tid] = 0;
  __syncthreads();
  int chunk = (g.E + 31) >> 5;
  int e0 = blk * chunk, e1 = min(g.E, e0 + chunk);
  for (int e = e0 + tid; e < e1; e += 256)
    atomicAdd(&lcnt[g.dst[e] >> g.shift], 1);
  __syncthreads();
  if (tid < 128) A.pcnt[bsel * 128 + tid] = lcnt[tid];
}

// ---------------- CSR scan ----------------

__global__ __launch_bounds__(512) void csr_scan(CsrGs G, const int* __restrict__ pcnt,
                                                int* __restrict__ cur, int* __restrict__ bases) {
  __shared__ int lc[TBUCK];
  __shared__ int lb[TBUCK + 5];
  int tid = threadIdx.x, lane = tid & 63, wv = tid >> 6;
  if (tid < TBUCK) {
    int gi = 0;
    #pragma unroll
    for (int k = 1; k < 5; ++k) if (tid >= G.g[k].tb) gi = k;
    int b = tid - G.g[gi].tb;
    int s = 0;
    for (int blk = 0; blk < 32; ++blk) s += pcnt[((gi << 5) + blk) * 128 + b];
    lc[tid] = s;
  }
  __syncthreads();
  if (wv < 5) {
    CsrG g = G.g[wv];
    int carry = 0;
    for (int base = 0; base < g.nbuck; base += 64) {
      int idx = base + lane;
      int v = (idx < g.nbuck) ? lc[g.tb + idx] : 0;
      int incl = v;
      #pragma unroll
      for (int o = 1; o < 64; o <<= 1) {
        int y = __shfl_up(incl, o);
        if (lane >= o) incl += y;
      }
      if (idx < g.nbuck) lb[g.sb + idx] = carry + incl - v;
      carry += __shfl(incl, 63);
    }
    if (lane == 0) lb[g.sb + g.nbuck] = carry;
  }
  __syncthreads();
  if (tid < TBUCK + 5) bases[tid] = lb[tid];
  if (tid < TBUCK) {
    int gi = 0;
    for (int k = 1; k < 5; ++k) if (tid >= G.g[k].tb) gi = k;
    cur[tid] = lb[tid + gi];
  }
  if (tid < 5) G.g[tid].offs[G.g[tid].n] = G.g[tid].E;
}

// ------------- mid3_k: csr_partition (600 blks) ∥ rdot (1024 blks) --------

__device__ void partition_body(const CsrGs& G, int* __restrict__ cur, int gi, int bx,
                               int nbx, unsigned char* smem) {
  CsrG g = G.g[gi];
  unsigned* ck = (unsigned*)smem;                 // 16384 B
  unsigned char* cb = smem + 16384;               // 4096 B
  int* lcnt = (int*)(smem + 20480);               // 512 B
  int* lcur = (int*)(smem + 20992);               // 512 B
  int tid = threadIdx.x;
  unsigned dmask = (1u << g.shift) - 1;
  for (int c0 = bx * 4096; c0 < g.E; c0 += nbx * 4096) {
    if (tid < 128) lcnt[tid] = 0;
    __syncthreads();
    #pragma unroll
    for (int i = 0; i < 16; ++i) {
      int e = c0 + i * 256 + tid;
      if (e < g.E) {
        int d = g.dst[e], s = g.src[e];
        int b = d >> g.shift;
        ck[i * 256 + tid] = ((unsigned)(d & dmask) << 16) | (unsigned)s;
        cb[i * 256 + tid] = (unsigned char)b;
        atomicAdd(&lcnt[b], 1);
      } else cb[i * 256 + tid] = 255;
    }
    __syncthreads();
    if (tid < g.nbuck && lcnt[tid] > 0) lcur[tid] = atomicAdd(&cur[g.tb + tid], lcnt[tid]);
    __syncthreads();
    #pragma unroll
    for (int i = 0; i < 16; ++i) {
      int b = cb[i * 256 + tid];
      if (b != 255) {
        int pos = atomicAdd(&lcur[b], 1);
        g.keys[pos] = ck[i * 256 + tid];
      }
    }
    __syncthreads();
  }
}

__device__ void rdot_body(const float* __restrict__ x, const float* __restrict__ v,
                          float* __restrict__ o, int n, int blk, int nblk) {
  int lane = threadIdx.x & 63;
  int wid = (blk * 256 + threadIdx.x) >> 6;
  int nw = nblk * 4;
  float va = v[lane], vb = v[64 + lane];
  for (int r = wid; r < n; r += nw) {
    float a = x[r * 128 + lane] * va + x[r * 128 + 64 + lane] * vb;
    #pragma unroll
    for (int of = 32; of; of >>= 1) a += __shfl_xor(a, of);
    if (lane == 0) o[r] = a;
  }
}

__global__ __launch_bounds__(256) void mid3_k(CsrGs G, int* cur,
                                              const float* rx, const float* rv,
                                              float* ro, int rnb) {
  __shared__ __align__(16) unsigned char smem[21504];
  int b = blockIdx.x;
  if (b < 600) {
    partition_body(G, cur, b / 120, b % 120, 120, smem);
  } else {
    rdot_body(rx, rv, ro, STU_N, b - 600, rnb);
  }
}

// ------------- mid4_k: build_lite (382 blks) ∥ MFMA GEMMs -----------------
// build_lite: 2-pass over global keys (hist, then scatter) -> only 6KB LDS,
// so fusing with the zero-LDS gemm does not cap occupancy.

struct GemmDesc { const float* X; s8* Y8; float* S; int n, b0;
                  const float* dv[6]; float* dq[6]; };
struct BigC {
  GemmDesc g[5];
  int gemm_blocks;
};

__device__ void build_lite(const CsrGs& G, const int* __restrict__ bases, int bid,
                           int* lh, int* lex, int* lcu, int* wsum) {
  int gi = 0;
  for (int k = 1; k < 5; ++k) if (bid >= G.g[k].tb) gi = k;
  CsrG g = G.g[gi];
  int b = bid - g.tb;
  int base = bases[g.sb + b];
  int cnt = bases[g.sb + b + 1] - base;

  int tid = threadIdx.x;
  lh[tid] = 0; lh[tid + 256] = 0;
  __syncthreads();
  for (int j = tid; j < cnt; j += 256)
    atomicAdd(&lh[g.keys[base + j] >> 16], 1);
  __syncthreads();
  int a0 = lh[2 * tid], a1 = lh[2 * tid + 1];
  int pair = a0 + a1;
  int lane = tid & 63, wv = tid >> 6;
  int incl = pair;
  #pragma unroll
  for (int o = 1; o < 64; o <<= 1) {
    int y = __shfl_up(incl, o);
    if (lane >= o) incl += y;
  }
  if (lane == 63) wsum[wv] = incl;
  __syncthreads();
  if (tid == 0) {
    int s = 0;
    #pragma unroll
    for (int w = 0; w < 4; ++w) { int t = wsum[w]; wsum[w] = s; s += t; }
  }
  __syncthreads();
  int ep = wsum[wv] + incl - pair;
  lex[2 * tid] = ep;       lex[2 * tid + 1] = ep + a0;
  lcu[2 * tid] = ep;       lcu[2 * tid + 1] = ep + a0;
  __syncthreads();
  int dst0 = b << g.shift;
  int ndst = min(1 << g.shift, g.n - dst0);
  for (int dl = tid; dl < ndst; dl += 256) g.offs[dst0 + dl] = base + lex[dl];
  for (int j = tid; j < cnt; j += 256) {
    unsigned k = g.keys[base + j];
    int dl = k >> 16;
    int pos = atomicAdd(&lcu[dl], 1);
    g.srcs[base + pos] = (int)(k & 0xFFFFu);
  }
}

template <int NV>
__device__ void gemm_bodyT(const GemmDesc& gd, const ushort* __restrict__ Wf, int blk) {
  int tid = threadIdx.x;
  int lane = tid & 63, wv = tid >> 6;
  int x = lane & 15, g = lane >> 4;
  int row = blk * 64 + wv * 16 + x;
  const float* xr = &gd.X[(size_t)(row < gd.n ? row : 0) * 128];
  bf16x8 afrag[4];
  float dacc[NV == 0 ? 1 : NV];
  #pragma unroll
  for (int v = 0; v < NV; ++v) dacc[v] = 0.f;
  #pragma unroll
  for (int kk = 0; kk < 4; ++kk) {
    float4 lo = *(const float4*)&xr[kk * 32 + 4 * g];
    float4 hi = *(const float4*)&xr[kk * 32 + 16 + 4 * g];
    afrag[kk] = packfrag(lo, hi);
    #pragma unroll
    for (int v = 0; v < NV; ++v) {
      const float* vp = gd.dv[v];
      float4 vlo = *(const float4*)&vp[kk * 32 + 4 * g];
      float4 vhi = *(const float4*)&vp[kk * 32 + 16 + 4 * g];
      dacc[v] += lo.x * vlo.x + lo.y * vlo.y + lo.z * vlo.z + lo.w * vlo.w
               + hi.x * vhi.x + hi.y * vhi.y + hi.z * vhi.z + hi.w * vhi.w;
    }
  }
  #pragma unroll
  for (int v = 0; v < NV; ++v) {
    float dsum = dacc[v];
    dsum += __shfl_xor(dsum, 16);
    dsum += __shfl_xor(dsum, 32);
    if (lane < 16 && row < gd.n) gd.dq[v][row] = dsum;
  }
  f32x4 acc[8];
  #pragma unroll
  for (int t = 0; t < 8; ++t) acc[t] = (f32x4){0.f, 0.f, 0.f, 0.f};
  #pragma unroll
  for (int nt = 0; nt < 8; ++nt) {
    #pragma unroll
    for (int kk = 0; kk < 4; ++kk) {
      union { uint4 u; bf16x8 s; } bu;
      bu.u = *(const uint4*)&Wf[(size_t)((nt * 4 + kk) * 64 + lane) * 8];
      acc[nt] = __builtin_amdgcn_mfma_f32_16x16x32_bf16(afrag[kk], bu.s, acc[nt], 0, 0, 0);
    }
  }
  // D layout: col = lane&15, row = (lane>>4)*4 + r. Quantize per row to s8.
  int orow = blk * 64 + wv * 16 + 4 * g;
  #pragma unroll
  for (int r = 0; r < 4; ++r) {
    float m8 = 0.f;
    #pragma unroll
    for (int nt = 0; nt < 8; ++nt) m8 = fmaxf(m8, fabsf(acc[nt][r]));
    #pragma unroll
    for (int msk = 1; msk < 16; msk <<= 1) m8 = fmaxf(m8, __shfl_xor(m8, msk));
    int gr = orow + r;
    if (gr < gd.n) {
      float invs = (m8 > 0.f) ? 127.f / m8 : 0.f;
      if (x == 0) gd.S[gr] = m8 * (1.f / 127.f);
      #pragma unroll
      for (int nt = 0; nt < 8; ++nt) {
        int q = (int)rintf(acc[nt][r] * invs);
        gd.Y8[(size_t)gr * 128 + nt * 16 + x] = (s8)q;
      }
    }
  }
}

__global__ __launch_bounds__(256, 2) void mid4_k(CsrGs G, const int* bases, BigC C,
                                                 const ushort* W0, const ushort* W1,
                                                 const ushort* W2, const ushort* W3,
                                                 const ushort* W4) {
  __shared__ int lh[512], lex[512], lcu[512], wsum[4];
  int b = blockIdx.x;
  if (b < TBUCK) {
    build_lite(G, bases, b, lh, lex, lcu, wsum);
    return;
  }
  b -= TBUCK;
  if (b < C.g[1].b0)      gemm_bodyT<6>(C.g[0], W0, b - C.g[0].b0);
  else if (b < C.g[2].b0) gemm_bodyT<4>(C.g[1], W1, b - C.g[1].b0);
  else if (b < C.g[3].b0) gemm_bodyT<0>(C.g[2], W2, b - C.g[2].b0);
  else if (b < C.g[4].b0) gemm_bodyT<1>(C.g[3], W3, b - C.g[3].b0);
  else                    gemm_bodyT<0>(C.g[4], W4, b - C.g[4].b0);
}

// ---------------- GAT core: 16-lane group per target, int8 gather ---------

__device__ __forceinline__ void fma8q(float acc[8], float wj, uint2 u) {
  int lo = (int)u.x, hi = (int)u.y;
  acc[0] += wj * (float)((lo << 24) >> 24);
  acc[1] += wj * (float)((lo << 16) >> 24);
  acc[2] += wj * (float)((lo << 8) >> 24);
  acc[3] += wj * (float)(lo >> 24);
  acc[4] += wj * (float)((hi << 24) >> 24);
  acc[5] += wj * (float)((hi << 16) >> 24);
  acc[6] += wj * (float)((hi << 8) >> 24);
  acc[7] += wj * (float)(hi >> 24);
}

// t = t4 + (lane>>4); lane il = lane&15 owns dims il*8..il*8+7 (s8 codes).
__device__ void gat_core16(const int* __restrict__ offs, const int* __restrict__ srcs,
                           const float* __restrict__ sl, const float* __restrict__ sr,
                           const s8* __restrict__ x8, const float* __restrict__ sc,
                           int t4, int n_tgt, int lane, float acc[8]) {
  int q = lane >> 4, il = lane & 15;
  int t = t4 + q;
  bool tv = t < n_tgt;
  int sbeg = tv ? offs[t] : 0;
  int send = tv ? offs[t + 1] : 0;
  float srt = tv ? sr[t] : 0.f;

  int i0l = sbeg + il;
  bool act0 = i0l < send;
  int s0 = act0 ? srcs[i0l] : 0;
  float sc0 = act0 ? sc[s0] : 0.f;
  float e0;
  {
    float e = sl[s0] + srt;
    e = e > 0.f ? e : 0.2f * e;
    e0 = act0 ? e : -1e30f;
  }
  float m = e0, se = act0 ? 1.f : 0.f;
  for (int i = i0l + 16; i < send; i += 16) {
    int s = srcs[i];
    float e = sl[s] + srt;
    e = e > 0.f ? e : 0.2f * e;
    float mn = fmaxf(m, e);
    se = se * __expf(m - mn) + __expf(e - mn);
    m = mn;
  }
  #pragma unroll
  for (int o = 8; o; o >>= 1) {
    float m2 = __shfl_xor(m, o), s2 = __shfl_xor(se, o);
    float mn = fmaxf(m, m2);
    se = se * __expf(m - mn) + s2 * __expf(m2 - mn);
    m = mn;
  }
  float inv = 1.f / (se + 1e-16f);

  #pragma unroll
  for (int r = 0; r < 8; ++r) acc[r] = 0.f;

  int qb = q << 4;
  for (int i0 = sbeg; i0 < send; i0 += 16) {
    int cnt = min(16, send - i0);
    int s; float wgt;
    if (i0 == sbeg) {
      s = s0;
      wgt = act0 ? __expf(e0 - m) * inv * sc0 : 0.f;
    } else {
      s = 0; wgt = 0.f;
      if (il < cnt) {
        s = srcs[i0 + il];
        float e = sl[s] + srt;
        e = e > 0.f ? e : 0.2f * e;
        wgt = __expf(e - m) * inv * sc[s];
      }
    }
    #pragma unroll 2
    for (int j = 0; j < cnt; ++j) {
      int sj = __shfl(s, qb + j);
      float wj = __shfl(wgt, qb + j);
      uint2 u = *(const uint2*)&x8[(size_t)sj * 128 + il * 8];
      fma8q(acc, wj, u);
    }
  }
}

__device__ __forceinline__ void gat_store16(const float acc[8], const float* base0,
                                            float* out, int t4, int n_tgt, int lane) {
  int q = lane >> 4, il = lane & 15;
  int t = t4 + q;
  if (t >= n_tgt) return;
  int d = t * 128 + il * 8;
  float4 a0 = make_float4(acc[0], acc[1], acc[2], acc[3]);
  float4 a1 = make_float4(acc[4], acc[5], acc[6], acc[7]);
  if (base0) {
    const float4 b0 = *(const float4*)&base0[d];
    const float4 b1 = *(const float4*)&base0[d + 4];
    a0.x += b0.x; a0.y += b0.y; a0.z += b0.z; a0.w += b0.w;
    a1.x += b1.x; a1.y += b1.y; a1.z += b1.z; a1.w += b1.w;
  }
  *(float4*)&out[d] = a0;
  *(float4*)&out[d + 4] = a1;
}

__device__ void c1c2_body16(const int* offs, const int* srcs, const float* sl,
                            const float* sr, const s8* x8, const float* sc,
                            const float* al, float* o, float* slo,
                            int t4, int n_tgt, int lane) {
  float acc[8];
  gat_core16(offs, srcs, sl, sr, x8, sc, t4, n_tgt, lane, acc);
  int q = lane >> 4, il = lane & 15;
  int t = t4 + q;
  float4 v0 = *(const float4*)&al[il * 8];
  float4 v1 = *(const float4*)&al[il * 8 + 4];
  float p = acc[0] * v0.x + acc[1] * v0.y + acc[2] * v0.z + acc[3] * v0.w +
            acc[4] * v1.x + acc[5] * v1.y + acc[6] * v1.z + acc[7] * v1.w;
  #pragma unroll
  for (int o2 = 8; o2; o2 >>= 1) p += __shfl_xor(p, o2);
  if (t < n_tgt) {
    if (il == 0) slo[t] = p;
    int d = t * 128 + il * 8;
    *(float4*)&o[d] = make_float4(acc[0], acc[1], acc[2], acc[3]);
    *(float4*)&o[d + 4] = make_float4(acc[4], acc[5], acc[6], acc[7]);
  }
}

// dual (fp32 gather of c1/c2 on cc graph), wave per target (small)
__device__ void gat_dual_core(const int* __restrict__ offs, const int* __restrict__ srcs,
                              const float* __restrict__ sl1, const float* __restrict__ sr1,
                              const float* __restrict__ xl1,
                              const float* __restrict__ sl2, const float* __restrict__ sr2,
                              const float* __restrict__ xl2,
                              const float* __restrict__ base,
                              float* __restrict__ out, int t, int lane) {
  int sbeg = offs[t], send = offs[t + 1];
  float srt1 = sr1[t], srt2 = sr2[t];
  float m1 = -1e30f, m2 = -1e30f;
  for (int i = sbeg + lane; i < send; i += 64) {
    int s = srcs[i];
    float e1 = sl1[s] + srt1; e1 = e1 > 0.f ? e1 : 0.2f * e1;
    float e2 = sl2[s] + srt2; e2 = e2 > 0.f ? e2 : 0.2f * e2;
    m1 = fmaxf(m1, e1); m2 = fmaxf(m2, e2);
  }
  #pragma unroll
  for (int o = 32; o; o >>= 1) {
    m1 = fmaxf(m1, __shfl_xor(m1, o));
    m2 = fmaxf(m2, __shfl_xor(m2, o));
  }
  float se1 = 0.f, se2 = 0.f;
  for (int i = sbeg + lane; i < send; i += 64) {
    int s = srcs[i];
    float e1 = sl1[s] + srt1; e1 = e1 > 0.f ? e1 : 0.2f * e1;
    float e2 = sl2[s] + srt2; e2 = e2 > 0.f ? e2 : 0.2f * e2;
    se1 += __expf(e1 - m1); se2 += __expf(e2 - m2);
  }
  #pragma unroll
  for (int o = 32; o; o >>= 1) {
    se1 += __shfl_xor(se1, o);
    se2 += __shfl_xor(se2, o);
  }
  float inv1 = 1.f / (se1 + 1e-16f), inv2 = 1.f / (se2 + 1e-16f);
  float ax = 0.f, ay = 0.f;
  for (int i0 = sbeg; i0 < send; i0 += 64) {
    int cnt = min(64, send - i0);
    int s = 0; float w1 = 0.f, w2 = 0.f;
    if (lane < cnt) {
      s = srcs[i0 + lane];
      float e1 = sl1[s] + srt1; e1 = e1 > 0.f ? e1 : 0.2f * e1;
      float e2 = sl2[s] + srt2; e2 = e2 > 0.f ? e2 : 0.2f * e2;
      w1 = __expf(e1 - m1) * inv1;
      w2 = __expf(e2 - m2) * inv2;
    }
    for (int j = 0; j < cnt; ++j) {
      int sj = __shfl(s, j);
      float wj1 = __shfl(w1, j);
      float wj2 = __shfl(w2, j);
      const float2 v1 = *(const float2*)&xl1[sj * 128 + lane * 2];
      const float2 v2 = *(const float2*)&xl2[sj * 128 + lane * 2];
      ax += wj1 * v1.x + wj2 * v2.x;
      ay += wj1 * v1.y + wj2 * v2.y;
    }
  }
  const float2 b = *(const float2*)&base[t * 128 + lane * 2];
  float2 o2; o2.x = ax + b.x; o2.y = ay + b.y;
  *(float2*)&out[t * 128 + lane * 2] = o2;
}

// ---- gats_k: [i1+i2 merged | s1 | c1c2], heavy blocks first ---------------

#define NB_I12 1250   // ceil(20000/16)
#define NB_S1  3125   // ceil(50000/16)
#define NB_CC  125    // ceil(2000/16)

struct GatsArgs {
  const int *offs4, *srcs4; const float *sl_is, *sr_is; const s8* x_is; const float* sc_is;
  const float* stu_raw_x; float* out_stu;
  const int *offs3, *srcs3; const float *sl_si, *sr_si; const s8* x_si; const float* sc_si;
  const int *offs2, *srcs2; const float *sl_ci, *sr_ci; const s8* x_ci; const float* sc_ci;
  const float* item_x; float* out_item;
  const int *offs0, *srcs0; const float *sl_cc, *sr_cc; const s8* x_cc; const float* sc_cc;
  const float* al_cce; float *c1, *sl_cce;
  const int *offs1, *srcs1; const float *sl_ic, *sr_ic; const s8* x_ic; const float* sc_ic;
  const float* al_ice; float *c2, *sl_ice;
};

__global__ void gats_k(GatsArgs A) {
  int b = blockIdx.x;
  int lane = threadIdx.x & 63;
  int wv = threadIdx.x >> 6;
  if (b < NB_I12) {
    int t4 = b * 16 + wv * 4;
    float acc1[8], acc2[8];
    gat_core16(A.offs2, A.srcs2, A.sl_ci, A.sr_ci, A.x_ci, A.sc_ci, t4, ITEM_N, lane, acc1);
    gat_core16(A.offs3, A.srcs3, A.sl_si, A.sr_si, A.x_si, A.sc_si, t4, ITEM_N, lane, acc2);
    #pragma unroll
    for (int r = 0; r < 8; ++r) acc1[r] += acc2[r];
    gat_store16(acc1, A.item_x, A.out_item, t4, ITEM_N, lane);
  } else if (b < NB_I12 + NB_S1) {
    int t4 = (b - NB_I12) * 16 + wv * 4;
    float acc[8];
    gat_core16(A.offs4, A.srcs4, A.sl_is, A.sr_is, A.x_is, A.sc_is, t4, STU_N, lane, acc);
    gat_store16(acc, A.stu_raw_x, A.out_stu, t4, STU_N, lane);
  } else {
    int sub = b - NB_I12 - NB_S1;   // 0..2*NB_CC-1
    int which = sub >= NB_CC;
    int t4 = (sub - which * NB_CC) * 16 + wv * 4;
    if (!which)
      c1c2_body16(A.offs0, A.srcs0, A.sl_cc, A.sr_cc, A.x_cc, A.sc_cc, A.al_cce,
                  A.c1, A.sl_cce, t4, CONC_N, lane);
    else
      c1c2_body16(A.offs1, A.srcs1, A.sl_ic, A.sr_ic, A.x_ic, A.sc_ic, A.al_ice,
                  A.c2, A.sl_ice, t4, CONC_N, lane);
  }
}

// ---- fin_k: dual(conc) only ----------------------------------------------

__global__ void fin_k(const int* offs0, const int* srcs0,
                      const float* sl_cce, const float* sr_cce, const float* c1,
                      const float* sl_ice, const float* sr_ice, const float* c2,
                      const float* conc_x, float* out_conc) {
  int t = (blockIdx.x * blockDim.x + threadIdx.x) >> 6;
  if (t >= CONC_N) return;
  gat_dual_core(offs0, srcs0, sl_cce, sr_cce, c1, sl_ice, sr_ice, c2,
                conc_x, out_conc, t, threadIdx.x & 63);
}

// ---------------- launch ----------------

extern "C" void kernel_launch(void* const* d_in, const int* in_sizes, int n_in,
                              void* d_out, int out_size, void* d_ws, size_t ws_size,
                              hipStream_t stream) {
  const float* stu_x     = (const float*)d_in[0];
  const float* item_x    = (const float*)d_in[1];
  const float* conc_x    = (const float*)d_in[2];
  const float* stu_raw_x = (const float*)d_in[3];
  const float* W_cc  = (const float*)d_in[4];
  const float* al_cc = (const float*)d_in[5];
  const float* ar_cc = (const float*)d_in[6];
  const float* W_ic  = (const float*)d_in[7];
  const float* al_ic = (const float*)d_in[8];
  const float* ar_ic = (const float*)d_in[9];
  const float* al_cce = (const float*)d_in[10];
  const float* ar_cce = (const float*)d_in[11];
  const float* al_ice = (const float*)d_in[12];
  const float* ar_ice = (const float*)d_in[13];
  const float* W_ci  = (const float*)d_in[14];
  const float* al_ci = (const float*)d_in[15];
  const float* ar_ci = (const float*)d_in[16];
  const float* W_si  = (const float*)d_in[17];
  const float* al_si = (const float*)d_in[18];
  const float* ar_si = (const float*)d_in[19];
  const float* W_is  = (const float*)d_in[22];
  const float* al_is = (const float*)d_in[23];
  const float* ar_is = (const float*)d_in[24];
  const int* cc_src  = (const int*)d_in[25];
  const int* cc_dst  = (const int*)d_in[26];
  const int* ic_item = (const int*)d_in[27];
  const int* ic_conc = (const int*)d_in[28];
  const int* si_stu  = (const int*)d_in[29];
  const int* si_item = (const int*)d_in[30];

  char* wsb = (char*)d_ws;
  size_t off = 0;
  auto alloc = [&](size_t bytes) -> void* {
    void* p = wsb + off;
    off = (off + bytes + 255) & ~(size_t)255;
    return p;
  };

  // int8 W-product tables (gather sources), 128 B/row + fp32 scale/row
  s8* concWcc = (s8*)alloc((size_t)CONC_N * 128);
  s8* itemWic = (s8*)alloc((size_t)ITEM_N * 128);
  s8* concWci = (s8*)alloc((size_t)CONC_N * 128);
  s8* stuWsi  = (s8*)alloc((size_t)STU_N  * 128);
  s8* itemWis = (s8*)alloc((size_t)ITEM_N * 128);
  float* scCcc = (float*)alloc(CONC_N * 4);
  float* scIic = (float*)alloc(ITEM_N * 4);
  float* scCci = (float*)alloc(CONC_N * 4);
  float* scSsi = (float*)alloc(STU_N * 4);
  float* scIis = (float*)alloc(ITEM_N * 4);
  ushort* Wbf[5];
  for (int i = 0; i < 5; ++i) Wbf[i] = (ushort*)alloc(128 * 128 * 2);
  float* c1buf   = (float*)alloc((size_t)CONC_N * 128 * 4);
  float* c2buf   = (float*)alloc((size_t)CONC_N * 128 * 4);
  float* vecs    = (float*)alloc(10 * 128 * 4);
  float* sl_cc  = (float*)alloc(CONC_N * 4);
  float* sr_cc  = (float*)alloc(CONC_N * 4);
  float* sl_ic  = (float*)alloc(ITEM_N * 4);
  float* sr_ic  = (float*)alloc(CONC_N * 4);
  float* sl_ci  = (float*)alloc(CONC_N * 4);
  float* sr_ci  = (float*)alloc(ITEM_N * 4);
  float* sl_si  = (float*)alloc(STU_N * 4);
  float* sr_si  = (float*)alloc(ITEM_N * 4);
  float* sl_is  = (float*)alloc(ITEM_N * 4);
  float* sr_is  = (float*)alloc(STU_N * 4);
  float* sl_cce = (float*)alloc(CONC_N * 4);
  float* sr_cce = (float*)alloc(CONC_N * 4);
  float* sl_ice = (float*)alloc(CONC_N * 4);
  float* sr_ice = (float*)alloc(CONC_N * 4);

  unsigned* keys0 = (unsigned*)alloc((size_t)NE_CC * 4);
  unsigned* keys1 = (unsigned*)alloc((size_t)NE_IC * 4);
  unsigned* keys2 = (unsigned*)alloc((size_t)NE_IC * 4);
  unsigned* keys3 = (unsigned*)alloc((size_t)NE_SI * 4);
  unsigned* keys4 = (unsigned*)alloc((size_t)NE_SI * 4);
  int* srcs0 = (int*)alloc((size_t)NE_CC * 4);
  int* srcs1 = (int*)alloc((size_t)NE_IC * 4);
  int* srcs2 = (int*)alloc((size_t)NE_IC * 4);
  int* srcs3 = (int*)alloc((size_t)NE_SI * 4);
  int* srcs4 = (int*)alloc((size_t)NE_SI * 4);
  int* offs0 = (int*)alloc((CONC_N + 1) * 4);
  int* offs1 = (int*)alloc((CONC_N + 1) * 4);
  int* offs2 = (int*)alloc((ITEM_N + 1) * 4);
  int* offs3 = (int*)alloc((ITEM_N + 1) * 4);
  int* offs4 = (int*)alloc((STU_N + 1) * 4);
  int* pcnt      = (int*)alloc(5 * 32 * 128 * 4);
  int* cur_all   = (int*)alloc(TBUCK * 4);
  int* bases_all = (int*)alloc((TBUCK + 5) * 4);

  float* out = (float*)d_out;
  float* out_conc = out;
  float* out_item = out + (size_t)CONC_N * 128;
  float* out_stu  = out + (size_t)(CONC_N + ITEM_N) * 128;

  CsrGs G;
  G.g[0] = {cc_dst,  cc_src,  keys0, srcs0, offs0, NE_CC, CONC_N, 5, 63,   0,   0};
  G.g[1] = {ic_conc, ic_item, keys1, srcs1, offs1, NE_IC, CONC_N, 5, 63,  63,  64};
  G.g[2] = {ic_item, ic_conc, keys2, srcs2, offs2, NE_IC, ITEM_N, 8, 79, 126, 128};
  G.g[3] = {si_item, si_stu,  keys3, srcs3, offs3, NE_SI, ITEM_N, 8, 79, 205, 208};
  G.g[4] = {si_stu,  si_item, keys4, srcs4, offs4, NE_SI, STU_N,  9, 98, 284, 288};

  // K1: setup (proj vectors + CSR histograms + W->frag-bf16)
  SetupArgs SA;
  SA.p[0] = {W_cc, al_cc, vecs + 0 * 128};
  SA.p[1] = {W_cc, ar_cc, vecs + 1 * 128};
  SA.p[2] = {W_ic, al_ic, vecs + 2 * 128};
  SA.p[3] = {W_ic, ar_ic, vecs + 3 * 128};
  SA.p[4] = {W_ci, al_ci, vecs + 4 * 128};
  SA.p[5] = {W_ci, ar_ci, vecs + 5 * 128};
  SA.p[6] = {W_si, al_si, vecs + 6 * 128};
  SA.p[7] = {W_si, ar_si, vecs + 7 * 128};
  SA.p[8] = {W_is, al_is, vecs + 8 * 128};
  SA.p[9] = {W_is, ar_is, vecs + 9 * 128};
  SA.G = G;
  SA.pcnt = pcnt;
  SA.wsrc[0] = W_cc; SA.wsrc[1] = W_ic; SA.wsrc[2] = W_ci;
  SA.wsrc[3] = W_si; SA.wsrc[4] = W_is;
  for (int i = 0; i < 5; ++i) SA.wdst[i] = Wbf[i];
  setup_k<<<175, 256, 0, stream>>>(SA);

  // K2: scan
  csr_scan<<<1, 512, 0, stream>>>(G, pcnt, cur_all, bases_all);

  // K3: partition (600) ∥ rdot (1024)
  mid3_k<<<600 + 1024, 256, 0, stream>>>(G, cur_all, stu_raw_x, vecs + 9 * 128,
                                         sr_is, 1024);

  // K4: build_lite (382) ∥ MFMA gemms (+fused dots, s8 output)
  BigC C;
  C.g[0] = {conc_x, concWcc, scCcc, CONC_N, 0,
            {vecs + 0 * 128, vecs + 1 * 128, vecs + 3 * 128, vecs + 4 * 128, ar_cce, ar_ice},
            {sl_cc, sr_cc, sr_ic, sl_ci, sr_cce, sr_ice}};
  C.g[1] = {item_x, itemWic, scIic, ITEM_N, 32,
            {vecs + 2 * 128, vecs + 5 * 128, vecs + 7 * 128, vecs + 8 * 128, nullptr, nullptr},
            {sl_ic, sr_ci, sr_si, sl_is, nullptr, nullptr}};
  C.g[2] = {conc_x, concWci, scCci, CONC_N, 345,
            {nullptr, nullptr, nullptr, nullptr, nullptr, nullptr},
            {nullptr, nullptr, nullptr, nullptr, nullptr, nullptr}};
  C.g[3] = {stu_x, stuWsi, scSsi, STU_N, 377,
            {vecs + 6 * 128, nullptr, nullptr, nullptr, nullptr, nullptr},
            {sl_si, nullptr, nullptr, nullptr, nullptr, nullptr}};
  C.g[4] = {item_x, itemWis, scIis, ITEM_N, 1159,
            {nullptr, nullptr, nullptr, nullptr, nullptr, nullptr},
            {nullptr, nullptr, nullptr, nullptr, nullptr, nullptr}};
  C.gemm_blocks = 1472;
  mid4_k<<<TBUCK + 1472, 256, 0, stream>>>(G, bases_all, C,
                                           Wbf[0], Wbf[1], Wbf[2], Wbf[3], Wbf[4]);

  // K5: all independent GATs in one launch (i1+i2 | s1 | c1c2), heavy first
  GatsArgs GA;
  GA.offs4 = offs4; GA.srcs4 = srcs4; GA.sl_is = sl_is; GA.sr_is = sr_is;
  GA.x_is = itemWis; GA.sc_is = scIis; GA.stu_raw_x = stu_raw_x; GA.out_stu = out_stu;
  GA.offs3 = offs3; GA.srcs3 = srcs3; GA.sl_si = sl_si; GA.sr_si = sr_si;
  GA.x_si = stuWsi; GA.sc_si = scSsi;
  GA.offs2 = offs2; GA.srcs2 = srcs2; GA.sl_ci = sl_ci; GA.sr_ci = sr_ci;
  GA.x_ci = concWci; GA.sc_ci = scCci; GA.item_x = item_x; GA.out_item = out_item;
  GA.offs0 = offs0; GA.srcs0 = srcs0; GA.sl_cc = sl_cc; GA.sr_cc = sr_cc;
  GA.x_cc = concWcc; GA.sc_cc = scCcc; GA.al_cce = al_cce; GA.c1 = c1buf; GA.sl_cce = sl_cce;
  GA.offs1 = offs1; GA.srcs1 = srcs1; GA.sl_ic = sl_ic; GA.sr_ic = sr_ic;
  GA.x_ic = itemWic; GA.sc_ic = scIic; GA.al_ice = al_ice; GA.c2 = c2buf; GA.sl_ice = sl_ice;
  gats_k<<<NB_I12 + NB_S1 + 2 * NB_CC, 256, 0, stream>>>(GA);

  // K6: dual (needs c1/c2 + their dots)
  fin_k<<<500, 256, 0, stream>>>(offs0, srcs0, sl_cce, sr_cce, c1buf,
                                 sl_ice, sr_ice, c2buf, conc_x, out_conc);
}

// Round 15
// 186.317 us; speedup vs baseline: 1.2868x; 1.0771x over previous
//
#include <hip/hip_runtime.h>

#define CONC_N 2000
#define ITEM_N 20000
#define STU_N  50000
#define NE_CC  40000
#define NE_IC  80000
#define NE_SI  1000000
#define TBUCK  382   // 63+63+79+79+98

typedef unsigned int uint;
typedef unsigned short ushort;
typedef signed char s8;
typedef __attribute__((ext_vector_type(8))) short bf16x8;
typedef __attribute__((ext_vector_type(4))) float f32x4;

__device__ __forceinline__ ushort f2bf(float f) {
  uint u = __float_as_uint(f);
  uint r = (u + 0x7FFFu + ((u >> 16) & 1u)) >> 16;
  return (ushort)r;
}

__device__ __forceinline__ bf16x8 packfrag(float4 lo, float4 hi) {
  union { bf16x8 s; uint u[4]; } p;
  p.u[0] = (uint)f2bf(lo.x) | ((uint)f2bf(lo.y) << 16);
  p.u[1] = (uint)f2bf(lo.z) | ((uint)f2bf(lo.w) << 16);
  p.u[2] = (uint)f2bf(hi.x) | ((uint)f2bf(hi.y) << 16);
  p.u[3] = (uint)f2bf(hi.z) | ((uint)f2bf(hi.w) << 16);
  return p.s;
}

// ---------------- CSR structures ----------------

struct CsrG {
  const int* dst; const int* src;
  unsigned* keys; int* srcs; int* offs;
  int E, n, shift, nbuck, tb, sb;
};
struct CsrGs { CsrG g[5]; };

// ------- setup: proj vectors (LDS-staged) + CSR histograms + W->frag-bf16 --

struct ProjDesc { const float* W; const float* a; float* out; };
struct SetupArgs {
  ProjDesc p[10];
  CsrGs G;
  int* pcnt;                 // [5*32][128]
  const float* wsrc[5];
  ushort* wdst[5];           // fragment-ordered bf16, 2048 recs x 16B
};

__global__ __launch_bounds__(256) void setup_k(SetupArgs A) {
  int b = blockIdx.x;
  int tid = threadIdx.x;
  if (b < 10) {              // proj: out = W^T a, LDS-staged coalesced
    __shared__ float Wl[128 * 132];
    __shared__ float a_s[128];
    ProjDesc d = A.p[b];
    #pragma unroll
    for (int i = 0; i < 16; ++i) {
      int s = tid + i * 256;
      int row = s >> 5, c4 = s & 31;
      float4 w = *(const float4*)&d.W[s * 4];
      float* dst = &Wl[row * 132 + c4 * 4];
      dst[0] = w.x; dst[1] = w.y; dst[2] = w.z; dst[3] = w.w;
    }
    if (tid < 128) a_s[tid] = d.a[tid];
    __syncthreads();
    if (tid < 128) {
      float acc = 0.f;
      #pragma unroll 4
      for (int j = 0; j < 128; ++j) acc += Wl[j * 132 + tid] * a_s[j];
      d.out[tid] = acc;
    }
    return;
  }
  if (b >= 170) {            // W fp32 -> fragment-ordered bf16
    int wi = b - 170;
    const float* Ws = A.wsrc[wi];
    ushort* Wd = A.wdst[wi];
    for (int rec = tid; rec < 2048; rec += 256) {
      int lane = rec & 63;
      int kk = (rec >> 6) & 3;
      int nt = rec >> 8;
      int x = lane & 15, g = lane >> 4;
      const float* src = &Ws[(nt * 16 + x) * 128 + kk * 32 + 4 * g];
      float4 lo = *(const float4*)src;
      float4 hi = *(const float4*)(src + 16);
      bf16x8 pk = packfrag(lo, hi);
      *(bf16x8*)&Wd[rec * 8] = pk;
    }
    return;
  }
  int bsel = b - 10;            // 0..159: histogram
  int gi = bsel >> 5, blk = bsel & 31;
  CsrG g = A.G.g[gi];
  __shared__ int lcnt[128];
  if (tid < 128) lcnt[tid] = 0;
  __syncthreads();
  int chunk = (g.E + 31) >> 5;
  int e0 = blk * chunk, e1 = min(g.E, e0 + chunk);
  for (int e = e0 + tid; e < e1; e += 256)
    atomicAdd(&lcnt[g.dst[e] >> g.shift], 1);
  __syncthreads();
  if (tid < 128) A.pcnt[bsel * 128 + tid] = lcnt[tid];
}

// ---------------- CSR scan ----------------

__global__ __launch_bounds__(512) void csr_scan(CsrGs G, const int* __restrict__ pcnt,
                                                int* __restrict__ cur, int* __restrict__ bases) {
  __shared__ int lc[TBUCK];
  __shared__ int lb[TBUCK + 5];
  int tid = threadIdx.x, lane = tid & 63, wv = tid >> 6;
  if (tid < TBUCK) {
    int gi = 0;
    #pragma unroll
    for (int k = 1; k < 5; ++k) if (tid >= G.g[k].tb) gi = k;
    int b = tid - G.g[gi].tb;
    int s = 0;
    for (int blk = 0; blk < 32; ++blk) s += pcnt[((gi << 5) + blk) * 128 + b];
    lc[tid] = s;
  }
  __syncthreads();
  if (wv < 5) {
    CsrG g = G.g[wv];
    int carry = 0;
    for (int base = 0; base < g.nbuck; base += 64) {
      int idx = base + lane;
      int v = (idx < g.nbuck) ? lc[g.tb + idx] : 0;
      int incl = v;
      #pragma unroll
      for (int o = 1; o < 64; o <<= 1) {
        int y = __shfl_up(incl, o);
        if (lane >= o) incl += y;
      }
      if (idx < g.nbuck) lb[g.sb + idx] = carry + incl - v;
      carry += __shfl(incl, 63);
    }
    if (lane == 0) lb[g.sb + g.nbuck] = carry;
  }
  __syncthreads();
  if (tid < TBUCK + 5) bases[tid] = lb[tid];
  if (tid < TBUCK) {
    int gi = 0;
    for (int k = 1; k < 5; ++k) if (tid >= G.g[k].tb) gi = k;
    cur[tid] = lb[tid + gi];
  }
  if (tid < 5) G.g[tid].offs[G.g[tid].n] = G.g[tid].E;
}

// ------------- mid3_k: csr_partition (600 blks) ∥ rdot (1024 blks) --------

__device__ void partition_body(const CsrGs& G, int* __restrict__ cur, int gi, int bx,
                               int nbx, unsigned char* smem) {
  CsrG g = G.g[gi];
  unsigned* ck = (unsigned*)smem;                 // 16384 B
  unsigned char* cb = smem + 16384;               // 4096 B
  int* lcnt = (int*)(smem + 20480);               // 512 B
  int* lcur = (int*)(smem + 20992);               // 512 B
  int tid = threadIdx.x;
  unsigned dmask = (1u << g.shift) - 1;
  for (int c0 = bx * 4096; c0 < g.E; c0 += nbx * 4096) {
    if (tid < 128) lcnt[tid] = 0;
    __syncthreads();
    #pragma unroll
    for (int i = 0; i < 16; ++i) {
      int e = c0 + i * 256 + tid;
      if (e < g.E) {
        int d = g.dst[e], s = g.src[e];
        int b = d >> g.shift;
        ck[i * 256 + tid] = ((unsigned)(d & dmask) << 16) | (unsigned)s;
        cb[i * 256 + tid] = (unsigned char)b;
        atomicAdd(&lcnt[b], 1);
      } else cb[i * 256 + tid] = 255;
    }
    __syncthreads();
    if (tid < g.nbuck && lcnt[tid] > 0) lcur[tid] = atomicAdd(&cur[g.tb + tid], lcnt[tid]);
    __syncthreads();
    #pragma unroll
    for (int i = 0; i < 16; ++i) {
      int b = cb[i * 256 + tid];
      if (b != 255) {
        int pos = atomicAdd(&lcur[b], 1);
        g.keys[pos] = ck[i * 256 + tid];
      }
    }
    __syncthreads();
  }
}

__device__ void rdot_body(const float* __restrict__ x, const float* __restrict__ v,
                          float* __restrict__ o, int n, int blk, int nblk) {
  int lane = threadIdx.x & 63;
  int wid = (blk * 256 + threadIdx.x) >> 6;
  int nw = nblk * 4;
  float va = v[lane], vb = v[64 + lane];
  for (int r = wid; r < n; r += nw) {
    float a = x[r * 128 + lane] * va + x[r * 128 + 64 + lane] * vb;
    #pragma unroll
    for (int of = 32; of; of >>= 1) a += __shfl_xor(a, of);
    if (lane == 0) o[r] = a;
  }
}

__global__ __launch_bounds__(256) void mid3_k(CsrGs G, int* cur,
                                              const float* rx, const float* rv,
                                              float* ro, int rnb) {
  __shared__ __align__(16) unsigned char smem[21504];
  int b = blockIdx.x;
  if (b < 600) {
    partition_body(G, cur, b / 120, b % 120, 120, smem);
  } else {
    rdot_body(rx, rv, ro, STU_N, b - 600, rnb);
  }
}

// ------------- mid4_k: build_lite (382 blks) ∥ MFMA GEMMs -----------------

struct GemmDesc { const float* X; s8* Y8; float* S; int n, b0;
                  const float* dv[6]; float* dq[6]; };
struct BigC {
  GemmDesc g[5];
  int gemm_blocks;
};

__device__ void build_lite(const CsrGs& G, const int* __restrict__ bases, int bid,
                           int* lh, int* lex, int* lcu, int* wsum) {
  int gi = 0;
  for (int k = 1; k < 5; ++k) if (bid >= G.g[k].tb) gi = k;
  CsrG g = G.g[gi];
  int b = bid - g.tb;
  int base = bases[g.sb + b];
  int cnt = bases[g.sb + b + 1] - base;

  int tid = threadIdx.x;
  lh[tid] = 0; lh[tid + 256] = 0;
  __syncthreads();
  for (int j = tid; j < cnt; j += 256)
    atomicAdd(&lh[g.keys[base + j] >> 16], 1);
  __syncthreads();
  int a0 = lh[2 * tid], a1 = lh[2 * tid + 1];
  int pair = a0 + a1;
  int lane = tid & 63, wv = tid >> 6;
  int incl = pair;
  #pragma unroll
  for (int o = 1; o < 64; o <<= 1) {
    int y = __shfl_up(incl, o);
    if (lane >= o) incl += y;
  }
  if (lane == 63) wsum[wv] = incl;
  __syncthreads();
  if (tid == 0) {
    int s = 0;
    #pragma unroll
    for (int w = 0; w < 4; ++w) { int t = wsum[w]; wsum[w] = s; s += t; }
  }
  __syncthreads();
  int ep = wsum[wv] + incl - pair;
  lex[2 * tid] = ep;       lex[2 * tid + 1] = ep + a0;
  lcu[2 * tid] = ep;       lcu[2 * tid + 1] = ep + a0;
  __syncthreads();
  int dst0 = b << g.shift;
  int ndst = min(1 << g.shift, g.n - dst0);
  for (int dl = tid; dl < ndst; dl += 256) g.offs[dst0 + dl] = base + lex[dl];
  for (int j = tid; j < cnt; j += 256) {
    unsigned k = g.keys[base + j];
    int dl = k >> 16;
    int pos = atomicAdd(&lcu[dl], 1);
    g.srcs[base + pos] = (int)(k & 0xFFFFu);
  }
}

template <int NV>
__device__ void gemm_bodyT(const GemmDesc& gd, const ushort* __restrict__ Wf, int blk) {
  int tid = threadIdx.x;
  int lane = tid & 63, wv = tid >> 6;
  int x = lane & 15, g = lane >> 4;
  int row = blk * 64 + wv * 16 + x;
  const float* xr = &gd.X[(size_t)(row < gd.n ? row : 0) * 128];
  bf16x8 afrag[4];
  float dacc[NV == 0 ? 1 : NV];
  #pragma unroll
  for (int v = 0; v < NV; ++v) dacc[v] = 0.f;
  #pragma unroll
  for (int kk = 0; kk < 4; ++kk) {
    float4 lo = *(const float4*)&xr[kk * 32 + 4 * g];
    float4 hi = *(const float4*)&xr[kk * 32 + 16 + 4 * g];
    afrag[kk] = packfrag(lo, hi);
    #pragma unroll
    for (int v = 0; v < NV; ++v) {
      const float* vp = gd.dv[v];
      float4 vlo = *(const float4*)&vp[kk * 32 + 4 * g];
      float4 vhi = *(const float4*)&vp[kk * 32 + 16 + 4 * g];
      dacc[v] += lo.x * vlo.x + lo.y * vlo.y + lo.z * vlo.z + lo.w * vlo.w
               + hi.x * vhi.x + hi.y * vhi.y + hi.z * vhi.z + hi.w * vhi.w;
    }
  }
  #pragma unroll
  for (int v = 0; v < NV; ++v) {
    float dsum = dacc[v];
    dsum += __shfl_xor(dsum, 16);
    dsum += __shfl_xor(dsum, 32);
    if (lane < 16 && row < gd.n) gd.dq[v][row] = dsum;
  }
  f32x4 acc[8];
  #pragma unroll
  for (int t = 0; t < 8; ++t) acc[t] = (f32x4){0.f, 0.f, 0.f, 0.f};
  #pragma unroll
  for (int nt = 0; nt < 8; ++nt) {
    #pragma unroll
    for (int kk = 0; kk < 4; ++kk) {
      union { uint4 u; bf16x8 s; } bu;
      bu.u = *(const uint4*)&Wf[(size_t)((nt * 4 + kk) * 64 + lane) * 8];
      acc[nt] = __builtin_amdgcn_mfma_f32_16x16x32_bf16(afrag[kk], bu.s, acc[nt], 0, 0, 0);
    }
  }
  // D layout: col = lane&15, row = (lane>>4)*4 + r. Quantize per row to s8.
  int orow = blk * 64 + wv * 16 + 4 * g;
  #pragma unroll
  for (int r = 0; r < 4; ++r) {
    float m8 = 0.f;
    #pragma unroll
    for (int nt = 0; nt < 8; ++nt) m8 = fmaxf(m8, fabsf(acc[nt][r]));
    #pragma unroll
    for (int msk = 1; msk < 16; msk <<= 1) m8 = fmaxf(m8, __shfl_xor(m8, msk));
    int gr = orow + r;
    if (gr < gd.n) {
      float invs = (m8 > 0.f) ? 127.f / m8 : 0.f;
      if (x == 0) gd.S[gr] = m8 * (1.f / 127.f);
      #pragma unroll
      for (int nt = 0; nt < 8; ++nt) {
        int q = (int)rintf(acc[nt][r] * invs);
        gd.Y8[(size_t)gr * 128 + nt * 16 + x] = (s8)q;
      }
    }
  }
}

__global__ __launch_bounds__(256, 2) void mid4_k(CsrGs G, const int* bases, BigC C,
                                                 const ushort* W0, const ushort* W1,
                                                 const ushort* W2, const ushort* W3,
                                                 const ushort* W4) {
  __shared__ int lh[512], lex[512], lcu[512], wsum[4];
  int b = blockIdx.x;
  if (b < TBUCK) {
    build_lite(G, bases, b, lh, lex, lcu, wsum);
    return;
  }
  b -= TBUCK;
  if (b < C.g[1].b0)      gemm_bodyT<6>(C.g[0], W0, b - C.g[0].b0);
  else if (b < C.g[2].b0) gemm_bodyT<4>(C.g[1], W1, b - C.g[1].b0);
  else if (b < C.g[3].b0) gemm_bodyT<0>(C.g[2], W2, b - C.g[2].b0);
  else if (b < C.g[4].b0) gemm_bodyT<1>(C.g[3], W3, b - C.g[3].b0);
  else                    gemm_bodyT<0>(C.g[4], W4, b - C.g[4].b0);
}

// ---------------- GAT core: 16-lane group per target, int8 gather ---------

__device__ __forceinline__ void fma8q(float acc[8], float wj, uint2 u) {
  int lo = (int)u.x, hi = (int)u.y;
  acc[0] += wj * (float)((lo << 24) >> 24);
  acc[1] += wj * (float)((lo << 16) >> 24);
  acc[2] += wj * (float)((lo << 8) >> 24);
  acc[3] += wj * (float)(lo >> 24);
  acc[4] += wj * (float)((hi << 24) >> 24);
  acc[5] += wj * (float)((hi << 16) >> 24);
  acc[6] += wj * (float)((hi << 8) >> 24);
  acc[7] += wj * (float)(hi >> 24);
}

// t = t4 + (lane>>4); lane il = lane&15 owns dims il*8..il*8+7 (s8 codes).
// 4-deep load batching: all 4 uint2 gathers issued before the 32 FMAs.
__device__ void gat_core16(const int* __restrict__ offs, const int* __restrict__ srcs,
                           const float* __restrict__ sl, const float* __restrict__ sr,
                           const s8* __restrict__ x8, const float* __restrict__ sc,
                           int t4, int n_tgt, int lane, float acc[8]) {
  int q = lane >> 4, il = lane & 15;
  int t = t4 + q;
  bool tv = t < n_tgt;
  int sbeg = tv ? offs[t] : 0;
  int send = tv ? offs[t + 1] : 0;
  float srt = tv ? sr[t] : 0.f;

  int i0l = sbeg + il;
  bool act0 = i0l < send;
  int s0 = act0 ? srcs[i0l] : 0;
  float sc0 = act0 ? sc[s0] : 0.f;
  float e0;
  {
    float e = sl[s0] + srt;
    e = e > 0.f ? e : 0.2f * e;
    e0 = act0 ? e : -1e30f;
  }
  float m = e0, se = act0 ? 1.f : 0.f;
  for (int i = i0l + 16; i < send; i += 16) {
    int s = srcs[i];
    float e = sl[s] + srt;
    e = e > 0.f ? e : 0.2f * e;
    float mn = fmaxf(m, e);
    se = se * __expf(m - mn) + __expf(e - mn);
    m = mn;
  }
  #pragma unroll
  for (int o = 8; o; o >>= 1) {
    float m2 = __shfl_xor(m, o), s2 = __shfl_xor(se, o);
    float mn = fmaxf(m, m2);
    se = se * __expf(m - mn) + s2 * __expf(m2 - mn);
    m = mn;
  }
  float inv = 1.f / (se + 1e-16f);

  #pragma unroll
  for (int r = 0; r < 8; ++r) acc[r] = 0.f;

  int qb = q << 4;
  for (int i0 = sbeg; i0 < send; i0 += 16) {
    int cnt = min(16, send - i0);
    int s; float wgt;
    if (i0 == sbeg) {
      s = s0;
      wgt = act0 ? __expf(e0 - m) * inv * sc0 : 0.f;
    } else {
      s = 0; wgt = 0.f;
      if (il < cnt) {
        s = srcs[i0 + il];
        float e = sl[s] + srt;
        e = e > 0.f ? e : 0.2f * e;
        wgt = __expf(e - m) * inv * sc[s];
      }
    }
    int j = 0;
    for (; j + 4 <= cnt; j += 4) {
      int sj0 = __shfl(s, qb + j);
      int sj1 = __shfl(s, qb + j + 1);
      int sj2 = __shfl(s, qb + j + 2);
      int sj3 = __shfl(s, qb + j + 3);
      float wj0 = __shfl(wgt, qb + j);
      float wj1 = __shfl(wgt, qb + j + 1);
      float wj2 = __shfl(wgt, qb + j + 2);
      float wj3 = __shfl(wgt, qb + j + 3);
      uint2 u0 = *(const uint2*)&x8[(size_t)sj0 * 128 + il * 8];
      uint2 u1 = *(const uint2*)&x8[(size_t)sj1 * 128 + il * 8];
      uint2 u2 = *(const uint2*)&x8[(size_t)sj2 * 128 + il * 8];
      uint2 u3 = *(const uint2*)&x8[(size_t)sj3 * 128 + il * 8];
      fma8q(acc, wj0, u0);
      fma8q(acc, wj1, u1);
      fma8q(acc, wj2, u2);
      fma8q(acc, wj3, u3);
    }
    for (; j < cnt; ++j) {
      int sj = __shfl(s, qb + j);
      float wj = __shfl(wgt, qb + j);
      uint2 u = *(const uint2*)&x8[(size_t)sj * 128 + il * 8];
      fma8q(acc, wj, u);
    }
  }
}

__device__ __forceinline__ void gat_store16(const float acc[8], const float* base0,
                                            float* out, int t4, int n_tgt, int lane) {
  int q = lane >> 4, il = lane & 15;
  int t = t4 + q;
  if (t >= n_tgt) return;
  int d = t * 128 + il * 8;
  float4 a0 = make_float4(acc[0], acc[1], acc[2], acc[3]);
  float4 a1 = make_float4(acc[4], acc[5], acc[6], acc[7]);
  if (base0) {
    const float4 b0 = *(const float4*)&base0[d];
    const float4 b1 = *(const float4*)&base0[d + 4];
    a0.x += b0.x; a0.y += b0.y; a0.z += b0.z; a0.w += b0.w;
    a1.x += b1.x; a1.y += b1.y; a1.z += b1.z; a1.w += b1.w;
  }
  *(float4*)&out[d] = a0;
  *(float4*)&out[d + 4] = a1;
}

__device__ void c1c2_body16(const int* offs, const int* srcs, const float* sl,
                            const float* sr, const s8* x8, const float* sc,
                            const float* al, float* o, float* slo,
                            int t4, int n_tgt, int lane) {
  float acc[8];
  gat_core16(offs, srcs, sl, sr, x8, sc, t4, n_tgt, lane, acc);
  int q = lane >> 4, il = lane & 15;
  int t = t4 + q;
  float4 v0 = *(const float4*)&al[il * 8];
  float4 v1 = *(const float4*)&al[il * 8 + 4];
  float p = acc[0] * v0.x + acc[1] * v0.y + acc[2] * v0.z + acc[3] * v0.w +
            acc[4] * v1.x + acc[5] * v1.y + acc[6] * v1.z + acc[7] * v1.w;
  #pragma unroll
  for (int o2 = 8; o2; o2 >>= 1) p += __shfl_xor(p, o2);
  if (t < n_tgt) {
    if (il == 0) slo[t] = p;
    int d = t * 128 + il * 8;
    *(float4*)&o[d] = make_float4(acc[0], acc[1], acc[2], acc[3]);
    *(float4*)&o[d + 4] = make_float4(acc[4], acc[5], acc[6], acc[7]);
  }
}

// dual (fp32 gather of c1/c2 on cc graph), wave per target (small)
__device__ void gat_dual_core(const int* __restrict__ offs, const int* __restrict__ srcs,
                              const float* __restrict__ sl1, const float* __restrict__ sr1,
                              const float* __restrict__ xl1,
                              const float* __restrict__ sl2, const float* __restrict__ sr2,
                              const float* __restrict__ xl2,
                              const float* __restrict__ base,
                              float* __restrict__ out, int t, int lane) {
  int sbeg = offs[t], send = offs[t + 1];
  float srt1 = sr1[t], srt2 = sr2[t];
  float m1 = -1e30f, m2 = -1e30f;
  for (int i = sbeg + lane; i < send; i += 64) {
    int s = srcs[i];
    float e1 = sl1[s] + srt1; e1 = e1 > 0.f ? e1 : 0.2f * e1;
    float e2 = sl2[s] + srt2; e2 = e2 > 0.f ? e2 : 0.2f * e2;
    m1 = fmaxf(m1, e1); m2 = fmaxf(m2, e2);
  }
  #pragma unroll
  for (int o = 32; o; o >>= 1) {
    m1 = fmaxf(m1, __shfl_xor(m1, o));
    m2 = fmaxf(m2, __shfl_xor(m2, o));
  }
  float se1 = 0.f, se2 = 0.f;
  for (int i = sbeg + lane; i < send; i += 64) {
    int s = srcs[i];
    float e1 = sl1[s] + srt1; e1 = e1 > 0.f ? e1 : 0.2f * e1;
    float e2 = sl2[s] + srt2; e2 = e2 > 0.f ? e2 : 0.2f * e2;
    se1 += __expf(e1 - m1); se2 += __expf(e2 - m2);
  }
  #pragma unroll
  for (int o = 32; o; o >>= 1) {
    se1 += __shfl_xor(se1, o);
    se2 += __shfl_xor(se2, o);
  }
  float inv1 = 1.f / (se1 + 1e-16f), inv2 = 1.f / (se2 + 1e-16f);
  float ax = 0.f, ay = 0.f;
  for (int i0 = sbeg; i0 < send; i0 += 64) {
    int cnt = min(64, send - i0);
    int s = 0; float w1 = 0.f, w2 = 0.f;
    if (lane < cnt) {
      s = srcs[i0 + lane];
      float e1 = sl1[s] + srt1; e1 = e1 > 0.f ? e1 : 0.2f * e1;
      float e2 = sl2[s] + srt2; e2 = e2 > 0.f ? e2 : 0.2f * e2;
      w1 = __expf(e1 - m1) * inv1;
      w2 = __expf(e2 - m2) * inv2;
    }
    for (int j = 0; j < cnt; ++j) {
      int sj = __shfl(s, j);
      float wj1 = __shfl(w1, j);
      float wj2 = __shfl(w2, j);
      const float2 v1 = *(const float2*)&xl1[sj * 128 + lane * 2];
      const float2 v2 = *(const float2*)&xl2[sj * 128 + lane * 2];
      ax += wj1 * v1.x + wj2 * v2.x;
      ay += wj1 * v1.y + wj2 * v2.y;
    }
  }
  const float2 b = *(const float2*)&base[t * 128 + lane * 2];
  float2 o2; o2.x = ax + b.x; o2.y = ay + b.y;
  *(float2*)&out[t * 128 + lane * 2] = o2;
}

// ---- gats_k: [i1+i2 merged | s1 | c1c2], heavy blocks first ---------------

#define NB_I12 1250   // ceil(20000/16)
#define NB_S1  3125   // ceil(50000/16)
#define NB_CC  125    // ceil(2000/16)

struct GatsArgs {
  const int *offs4, *srcs4; const float *sl_is, *sr_is; const s8* x_is; const float* sc_is;
  const float* stu_raw_x; float* out_stu;
  const int *offs3, *srcs3; const float *sl_si, *sr_si; const s8* x_si; const float* sc_si;
  const int *offs2, *srcs2; const float *sl_ci, *sr_ci; const s8* x_ci; const float* sc_ci;
  const float* item_x; float* out_item;
  const int *offs0, *srcs0; const float *sl_cc, *sr_cc; const s8* x_cc; const float* sc_cc;
  const float* al_cce; float *c1, *sl_cce;
  const int *offs1, *srcs1; const float *sl_ic, *sr_ic; const s8* x_ic; const float* sc_ic;
  const float* al_ice; float *c2, *sl_ice;
};

__global__ void gats_k(GatsArgs A) {
  int b = blockIdx.x;
  int lane = threadIdx.x & 63;
  int wv = threadIdx.x >> 6;
  if (b < NB_I12) {
    int t4 = b * 16 + wv * 4;
    float acc1[8], acc2[8];
    gat_core16(A.offs2, A.srcs2, A.sl_ci, A.sr_ci, A.x_ci, A.sc_ci, t4, ITEM_N, lane, acc1);
    gat_core16(A.offs3, A.srcs3, A.sl_si, A.sr_si, A.x_si, A.sc_si, t4, ITEM_N, lane, acc2);
    #pragma unroll
    for (int r = 0; r < 8; ++r) acc1[r] += acc2[r];
    gat_store16(acc1, A.item_x, A.out_item, t4, ITEM_N, lane);
  } else if (b < NB_I12 + NB_S1) {
    int t4 = (b - NB_I12) * 16 + wv * 4;
    float acc[8];
    gat_core16(A.offs4, A.srcs4, A.sl_is, A.sr_is, A.x_is, A.sc_is, t4, STU_N, lane, acc);
    gat_store16(acc, A.stu_raw_x, A.out_stu, t4, STU_N, lane);
  } else {
    int sub = b - NB_I12 - NB_S1;   // 0..2*NB_CC-1
    int which = sub >= NB_CC;
    int t4 = (sub - which * NB_CC) * 16 + wv * 4;
    if (!which)
      c1c2_body16(A.offs0, A.srcs0, A.sl_cc, A.sr_cc, A.x_cc, A.sc_cc, A.al_cce,
                  A.c1, A.sl_cce, t4, CONC_N, lane);
    else
      c1c2_body16(A.offs1, A.srcs1, A.sl_ic, A.sr_ic, A.x_ic, A.sc_ic, A.al_ice,
                  A.c2, A.sl_ice, t4, CONC_N, lane);
  }
}

// ---- fin_k: dual(conc) only ----------------------------------------------

__global__ void fin_k(const int* offs0, const int* srcs0,
                      const float* sl_cce, const float* sr_cce, const float* c1,
                      const float* sl_ice, const float* sr_ice, const float* c2,
                      const float* conc_x, float* out_conc) {
  int t = (blockIdx.x * blockDim.x + threadIdx.x) >> 6;
  if (t >= CONC_N) return;
  gat_dual_core(offs0, srcs0, sl_cce, sr_cce, c1, sl_ice, sr_ice, c2,
                conc_x, out_conc, t, threadIdx.x & 63);
}

// ---------------- launch ----------------

extern "C" void kernel_launch(void* const* d_in, const int* in_sizes, int n_in,
                              void* d_out, int out_size, void* d_ws, size_t ws_size,
                              hipStream_t stream) {
  const float* stu_x     = (const float*)d_in[0];
  const float* item_x    = (const float*)d_in[1];
  const float* conc_x    = (const float*)d_in[2];
  const float* stu_raw_x = (const float*)d_in[3];
  const float* W_cc  = (const float*)d_in[4];
  const float* al_cc = (const float*)d_in[5];
  const float* ar_cc = (const float*)d_in[6];
  const float* W_ic  = (const float*)d_in[7];
  const float* al_ic = (const float*)d_in[8];
  const float* ar_ic = (const float*)d_in[9];
  const float* al_cce = (const float*)d_in[10];
  const float* ar_cce = (const float*)d_in[11];
  const float* al_ice = (const float*)d_in[12];
  const float* ar_ice = (const float*)d_in[13];
  const float* W_ci  = (const float*)d_in[14];
  const float* al_ci = (const float*)d_in[15];
  const float* ar_ci = (const float*)d_in[16];
  const float* W_si  = (const float*)d_in[17];
  const float* al_si = (const float*)d_in[18];
  const float* ar_si = (const float*)d_in[19];
  const float* W_is  = (const float*)d_in[22];
  const float* al_is = (const float*)d_in[23];
  const float* ar_is = (const float*)d_in[24];
  const int* cc_src  = (const int*)d_in[25];
  const int* cc_dst  = (const int*)d_in[26];
  const int* ic_item = (const int*)d_in[27];
  const int* ic_conc = (const int*)d_in[28];
  const int* si_stu  = (const int*)d_in[29];
  const int* si_item = (const int*)d_in[30];

  char* wsb = (char*)d_ws;
  size_t off = 0;
  auto alloc = [&](size_t bytes) -> void* {
    void* p = wsb + off;
    off = (off + bytes + 255) & ~(size_t)255;
    return p;
  };

  // int8 W-product tables (gather sources), 128 B/row + fp32 scale/row
  s8* concWcc = (s8*)alloc((size_t)CONC_N * 128);
  s8* itemWic = (s8*)alloc((size_t)ITEM_N * 128);
  s8* concWci = (s8*)alloc((size_t)CONC_N * 128);
  s8* stuWsi  = (s8*)alloc((size_t)STU_N  * 128);
  s8* itemWis = (s8*)alloc((size_t)ITEM_N * 128);
  float* scCcc = (float*)alloc(CONC_N * 4);
  float* scIic = (float*)alloc(ITEM_N * 4);
  float* scCci = (float*)alloc(CONC_N * 4);
  float* scSsi = (float*)alloc(STU_N * 4);
  float* scIis = (float*)alloc(ITEM_N * 4);
  ushort* Wbf[5];
  for (int i = 0; i < 5; ++i) Wbf[i] = (ushort*)alloc(128 * 128 * 2);
  float* c1buf   = (float*)alloc((size_t)CONC_N * 128 * 4);
  float* c2buf   = (float*)alloc((size_t)CONC_N * 128 * 4);
  float* vecs    = (float*)alloc(10 * 128 * 4);
  float* sl_cc  = (float*)alloc(CONC_N * 4);
  float* sr_cc  = (float*)alloc(CONC_N * 4);
  float* sl_ic  = (float*)alloc(ITEM_N * 4);
  float* sr_ic  = (float*)alloc(CONC_N * 4);
  float* sl_ci  = (float*)alloc(CONC_N * 4);
  float* sr_ci  = (float*)alloc(ITEM_N * 4);
  float* sl_si  = (float*)alloc(STU_N * 4);
  float* sr_si  = (float*)alloc(ITEM_N * 4);
  float* sl_is  = (float*)alloc(ITEM_N * 4);
  float* sr_is  = (float*)alloc(STU_N * 4);
  float* sl_cce = (float*)alloc(CONC_N * 4);
  float* sr_cce = (float*)alloc(CONC_N * 4);
  float* sl_ice = (float*)alloc(CONC_N * 4);
  float* sr_ice = (float*)alloc(CONC_N * 4);

  unsigned* keys0 = (unsigned*)alloc((size_t)NE_CC * 4);
  unsigned* keys1 = (unsigned*)alloc((size_t)NE_IC * 4);
  unsigned* keys2 = (unsigned*)alloc((size_t)NE_IC * 4);
  unsigned* keys3 = (unsigned*)alloc((size_t)NE_SI * 4);
  unsigned* keys4 = (unsigned*)alloc((size_t)NE_SI * 4);
  int* srcs0 = (int*)alloc((size_t)NE_CC * 4);
  int* srcs1 = (int*)alloc((size_t)NE_IC * 4);
  int* srcs2 = (int*)alloc((size_t)NE_IC * 4);
  int* srcs3 = (int*)alloc((size_t)NE_SI * 4);
  int* srcs4 = (int*)alloc((size_t)NE_SI * 4);
  int* offs0 = (int*)alloc((CONC_N + 1) * 4);
  int* offs1 = (int*)alloc((CONC_N + 1) * 4);
  int* offs2 = (int*)alloc((ITEM_N + 1) * 4);
  int* offs3 = (int*)alloc((ITEM_N + 1) * 4);
  int* offs4 = (int*)alloc((STU_N + 1) * 4);
  int* pcnt      = (int*)alloc(5 * 32 * 128 * 4);
  int* cur_all   = (int*)alloc(TBUCK * 4);
  int* bases_all = (int*)alloc((TBUCK + 5) * 4);

  float* out = (float*)d_out;
  float* out_conc = out;
  float* out_item = out + (size_t)CONC_N * 128;
  float* out_stu  = out + (size_t)(CONC_N + ITEM_N) * 128;

  CsrGs G;
  G.g[0] = {cc_dst,  cc_src,  keys0, srcs0, offs0, NE_CC, CONC_N, 5, 63,   0,   0};
  G.g[1] = {ic_conc, ic_item, keys1, srcs1, offs1, NE_IC, CONC_N, 5, 63,  63,  64};
  G.g[2] = {ic_item, ic_conc, keys2, srcs2, offs2, NE_IC, ITEM_N, 8, 79, 126, 128};
  G.g[3] = {si_item, si_stu,  keys3, srcs3, offs3, NE_SI, ITEM_N, 8, 79, 205, 208};
  G.g[4] = {si_stu,  si_item, keys4, srcs4, offs4, NE_SI, STU_N,  9, 98, 284, 288};

  // K1: setup (proj vectors + CSR histograms + W->frag-bf16)
  SetupArgs SA;
  SA.p[0] = {W_cc, al_cc, vecs + 0 * 128};
  SA.p[1] = {W_cc, ar_cc, vecs + 1 * 128};
  SA.p[2] = {W_ic, al_ic, vecs + 2 * 128};
  SA.p[3] = {W_ic, ar_ic, vecs + 3 * 128};
  SA.p[4] = {W_ci, al_ci, vecs + 4 * 128};
  SA.p[5] = {W_ci, ar_ci, vecs + 5 * 128};
  SA.p[6] = {W_si, al_si, vecs + 6 * 128};
  SA.p[7] = {W_si, ar_si, vecs + 7 * 128};
  SA.p[8] = {W_is, al_is, vecs + 8 * 128};
  SA.p[9] = {W_is, ar_is, vecs + 9 * 128};
  SA.G = G;
  SA.pcnt = pcnt;
  SA.wsrc[0] = W_cc; SA.wsrc[1] = W_ic; SA.wsrc[2] = W_ci;
  SA.wsrc[3] = W_si; SA.wsrc[4] = W_is;
  for (int i = 0; i < 5; ++i) SA.wdst[i] = Wbf[i];
  setup_k<<<175, 256, 0, stream>>>(SA);

  // K2: scan
  csr_scan<<<1, 512, 0, stream>>>(G, pcnt, cur_all, bases_all);

  // K3: partition (600) ∥ rdot (1024)
  mid3_k<<<600 + 1024, 256, 0, stream>>>(G, cur_all, stu_raw_x, vecs + 9 * 128,
                                         sr_is, 1024);

  // K4: build_lite (382) ∥ MFMA gemms (+fused dots, s8 output)
  BigC C;
  C.g[0] = {conc_x, concWcc, scCcc, CONC_N, 0,
            {vecs + 0 * 128, vecs + 1 * 128, vecs + 3 * 128, vecs + 4 * 128, ar_cce, ar_ice},
            {sl_cc, sr_cc, sr_ic, sl_ci, sr_cce, sr_ice}};
  C.g[1] = {item_x, itemWic, scIic, ITEM_N, 32,
            {vecs + 2 * 128, vecs + 5 * 128, vecs + 7 * 128, vecs + 8 * 128, nullptr, nullptr},
            {sl_ic, sr_ci, sr_si, sl_is, nullptr, nullptr}};
  C.g[2] = {conc_x, concWci, scCci, CONC_N, 345,
            {nullptr, nullptr, nullptr, nullptr, nullptr, nullptr},
            {nullptr, nullptr, nullptr, nullptr, nullptr, nullptr}};
  C.g[3] = {stu_x, stuWsi, scSsi, STU_N, 377,
            {vecs + 6 * 128, nullptr, nullptr, nullptr, nullptr, nullptr},
            {sl_si, nullptr, nullptr, nullptr, nullptr, nullptr}};
  C.g[4] = {item_x, itemWis, scIis, ITEM_N, 1159,
            {nullptr, nullptr, nullptr, nullptr, nullptr, nullptr},
            {nullptr, nullptr, nullptr, nullptr, nullptr, nullptr}};
  C.gemm_blocks = 1472;
  mid4_k<<<TBUCK + 1472, 256, 0, stream>>>(G, bases_all, C,
                                           Wbf[0], Wbf[1], Wbf[2], Wbf[3], Wbf[4]);

  // K5: all independent GATs in one launch (i1+i2 | s1 | c1c2), heavy first
  GatsArgs GA;
  GA.offs4 = offs4; GA.srcs4 = srcs4; GA.sl_is = sl_is; GA.sr_is = sr_is;
  GA.x_is = itemWis; GA.sc_is = scIis; GA.stu_raw_x = stu_raw_x; GA.out_stu = out_stu;
  GA.offs3 = offs3; GA.srcs3 = srcs3; GA.sl_si = sl_si; GA.sr_si = sr_si;
  GA.x_si = stuWsi; GA.sc_si = scSsi;
  GA.offs2 = offs2; GA.srcs2 = srcs2; GA.sl_ci = sl_ci; GA.sr_ci = sr_ci;
  GA.x_ci = concWci; GA.sc_ci = scCci; GA.item_x = item_x; GA.out_item = out_item;
  GA.offs0 = offs0; GA.srcs0 = srcs0; GA.sl_cc = sl_cc; GA.sr_cc = sr_cc;
  GA.x_cc = concWcc; GA.sc_cc = scCcc; GA.al_cce = al_cce; GA.c1 = c1buf; GA.sl_cce = sl_cce;
  GA.offs1 = offs1; GA.srcs1 = srcs1; GA.sl_ic = sl_ic; GA.sr_ic = sr_ic;
  GA.x_ic = itemWic; GA.sc_ic = scIic; GA.al_ice = al_ice; GA.c2 = c2buf; GA.sl_ice = sl_ice;
  gats_k<<<NB_I12 + NB_S1 + 2 * NB_CC, 256, 0, stream>>>(GA);

  // K6: dual (needs c1/c2 + their dots)
  fin_k<<<500, 256, 0, stream>>>(offs0, srcs0, sl_cce, sr_cce, c1buf,
                                 sl_ice, sr_ice, c2buf, conc_x, out_conc);
}

// Round 16
// 183.039 us; speedup vs baseline: 1.3098x; 1.0179x over previous
//
#include <hip/hip_runtime.h>

#define CONC_N 2000
#define ITEM_N 20000
#define STU_N  50000
#define NE_CC  40000
#define NE_IC  80000
#define NE_SI  1000000
#define TBUCK  382   // 63+63+79+79+98

typedef unsigned int uint;
typedef unsigned short ushort;
typedef signed char s8;
typedef __attribute__((ext_vector_type(8))) short bf16x8;
typedef __attribute__((ext_vector_type(4))) float f32x4;

__device__ __forceinline__ ushort f2bf(float f) {
  uint u = __float_as_uint(f);
  uint r = (u + 0x7FFFu + ((u >> 16) & 1u)) >> 16;
  return (ushort)r;
}

__device__ __forceinline__ bf16x8 packfrag(float4 lo, float4 hi) {
  union { bf16x8 s; uint u[4]; } p;
  p.u[0] = (uint)f2bf(lo.x) | ((uint)f2bf(lo.y) << 16);
  p.u[1] = (uint)f2bf(lo.z) | ((uint)f2bf(lo.w) << 16);
  p.u[2] = (uint)f2bf(hi.x) | ((uint)f2bf(hi.y) << 16);
  p.u[3] = (uint)f2bf(hi.z) | ((uint)f2bf(hi.w) << 16);
  return p.s;
}

// ---------------- CSR structures ----------------

struct CsrG {
  const int* dst; const int* src;
  unsigned* keys; int* srcs; int* offs;
  int E, n, shift, nbuck, tb, sb;
};
struct CsrGs { CsrG g[5]; };

// ------- setup: proj vectors (LDS-staged) + CSR histograms + W->frag-bf16 --

struct ProjDesc { const float* W; const float* a; float* out; };
struct SetupArgs {
  ProjDesc p[10];
  CsrGs G;
  int* pcnt;                 // [5*32][128]
  const float* wsrc[5];
  ushort* wdst[5];           // fragment-ordered bf16, 2048 recs x 16B
};

__global__ __launch_bounds__(256) void setup_k(SetupArgs A) {
  int b = blockIdx.x;
  int tid = threadIdx.x;
  if (b < 10) {              // proj: out = W^T a, LDS-staged coalesced
    __shared__ float Wl[128 * 132];
    __shared__ float a_s[128];
    ProjDesc d = A.p[b];
    #pragma unroll
    for (int i = 0; i < 16; ++i) {
      int s = tid + i * 256;
      int row = s >> 5, c4 = s & 31;
      float4 w = *(const float4*)&d.W[s * 4];
      float* dst = &Wl[row * 132 + c4 * 4];
      dst[0] = w.x; dst[1] = w.y; dst[2] = w.z; dst[3] = w.w;
    }
    if (tid < 128) a_s[tid] = d.a[tid];
    __syncthreads();
    if (tid < 128) {
      float acc = 0.f;
      #pragma unroll 4
      for (int j = 0; j < 128; ++j) acc += Wl[j * 132 + tid] * a_s[j];
      d.out[tid] = acc;
    }
    return;
  }
  if (b >= 170) {            // W fp32 -> fragment-ordered bf16
    int wi = b - 170;
    const float* Ws = A.wsrc[wi];
    ushort* Wd = A.wdst[wi];
    for (int rec = tid; rec < 2048; rec += 256) {
      int lane = rec & 63;
      int kk = (rec >> 6) & 3;
      int nt = rec >> 8;
      int x = lane & 15, g = lane >> 4;
      const float* src = &Ws[(nt * 16 + x) * 128 + kk * 32 + 4 * g];
      float4 lo = *(const float4*)src;
      float4 hi = *(const float4*)(src + 16);
      bf16x8 pk = packfrag(lo, hi);
      *(bf16x8*)&Wd[rec * 8] = pk;
    }
    return;
  }
  int bsel = b - 10;            // 0..159: histogram
  int gi = bsel >> 5, blk = bsel & 31;
  CsrG g = A.G.g[gi];
  __shared__ int lcnt[128];
  if (tid < 128) lcnt[tid] = 0;
  __syncthreads();
  int chunk = (g.E + 31) >> 5;
  int e0 = blk * chunk, e1 = min(g.E, e0 + chunk);
  for (int e = e0 + tid; e < e1; e += 256)
    atomicAdd(&lcnt[g.dst[e] >> g.shift], 1);
  __syncthreads();
  if (tid < 128) A.pcnt[bsel * 128 + tid] = lcnt[tid];
}

// ---------------- CSR scan ----------------

__global__ __launch_bounds__(512) void csr_scan(CsrGs G, const int* __restrict__ pcnt,
                                                int* __restrict__ cur, int* __restrict__ bases) {
  __shared__ int lc[TBUCK];
  __shared__ int lb[TBUCK + 5];
  int tid = threadIdx.x, lane = tid & 63, wv = tid >> 6;
  if (tid < TBUCK) {
    int gi = 0;
    #pragma unroll
    for (int k = 1; k < 5; ++k) if (tid >= G.g[k].tb) gi = k;
    int b = tid - G.g[gi].tb;
    int s = 0;
    for (int blk = 0; blk < 32; ++blk) s += pcnt[((gi << 5) + blk) * 128 + b];
    lc[tid] = s;
  }
  __syncthreads();
  if (wv < 5) {
    CsrG g = G.g[wv];
    int carry = 0;
    for (int base = 0; base < g.nbuck; base += 64) {
      int idx = base + lane;
      int v = (idx < g.nbuck) ? lc[g.tb + idx] : 0;
      int incl = v;
      #pragma unroll
      for (int o = 1; o < 64; o <<= 1) {
        int y = __shfl_up(incl, o);
        if (lane >= o) incl += y;
      }
      if (idx < g.nbuck) lb[g.sb + idx] = carry + incl - v;
      carry += __shfl(incl, 63);
    }
    if (lane == 0) lb[g.sb + g.nbuck] = carry;
  }
  __syncthreads();
  if (tid < TBUCK + 5) bases[tid] = lb[tid];
  if (tid < TBUCK) {
    int gi = 0;
    for (int k = 1; k < 5; ++k) if (tid >= G.g[k].tb) gi = k;
    cur[tid] = lb[tid + gi];
  }
  if (tid < 5) G.g[tid].offs[G.g[tid].n] = G.g[tid].E;
}

// ------------- mid3_k: csr_partition (600 blks) ∥ rdot (1024 blks) --------

__device__ void partition_body(const CsrGs& G, int* __restrict__ cur, int gi, int bx,
                               int nbx, unsigned char* smem) {
  CsrG g = G.g[gi];
  unsigned* ck = (unsigned*)smem;                 // 16384 B
  unsigned char* cb = smem + 16384;               // 4096 B
  int* lcnt = (int*)(smem + 20480);               // 512 B
  int* lcur = (int*)(smem + 20992);               // 512 B
  int tid = threadIdx.x;
  unsigned dmask = (1u << g.shift) - 1;
  for (int c0 = bx * 4096; c0 < g.E; c0 += nbx * 4096) {
    if (tid < 128) lcnt[tid] = 0;
    __syncthreads();
    #pragma unroll
    for (int i = 0; i < 16; ++i) {
      int e = c0 + i * 256 + tid;
      if (e < g.E) {
        int d = g.dst[e], s = g.src[e];
        int b = d >> g.shift;
        ck[i * 256 + tid] = ((unsigned)(d & dmask) << 16) | (unsigned)s;
        cb[i * 256 + tid] = (unsigned char)b;
        atomicAdd(&lcnt[b], 1);
      } else cb[i * 256 + tid] = 255;
    }
    __syncthreads();
    if (tid < g.nbuck && lcnt[tid] > 0) lcur[tid] = atomicAdd(&cur[g.tb + tid], lcnt[tid]);
    __syncthreads();
    #pragma unroll
    for (int i = 0; i < 16; ++i) {
      int b = cb[i * 256 + tid];
      if (b != 255) {
        int pos = atomicAdd(&lcur[b], 1);
        g.keys[pos] = ck[i * 256 + tid];
      }
    }
    __syncthreads();
  }
}

__device__ void rdot_body(const float* __restrict__ x, const float* __restrict__ v,
                          float* __restrict__ o, int n, int blk, int nblk) {
  int lane = threadIdx.x & 63;
  int wid = (blk * 256 + threadIdx.x) >> 6;
  int nw = nblk * 4;
  float va = v[lane], vb = v[64 + lane];
  for (int r = wid; r < n; r += nw) {
    float a = x[r * 128 + lane] * va + x[r * 128 + 64 + lane] * vb;
    #pragma unroll
    for (int of = 32; of; of >>= 1) a += __shfl_xor(a, of);
    if (lane == 0) o[r] = a;
  }
}

__global__ __launch_bounds__(256) void mid3_k(CsrGs G, int* cur,
                                              const float* rx, const float* rv,
                                              float* ro, int rnb) {
  __shared__ __align__(16) unsigned char smem[21504];
  int b = blockIdx.x;
  if (b < 600) {
    partition_body(G, cur, b / 120, b % 120, 120, smem);
  } else {
    rdot_body(rx, rv, ro, STU_N, b - 600, rnb);
  }
}

// ------------- mid4_k: build_lite (382 blks) ∥ MFMA GEMMs -----------------

struct GemmDesc { const float* X; s8* Y8; float* S; int n, b0;
                  const float* dv[6]; float* dq[6]; };
struct BigC {
  GemmDesc g[5];
  int gemm_blocks;
};

__device__ void build_lite(const CsrGs& G, const int* __restrict__ bases, int bid,
                           int* lh, int* lex, int* lcu, int* wsum) {
  int gi = 0;
  for (int k = 1; k < 5; ++k) if (bid >= G.g[k].tb) gi = k;
  CsrG g = G.g[gi];
  int b = bid - g.tb;
  int base = bases[g.sb + b];
  int cnt = bases[g.sb + b + 1] - base;

  int tid = threadIdx.x;
  lh[tid] = 0; lh[tid + 256] = 0;
  __syncthreads();
  for (int j = tid; j < cnt; j += 256)
    atomicAdd(&lh[g.keys[base + j] >> 16], 1);
  __syncthreads();
  int a0 = lh[2 * tid], a1 = lh[2 * tid + 1];
  int pair = a0 + a1;
  int lane = tid & 63, wv = tid >> 6;
  int incl = pair;
  #pragma unroll
  for (int o = 1; o < 64; o <<= 1) {
    int y = __shfl_up(incl, o);
    if (lane >= o) incl += y;
  }
  if (lane == 63) wsum[wv] = incl;
  __syncthreads();
  if (tid == 0) {
    int s = 0;
    #pragma unroll
    for (int w = 0; w < 4; ++w) { int t = wsum[w]; wsum[w] = s; s += t; }
  }
  __syncthreads();
  int ep = wsum[wv] + incl - pair;
  lex[2 * tid] = ep;       lex[2 * tid + 1] = ep + a0;
  lcu[2 * tid] = ep;       lcu[2 * tid + 1] = ep + a0;
  __syncthreads();
  int dst0 = b << g.shift;
  int ndst = min(1 << g.shift, g.n - dst0);
  for (int dl = tid; dl < ndst; dl += 256) g.offs[dst0 + dl] = base + lex[dl];
  for (int j = tid; j < cnt; j += 256) {
    unsigned k = g.keys[base + j];
    int dl = k >> 16;
    int pos = atomicAdd(&lcu[dl], 1);
    g.srcs[base + pos] = (int)(k & 0xFFFFu);
  }
}

template <int NV>
__device__ void gemm_bodyT(const GemmDesc& gd, const ushort* __restrict__ Wf, int blk) {
  int tid = threadIdx.x;
  int lane = tid & 63, wv = tid >> 6;
  int x = lane & 15, g = lane >> 4;
  int row = blk * 64 + wv * 16 + x;
  const float* xr = &gd.X[(size_t)(row < gd.n ? row : 0) * 128];
  bf16x8 afrag[4];
  float dacc[NV == 0 ? 1 : NV];
  #pragma unroll
  for (int v = 0; v < NV; ++v) dacc[v] = 0.f;
  #pragma unroll
  for (int kk = 0; kk < 4; ++kk) {
    float4 lo = *(const float4*)&xr[kk * 32 + 4 * g];
    float4 hi = *(const float4*)&xr[kk * 32 + 16 + 4 * g];
    afrag[kk] = packfrag(lo, hi);
    #pragma unroll
    for (int v = 0; v < NV; ++v) {
      const float* vp = gd.dv[v];
      float4 vlo = *(const float4*)&vp[kk * 32 + 4 * g];
      float4 vhi = *(const float4*)&vp[kk * 32 + 16 + 4 * g];
      dacc[v] += lo.x * vlo.x + lo.y * vlo.y + lo.z * vlo.z + lo.w * vlo.w
               + hi.x * vhi.x + hi.y * vhi.y + hi.z * vhi.z + hi.w * vhi.w;
    }
  }
  #pragma unroll
  for (int v = 0; v < NV; ++v) {
    float dsum = dacc[v];
    dsum += __shfl_xor(dsum, 16);
    dsum += __shfl_xor(dsum, 32);
    if (lane < 16 && row < gd.n) gd.dq[v][row] = dsum;
  }
  f32x4 acc[8];
  #pragma unroll
  for (int t = 0; t < 8; ++t) acc[t] = (f32x4){0.f, 0.f, 0.f, 0.f};
  #pragma unroll
  for (int nt = 0; nt < 8; ++nt) {
    #pragma unroll
    for (int kk = 0; kk < 4; ++kk) {
      union { uint4 u; bf16x8 s; } bu;
      bu.u = *(const uint4*)&Wf[(size_t)((nt * 4 + kk) * 64 + lane) * 8];
      acc[nt] = __builtin_amdgcn_mfma_f32_16x16x32_bf16(afrag[kk], bu.s, acc[nt], 0, 0, 0);
    }
  }
  // D layout: col = lane&15, row = (lane>>4)*4 + r. Quantize per row to s8.
  int orow = blk * 64 + wv * 16 + 4 * g;
  #pragma unroll
  for (int r = 0; r < 4; ++r) {
    float m8 = 0.f;
    #pragma unroll
    for (int nt = 0; nt < 8; ++nt) m8 = fmaxf(m8, fabsf(acc[nt][r]));
    #pragma unroll
    for (int msk = 1; msk < 16; msk <<= 1) m8 = fmaxf(m8, __shfl_xor(m8, msk));
    int gr = orow + r;
    if (gr < gd.n) {
      float invs = (m8 > 0.f) ? 127.f / m8 : 0.f;
      if (x == 0) gd.S[gr] = m8 * (1.f / 127.f);
      #pragma unroll
      for (int nt = 0; nt < 8; ++nt) {
        int q = (int)rintf(acc[nt][r] * invs);
        gd.Y8[(size_t)gr * 128 + nt * 16 + x] = (s8)q;
      }
    }
  }
}

__global__ __launch_bounds__(256, 2) void mid4_k(CsrGs G, const int* bases, BigC C,
                                                 const ushort* W0, const ushort* W1,
                                                 const ushort* W2, const ushort* W3,
                                                 const ushort* W4) {
  __shared__ int lh[512], lex[512], lcu[512], wsum[4];
  int b = blockIdx.x;
  if (b < TBUCK) {
    build_lite(G, bases, b, lh, lex, lcu, wsum);
    return;
  }
  b -= TBUCK;
  if (b < C.g[1].b0)      gemm_bodyT<6>(C.g[0], W0, b - C.g[0].b0);
  else if (b < C.g[2].b0) gemm_bodyT<4>(C.g[1], W1, b - C.g[1].b0);
  else if (b < C.g[3].b0) gemm_bodyT<0>(C.g[2], W2, b - C.g[2].b0);
  else if (b < C.g[4].b0) gemm_bodyT<1>(C.g[3], W3, b - C.g[3].b0);
  else                    gemm_bodyT<0>(C.g[4], W4, b - C.g[4].b0);
}

// ---------------- GAT core: single-pass flash softmax, int8 gather --------

__device__ __forceinline__ void fma8q(float acc[8], float wj, uint2 u) {
  int lo = (int)u.x, hi = (int)u.y;
  acc[0] += wj * (float)((lo << 24) >> 24);
  acc[1] += wj * (float)((lo << 16) >> 24);
  acc[2] += wj * (float)((lo << 8) >> 24);
  acc[3] += wj * (float)(lo >> 24);
  acc[4] += wj * (float)((hi << 24) >> 24);
  acc[5] += wj * (float)((hi << 16) >> 24);
  acc[6] += wj * (float)((hi << 8) >> 24);
  acc[7] += wj * (float)(hi >> 24);
}

// t = t4 + (lane>>4); lane il = lane&15 owns dims il*8..il*8+7 (s8 codes).
// Single pass: online max/sum with acc rescale (flash-style), 4-deep loads.
__device__ void gat_core16(const int* __restrict__ offs, const int* __restrict__ srcs,
                           const float* __restrict__ sl, const float* __restrict__ sr,
                           const s8* __restrict__ x8, const float* __restrict__ sc,
                           int t4, int n_tgt, int lane, float acc[8]) {
  int q = lane >> 4, il = lane & 15;
  int t = t4 + q;
  bool tv = t < n_tgt;
  int sbeg = tv ? offs[t] : 0;
  int send = tv ? offs[t + 1] : 0;
  float srt = tv ? sr[t] : 0.f;

  float m = -1e30f, se = 0.f;
  #pragma unroll
  for (int r = 0; r < 8; ++r) acc[r] = 0.f;
  int qb = q << 4;

  for (int i0 = sbeg; i0 < send; i0 += 16) {
    int cnt = min(16, send - i0);
    int s = 0; float e = -1e30f, scs = 0.f;
    if (il < cnt) {
      s = srcs[i0 + il];
      float ee = sl[s] + srt;
      e = ee > 0.f ? ee : 0.2f * ee;
      scs = sc[s];
    }
    // group max of this chunk (offsets <16 stay within the 16-lane group)
    float cm = e;
    #pragma unroll
    for (int o = 8; o; o >>= 1) cm = fmaxf(cm, __shfl_xor(cm, o));
    float mn = fmaxf(m, cm);
    float f = __expf(m - mn);   // first chunk: exp(-inf)=0, acc/se are 0
    m = mn;
    se *= f;
    #pragma unroll
    for (int r = 0; r < 8; ++r) acc[r] *= f;
    float w = (il < cnt) ? __expf(e - m) : 0.f;
    se += w;
    float ws = w * scs;

    int j = 0;
    for (; j + 4 <= cnt; j += 4) {
      int sj0 = __shfl(s, qb + j);
      int sj1 = __shfl(s, qb + j + 1);
      int sj2 = __shfl(s, qb + j + 2);
      int sj3 = __shfl(s, qb + j + 3);
      float wj0 = __shfl(ws, qb + j);
      float wj1 = __shfl(ws, qb + j + 1);
      float wj2 = __shfl(ws, qb + j + 2);
      float wj3 = __shfl(ws, qb + j + 3);
      uint2 u0 = *(const uint2*)&x8[(size_t)sj0 * 128 + il * 8];
      uint2 u1 = *(const uint2*)&x8[(size_t)sj1 * 128 + il * 8];
      uint2 u2 = *(const uint2*)&x8[(size_t)sj2 * 128 + il * 8];
      uint2 u3 = *(const uint2*)&x8[(size_t)sj3 * 128 + il * 8];
      fma8q(acc, wj0, u0);
      fma8q(acc, wj1, u1);
      fma8q(acc, wj2, u2);
      fma8q(acc, wj3, u3);
    }
    for (; j < cnt; ++j) {
      int sj = __shfl(s, qb + j);
      float wj = __shfl(ws, qb + j);
      uint2 u = *(const uint2*)&x8[(size_t)sj * 128 + il * 8];
      fma8q(acc, wj, u);
    }
  }
  // reduce se across the 16-lane group, normalize
  #pragma unroll
  for (int o = 8; o; o >>= 1) se += __shfl_xor(se, o);
  float inv = 1.f / (se + 1e-16f);
  #pragma unroll
  for (int r = 0; r < 8; ++r) acc[r] *= inv;
}

__device__ __forceinline__ void gat_store16(const float acc[8], const float* base0,
                                            float* out, int t4, int n_tgt, int lane) {
  int q = lane >> 4, il = lane & 15;
  int t = t4 + q;
  if (t >= n_tgt) return;
  int d = t * 128 + il * 8;
  float4 a0 = make_float4(acc[0], acc[1], acc[2], acc[3]);
  float4 a1 = make_float4(acc[4], acc[5], acc[6], acc[7]);
  if (base0) {
    const float4 b0 = *(const float4*)&base0[d];
    const float4 b1 = *(const float4*)&base0[d + 4];
    a0.x += b0.x; a0.y += b0.y; a0.z += b0.z; a0.w += b0.w;
    a1.x += b1.x; a1.y += b1.y; a1.z += b1.z; a1.w += b1.w;
  }
  *(float4*)&out[d] = a0;
  *(float4*)&out[d + 4] = a1;
}

__device__ void c1c2_body16(const int* offs, const int* srcs, const float* sl,
                            const float* sr, const s8* x8, const float* sc,
                            const float* al, float* o, float* slo,
                            int t4, int n_tgt, int lane) {
  float acc[8];
  gat_core16(offs, srcs, sl, sr, x8, sc, t4, n_tgt, lane, acc);
  int q = lane >> 4, il = lane & 15;
  int t = t4 + q;
  float4 v0 = *(const float4*)&al[il * 8];
  float4 v1 = *(const float4*)&al[il * 8 + 4];
  float p = acc[0] * v0.x + acc[1] * v0.y + acc[2] * v0.z + acc[3] * v0.w +
            acc[4] * v1.x + acc[5] * v1.y + acc[6] * v1.z + acc[7] * v1.w;
  #pragma unroll
  for (int o2 = 8; o2; o2 >>= 1) p += __shfl_xor(p, o2);
  if (t < n_tgt) {
    if (il == 0) slo[t] = p;
    int d = t * 128 + il * 8;
    *(float4*)&o[d] = make_float4(acc[0], acc[1], acc[2], acc[3]);
    *(float4*)&o[d + 4] = make_float4(acc[4], acc[5], acc[6], acc[7]);
  }
}

// dual (fp32 gather of c1/c2 on cc graph), wave per target (small)
__device__ void gat_dual_core(const int* __restrict__ offs, const int* __restrict__ srcs,
                              const float* __restrict__ sl1, const float* __restrict__ sr1,
                              const float* __restrict__ xl1,
                              const float* __restrict__ sl2, const float* __restrict__ sr2,
                              const float* __restrict__ xl2,
                              const float* __restrict__ base,
                              float* __restrict__ out, int t, int lane) {
  int sbeg = offs[t], send = offs[t + 1];
  float srt1 = sr1[t], srt2 = sr2[t];
  float m1 = -1e30f, m2 = -1e30f;
  for (int i = sbeg + lane; i < send; i += 64) {
    int s = srcs[i];
    float e1 = sl1[s] + srt1; e1 = e1 > 0.f ? e1 : 0.2f * e1;
    float e2 = sl2[s] + srt2; e2 = e2 > 0.f ? e2 : 0.2f * e2;
    m1 = fmaxf(m1, e1); m2 = fmaxf(m2, e2);
  }
  #pragma unroll
  for (int o = 32; o; o >>= 1) {
    m1 = fmaxf(m1, __shfl_xor(m1, o));
    m2 = fmaxf(m2, __shfl_xor(m2, o));
  }
  float se1 = 0.f, se2 = 0.f;
  for (int i = sbeg + lane; i < send; i += 64) {
    int s = srcs[i];
    float e1 = sl1[s] + srt1; e1 = e1 > 0.f ? e1 : 0.2f * e1;
    float e2 = sl2[s] + srt2; e2 = e2 > 0.f ? e2 : 0.2f * e2;
    se1 += __expf(e1 - m1); se2 += __expf(e2 - m2);
  }
  #pragma unroll
  for (int o = 32; o; o >>= 1) {
    se1 += __shfl_xor(se1, o);
    se2 += __shfl_xor(se2, o);
  }
  float inv1 = 1.f / (se1 + 1e-16f), inv2 = 1.f / (se2 + 1e-16f);
  float ax = 0.f, ay = 0.f;
  for (int i0 = sbeg; i0 < send; i0 += 64) {
    int cnt = min(64, send - i0);
    int s = 0; float w1 = 0.f, w2 = 0.f;
    if (lane < cnt) {
      s = srcs[i0 + lane];
      float e1 = sl1[s] + srt1; e1 = e1 > 0.f ? e1 : 0.2f * e1;
      float e2 = sl2[s] + srt2; e2 = e2 > 0.f ? e2 : 0.2f * e2;
      w1 = __expf(e1 - m1) * inv1;
      w2 = __expf(e2 - m2) * inv2;
    }
    for (int j = 0; j < cnt; ++j) {
      int sj = __shfl(s, j);
      float wj1 = __shfl(w1, j);
      float wj2 = __shfl(w2, j);
      const float2 v1 = *(const float2*)&xl1[sj * 128 + lane * 2];
      const float2 v2 = *(const float2*)&xl2[sj * 128 + lane * 2];
      ax += wj1 * v1.x + wj2 * v2.x;
      ay += wj1 * v1.y + wj2 * v2.y;
    }
  }
  const float2 b = *(const float2*)&base[t * 128 + lane * 2];
  float2 o2; o2.x = ax + b.x; o2.y = ay + b.y;
  *(float2*)&out[t * 128 + lane * 2] = o2;
}

// ---- gats_k: [i1+i2 merged | s1 | c1c2], heavy blocks first ---------------

#define NB_I12 1250   // ceil(20000/16)
#define NB_S1  3125   // ceil(50000/16)
#define NB_CC  125    // ceil(2000/16)

struct GatsArgs {
  const int *offs4, *srcs4; const float *sl_is, *sr_is; const s8* x_is; const float* sc_is;
  const float* stu_raw_x; float* out_stu;
  const int *offs3, *srcs3; const float *sl_si, *sr_si; const s8* x_si; const float* sc_si;
  const int *offs2, *srcs2; const float *sl_ci, *sr_ci; const s8* x_ci; const float* sc_ci;
  const float* item_x; float* out_item;
  const int *offs0, *srcs0; const float *sl_cc, *sr_cc; const s8* x_cc; const float* sc_cc;
  const float* al_cce; float *c1, *sl_cce;
  const int *offs1, *srcs1; const float *sl_ic, *sr_ic; const s8* x_ic; const float* sc_ic;
  const float* al_ice; float *c2, *sl_ice;
};

__global__ void gats_k(GatsArgs A) {
  int b = blockIdx.x;
  int lane = threadIdx.x & 63;
  int wv = threadIdx.x >> 6;
  if (b < NB_I12) {
    int t4 = b * 16 + wv * 4;
    float acc1[8], acc2[8];
    gat_core16(A.offs2, A.srcs2, A.sl_ci, A.sr_ci, A.x_ci, A.sc_ci, t4, ITEM_N, lane, acc1);
    gat_core16(A.offs3, A.srcs3, A.sl_si, A.sr_si, A.x_si, A.sc_si, t4, ITEM_N, lane, acc2);
    #pragma unroll
    for (int r = 0; r < 8; ++r) acc1[r] += acc2[r];
    gat_store16(acc1, A.item_x, A.out_item, t4, ITEM_N, lane);
  } else if (b < NB_I12 + NB_S1) {
    int t4 = (b - NB_I12) * 16 + wv * 4;
    float acc[8];
    gat_core16(A.offs4, A.srcs4, A.sl_is, A.sr_is, A.x_is, A.sc_is, t4, STU_N, lane, acc);
    gat_store16(acc, A.stu_raw_x, A.out_stu, t4, STU_N, lane);
  } else {
    int sub = b - NB_I12 - NB_S1;   // 0..2*NB_CC-1
    int which = sub >= NB_CC;
    int t4 = (sub - which * NB_CC) * 16 + wv * 4;
    if (!which)
      c1c2_body16(A.offs0, A.srcs0, A.sl_cc, A.sr_cc, A.x_cc, A.sc_cc, A.al_cce,
                  A.c1, A.sl_cce, t4, CONC_N, lane);
    else
      c1c2_body16(A.offs1, A.srcs1, A.sl_ic, A.sr_ic, A.x_ic, A.sc_ic, A.al_ice,
                  A.c2, A.sl_ice, t4, CONC_N, lane);
  }
}

// ---- fin_k: dual(conc) only ----------------------------------------------

__global__ void fin_k(const int* offs0, const int* srcs0,
                      const float* sl_cce, const float* sr_cce, const float* c1,
                      const float* sl_ice, const float* sr_ice, const float* c2,
                      const float* conc_x, float* out_conc) {
  int t = (blockIdx.x * blockDim.x + threadIdx.x) >> 6;
  if (t >= CONC_N) return;
  gat_dual_core(offs0, srcs0, sl_cce, sr_cce, c1, sl_ice, sr_ice, c2,
                conc_x, out_conc, t, threadIdx.x & 63);
}

// ---------------- launch ----------------

extern "C" void kernel_launch(void* const* d_in, const int* in_sizes, int n_in,
                              void* d_out, int out_size, void* d_ws, size_t ws_size,
                              hipStream_t stream) {
  const float* stu_x     = (const float*)d_in[0];
  const float* item_x    = (const float*)d_in[1];
  const float* conc_x    = (const float*)d_in[2];
  const float* stu_raw_x = (const float*)d_in[3];
  const float* W_cc  = (const float*)d_in[4];
  const float* al_cc = (const float*)d_in[5];
  const float* ar_cc = (const float*)d_in[6];
  const float* W_ic  = (const float*)d_in[7];
  const float* al_ic = (const float*)d_in[8];
  const float* ar_ic = (const float*)d_in[9];
  const float* al_cce = (const float*)d_in[10];
  const float* ar_cce = (const float*)d_in[11];
  const float* al_ice = (const float*)d_in[12];
  const float* ar_ice = (const float*)d_in[13];
  const float* W_ci  = (const float*)d_in[14];
  const float* al_ci = (const float*)d_in[15];
  const float* ar_ci = (const float*)d_in[16];
  const float* W_si  = (const float*)d_in[17];
  const float* al_si = (const float*)d_in[18];
  const float* ar_si = (const float*)d_in[19];
  const float* W_is  = (const float*)d_in[22];
  const float* al_is = (const float*)d_in[23];
  const float* ar_is = (const float*)d_in[24];
  const int* cc_src  = (const int*)d_in[25];
  const int* cc_dst  = (const int*)d_in[26];
  const int* ic_item = (const int*)d_in[27];
  const int* ic_conc = (const int*)d_in[28];
  const int* si_stu  = (const int*)d_in[29];
  const int* si_item = (const int*)d_in[30];

  char* wsb = (char*)d_ws;
  size_t off = 0;
  auto alloc = [&](size_t bytes) -> void* {
    void* p = wsb + off;
    off = (off + bytes + 255) & ~(size_t)255;
    return p;
  };

  // int8 W-product tables (gather sources), 128 B/row + fp32 scale/row
  s8* concWcc = (s8*)alloc((size_t)CONC_N * 128);
  s8* itemWic = (s8*)alloc((size_t)ITEM_N * 128);
  s8* concWci = (s8*)alloc((size_t)CONC_N * 128);
  s8* stuWsi  = (s8*)alloc((size_t)STU_N  * 128);
  s8* itemWis = (s8*)alloc((size_t)ITEM_N * 128);
  float* scCcc = (float*)alloc(CONC_N * 4);
  float* scIic = (float*)alloc(ITEM_N * 4);
  float* scCci = (float*)alloc(CONC_N * 4);
  float* scSsi = (float*)alloc(STU_N * 4);
  float* scIis = (float*)alloc(ITEM_N * 4);
  ushort* Wbf[5];
  for (int i = 0; i < 5; ++i) Wbf[i] = (ushort*)alloc(128 * 128 * 2);
  float* c1buf   = (float*)alloc((size_t)CONC_N * 128 * 4);
  float* c2buf   = (float*)alloc((size_t)CONC_N * 128 * 4);
  float* vecs    = (float*)alloc(10 * 128 * 4);
  float* sl_cc  = (float*)alloc(CONC_N * 4);
  float* sr_cc  = (float*)alloc(CONC_N * 4);
  float* sl_ic  = (float*)alloc(ITEM_N * 4);
  float* sr_ic  = (float*)alloc(CONC_N * 4);
  float* sl_ci  = (float*)alloc(CONC_N * 4);
  float* sr_ci  = (float*)alloc(ITEM_N * 4);
  float* sl_si  = (float*)alloc(STU_N * 4);
  float* sr_si  = (float*)alloc(ITEM_N * 4);
  float* sl_is  = (float*)alloc(ITEM_N * 4);
  float* sr_is  = (float*)alloc(STU_N * 4);
  float* sl_cce = (float*)alloc(CONC_N * 4);
  float* sr_cce = (float*)alloc(CONC_N * 4);
  float* sl_ice = (float*)alloc(CONC_N * 4);
  float* sr_ice = (float*)alloc(CONC_N * 4);

  unsigned* keys0 = (unsigned*)alloc((size_t)NE_CC * 4);
  unsigned* keys1 = (unsigned*)alloc((size_t)NE_IC * 4);
  unsigned* keys2 = (unsigned*)alloc((size_t)NE_IC * 4);
  unsigned* keys3 = (unsigned*)alloc((size_t)NE_SI * 4);
  unsigned* keys4 = (unsigned*)alloc((size_t)NE_SI * 4);
  int* srcs0 = (int*)alloc((size_t)NE_CC * 4);
  int* srcs1 = (int*)alloc((size_t)NE_IC * 4);
  int* srcs2 = (int*)alloc((size_t)NE_IC * 4);
  int* srcs3 = (int*)alloc((size_t)NE_SI * 4);
  int* srcs4 = (int*)alloc((size_t)NE_SI * 4);
  int* offs0 = (int*)alloc((CONC_N + 1) * 4);
  int* offs1 = (int*)alloc((CONC_N + 1) * 4);
  int* offs2 = (int*)alloc((ITEM_N + 1) * 4);
  int* offs3 = (int*)alloc((ITEM_N + 1) * 4);
  int* offs4 = (int*)alloc((STU_N + 1) * 4);
  int* pcnt      = (int*)alloc(5 * 32 * 128 * 4);
  int* cur_all   = (int*)alloc(TBUCK * 4);
  int* bases_all = (int*)alloc((TBUCK + 5) * 4);

  float* out = (float*)d_out;
  float* out_conc = out;
  float* out_item = out + (size_t)CONC_N * 128;
  float* out_stu  = out + (size_t)(CONC_N + ITEM_N) * 128;

  CsrGs G;
  G.g[0] = {cc_dst,  cc_src,  keys0, srcs0, offs0, NE_CC, CONC_N, 5, 63,   0,   0};
  G.g[1] = {ic_conc, ic_item, keys1, srcs1, offs1, NE_IC, CONC_N, 5, 63,  63,  64};
  G.g[2] = {ic_item, ic_conc, keys2, srcs2, offs2, NE_IC, ITEM_N, 8, 79, 126, 128};
  G.g[3] = {si_item, si_stu,  keys3, srcs3, offs3, NE_SI, ITEM_N, 8, 79, 205, 208};
  G.g[4] = {si_stu,  si_item, keys4, srcs4, offs4, NE_SI, STU_N,  9, 98, 284, 288};

  // K1: setup (proj vectors + CSR histograms + W->frag-bf16)
  SetupArgs SA;
  SA.p[0] = {W_cc, al_cc, vecs + 0 * 128};
  SA.p[1] = {W_cc, ar_cc, vecs + 1 * 128};
  SA.p[2] = {W_ic, al_ic, vecs + 2 * 128};
  SA.p[3] = {W_ic, ar_ic, vecs + 3 * 128};
  SA.p[4] = {W_ci, al_ci, vecs + 4 * 128};
  SA.p[5] = {W_ci, ar_ci, vecs + 5 * 128};
  SA.p[6] = {W_si, al_si, vecs + 6 * 128};
  SA.p[7] = {W_si, ar_si, vecs + 7 * 128};
  SA.p[8] = {W_is, al_is, vecs + 8 * 128};
  SA.p[9] = {W_is, ar_is, vecs + 9 * 128};
  SA.G = G;
  SA.pcnt = pcnt;
  SA.wsrc[0] = W_cc; SA.wsrc[1] = W_ic; SA.wsrc[2] = W_ci;
  SA.wsrc[3] = W_si; SA.wsrc[4] = W_is;
  for (int i = 0; i < 5; ++i) SA.wdst[i] = Wbf[i];
  setup_k<<<175, 256, 0, stream>>>(SA);

  // K2: scan
  csr_scan<<<1, 512, 0, stream>>>(G, pcnt, cur_all, bases_all);

  // K3: partition (600) ∥ rdot (1024)
  mid3_k<<<600 + 1024, 256, 0, stream>>>(G, cur_all, stu_raw_x, vecs + 9 * 128,
                                         sr_is, 1024);

  // K4: build_lite (382) ∥ MFMA gemms (+fused dots, s8 output)
  BigC C;
  C.g[0] = {conc_x, concWcc, scCcc, CONC_N, 0,
            {vecs + 0 * 128, vecs + 1 * 128, vecs + 3 * 128, vecs + 4 * 128, ar_cce, ar_ice},
            {sl_cc, sr_cc, sr_ic, sl_ci, sr_cce, sr_ice}};
  C.g[1] = {item_x, itemWic, scIic, ITEM_N, 32,
            {vecs + 2 * 128, vecs + 5 * 128, vecs + 7 * 128, vecs + 8 * 128, nullptr, nullptr},
            {sl_ic, sr_ci, sr_si, sl_is, nullptr, nullptr}};
  C.g[2] = {conc_x, concWci, scCci, CONC_N, 345,
            {nullptr, nullptr, nullptr, nullptr, nullptr, nullptr},
            {nullptr, nullptr, nullptr, nullptr, nullptr, nullptr}};
  C.g[3] = {stu_x, stuWsi, scSsi, STU_N, 377,
            {vecs + 6 * 128, nullptr, nullptr, nullptr, nullptr, nullptr},
            {sl_si, nullptr, nullptr, nullptr, nullptr, nullptr}};
  C.g[4] = {item_x, itemWis, scIis, ITEM_N, 1159,
            {nullptr, nullptr, nullptr, nullptr, nullptr, nullptr},
            {nullptr, nullptr, nullptr, nullptr, nullptr, nullptr}};
  C.gemm_blocks = 1472;
  mid4_k<<<TBUCK + 1472, 256, 0, stream>>>(G, bases_all, C,
                                           Wbf[0], Wbf[1], Wbf[2], Wbf[3], Wbf[4]);

  // K5: all independent GATs in one launch (i1+i2 | s1 | c1c2), heavy first
  GatsArgs GA;
  GA.offs4 = offs4; GA.srcs4 = srcs4; GA.sl_is = sl_is; GA.sr_is = sr_is;
  GA.x_is = itemWis; GA.sc_is = scIis; GA.stu_raw_x = stu_raw_x; GA.out_stu = out_stu;
  GA.offs3 = offs3; GA.srcs3 = srcs3; GA.sl_si = sl_si; GA.sr_si = sr_si;
  GA.x_si = stuWsi; GA.sc_si = scSsi;
  GA.offs2 = offs2; GA.srcs2 = srcs2; GA.sl_ci = sl_ci; GA.sr_ci = sr_ci;
  GA.x_ci = concWci; GA.sc_ci = scCci; GA.item_x = item_x; GA.out_item = out_item;
  GA.offs0 = offs0; GA.srcs0 = srcs0; GA.sl_cc = sl_cc; GA.sr_cc = sr_cc;
  GA.x_cc = concWcc; GA.sc_cc = scCcc; GA.al_cce = al_cce; GA.c1 = c1buf; GA.sl_cce = sl_cce;
  GA.offs1 = offs1; GA.srcs1 = srcs1; GA.sl_ic = sl_ic; GA.sr_ic = sr_ic;
  GA.x_ic = itemWic; GA.sc_ic = scIic; GA.al_ice = al_ice; GA.c2 = c2buf; GA.sl_ice = sl_ice;
  gats_k<<<NB_I12 + NB_S1 + 2 * NB_CC, 256, 0, stream>>>(GA);

  // K6: dual (needs c1/c2 + their dots)
  fin_k<<<500, 256, 0, stream>>>(offs0, srcs0, sl_cce, sr_cce, c1buf,
                                 sl_ice, sr_ice, c2buf, conc_x, out_conc);
}

// Round 17
// 172.991 us; speedup vs baseline: 1.3859x; 1.0581x over previous
//
#include <hip/hip_runtime.h>

#define CONC_N 2000
#define ITEM_N 20000
#define STU_N  50000
#define NE_CC  40000
#define NE_IC  80000
#define NE_SI  1000000
#define TBUCK  382   // 63+63+79+79+98

typedef unsigned int uint;
typedef unsigned short ushort;
typedef signed char s8;
typedef __attribute__((ext_vector_type(8))) short bf16x8;
typedef __attribute__((ext_vector_type(4))) float f32x4;

__device__ __forceinline__ ushort f2bf(float f) {
  uint u = __float_as_uint(f);
  uint r = (u + 0x7FFFu + ((u >> 16) & 1u)) >> 16;
  return (ushort)r;
}

__device__ __forceinline__ bf16x8 packfrag(float4 lo, float4 hi) {
  union { bf16x8 s; uint u[4]; } p;
  p.u[0] = (uint)f2bf(lo.x) | ((uint)f2bf(lo.y) << 16);
  p.u[1] = (uint)f2bf(lo.z) | ((uint)f2bf(lo.w) << 16);
  p.u[2] = (uint)f2bf(hi.x) | ((uint)f2bf(hi.y) << 16);
  p.u[3] = (uint)f2bf(hi.z) | ((uint)f2bf(hi.w) << 16);
  return p.s;
}

// ---------------- CSR structures ----------------

struct CsrG {
  const int* dst; const int* src;
  unsigned* keys; int* srcs; int* offs;
  int E, n, shift, nbuck, tb, sb;
};
struct CsrGs { CsrG g[5]; };

// ------- setup: proj vectors (LDS-staged) + CSR histograms + W->frag-bf16 --

struct ProjDesc { const float* W; const float* a; float* out; };
struct SetupArgs {
  ProjDesc p[10];
  CsrGs G;
  int* pcnt;                 // [5*32][128]
  const float* wsrc[5];
  ushort* wdst[5];           // fragment-ordered bf16, 2048 recs x 16B
};

__global__ __launch_bounds__(256) void setup_k(SetupArgs A) {
  int b = blockIdx.x;
  int tid = threadIdx.x;
  if (b < 10) {              // proj: out = W^T a, LDS-staged coalesced
    __shared__ float Wl[128 * 132];
    __shared__ float a_s[128];
    ProjDesc d = A.p[b];
    #pragma unroll
    for (int i = 0; i < 16; ++i) {
      int s = tid + i * 256;
      int row = s >> 5, c4 = s & 31;
      float4 w = *(const float4*)&d.W[s * 4];
      float* dst = &Wl[row * 132 + c4 * 4];
      dst[0] = w.x; dst[1] = w.y; dst[2] = w.z; dst[3] = w.w;
    }
    if (tid < 128) a_s[tid] = d.a[tid];
    __syncthreads();
    if (tid < 128) {
      float acc = 0.f;
      #pragma unroll 4
      for (int j = 0; j < 128; ++j) acc += Wl[j * 132 + tid] * a_s[j];
      d.out[tid] = acc;
    }
    return;
  }
  if (b >= 170) {            // W fp32 -> fragment-ordered bf16
    int wi = b - 170;
    const float* Ws = A.wsrc[wi];
    ushort* Wd = A.wdst[wi];
    for (int rec = tid; rec < 2048; rec += 256) {
      int lane = rec & 63;
      int kk = (rec >> 6) & 3;
      int nt = rec >> 8;
      int x = lane & 15, g = lane >> 4;
      const float* src = &Ws[(nt * 16 + x) * 128 + kk * 32 + 4 * g];
      float4 lo = *(const float4*)src;
      float4 hi = *(const float4*)(src + 16);
      bf16x8 pk = packfrag(lo, hi);
      *(bf16x8*)&Wd[rec * 8] = pk;
    }
    return;
  }
  int bsel = b - 10;            // 0..159: histogram
  int gi = bsel >> 5, blk = bsel & 31;
  CsrG g = A.G.g[gi];
  __shared__ int lcnt[128];
  if (tid < 128) lcnt[tid] = 0;
  __syncthreads();
  int chunk = (g.E + 31) >> 5;
  int e0 = blk * chunk, e1 = min(g.E, e0 + chunk);
  for (int e = e0 + tid; e < e1; e += 256)
    atomicAdd(&lcnt[g.dst[e] >> g.shift], 1);
  __syncthreads();
  if (tid < 128) A.pcnt[bsel * 128 + tid] = lcnt[tid];
}

// ---------------- CSR scan ----------------

__global__ __launch_bounds__(512) void csr_scan(CsrGs G, const int* __restrict__ pcnt,
                                                int* __restrict__ cur, int* __restrict__ bases) {
  __shared__ int lc[TBUCK];
  __shared__ int lb[TBUCK + 5];
  int tid = threadIdx.x, lane = tid & 63, wv = tid >> 6;
  if (tid < TBUCK) {
    int gi = 0;
    #pragma unroll
    for (int k = 1; k < 5; ++k) if (tid >= G.g[k].tb) gi = k;
    int b = tid - G.g[gi].tb;
    int s = 0;
    for (int blk = 0; blk < 32; ++blk) s += pcnt[((gi << 5) + blk) * 128 + b];
    lc[tid] = s;
  }
  __syncthreads();
  if (wv < 5) {
    CsrG g = G.g[wv];
    int carry = 0;
    for (int base = 0; base < g.nbuck; base += 64) {
      int idx = base + lane;
      int v = (idx < g.nbuck) ? lc[g.tb + idx] : 0;
      int incl = v;
      #pragma unroll
      for (int o = 1; o < 64; o <<= 1) {
        int y = __shfl_up(incl, o);
        if (lane >= o) incl += y;
      }
      if (idx < g.nbuck) lb[g.sb + idx] = carry + incl - v;
      carry += __shfl(incl, 63);
    }
    if (lane == 0) lb[g.sb + g.nbuck] = carry;
  }
  __syncthreads();
  if (tid < TBUCK + 5) bases[tid] = lb[tid];
  if (tid < TBUCK) {
    int gi = 0;
    for (int k = 1; k < 5; ++k) if (tid >= G.g[k].tb) gi = k;
    cur[tid] = lb[tid + gi];
  }
  if (tid < 5) G.g[tid].offs[G.g[tid].n] = G.g[tid].E;
}

// ------------- mid3_k: csr_partition (600 blks) ∥ rdot (1024 blks) --------

__device__ void partition_body(const CsrGs& G, int* __restrict__ cur, int gi, int bx,
                               int nbx, unsigned char* smem) {
  CsrG g = G.g[gi];
  unsigned* ck = (unsigned*)smem;                 // 16384 B
  unsigned char* cb = smem + 16384;               // 4096 B
  int* lcnt = (int*)(smem + 20480);               // 512 B
  int* lcur = (int*)(smem + 20992);               // 512 B
  int tid = threadIdx.x;
  unsigned dmask = (1u << g.shift) - 1;
  for (int c0 = bx * 4096; c0 < g.E; c0 += nbx * 4096) {
    if (tid < 128) lcnt[tid] = 0;
    __syncthreads();
    #pragma unroll
    for (int i = 0; i < 16; ++i) {
      int e = c0 + i * 256 + tid;
      if (e < g.E) {
        int d = g.dst[e], s = g.src[e];
        int b = d >> g.shift;
        ck[i * 256 + tid] = ((unsigned)(d & dmask) << 16) | (unsigned)s;
        cb[i * 256 + tid] = (unsigned char)b;
        atomicAdd(&lcnt[b], 1);
      } else cb[i * 256 + tid] = 255;
    }
    __syncthreads();
    if (tid < g.nbuck && lcnt[tid] > 0) lcur[tid] = atomicAdd(&cur[g.tb + tid], lcnt[tid]);
    __syncthreads();
    #pragma unroll
    for (int i = 0; i < 16; ++i) {
      int b = cb[i * 256 + tid];
      if (b != 255) {
        int pos = atomicAdd(&lcur[b], 1);
        g.keys[pos] = ck[i * 256 + tid];
      }
    }
    __syncthreads();
  }
}

__device__ void rdot_body(const float* __restrict__ x, const float* __restrict__ v,
                          float* __restrict__ o, int n, int blk, int nblk) {
  int lane = threadIdx.x & 63;
  int wid = (blk * 256 + threadIdx.x) >> 6;
  int nw = nblk * 4;
  float va = v[lane], vb = v[64 + lane];
  for (int r = wid; r < n; r += nw) {
    float a = x[r * 128 + lane] * va + x[r * 128 + 64 + lane] * vb;
    #pragma unroll
    for (int of = 32; of; of >>= 1) a += __shfl_xor(a, of);
    if (lane == 0) o[r] = a;
  }
}

__global__ __launch_bounds__(256) void mid3_k(CsrGs G, int* cur,
                                              const float* rx, const float* rv,
                                              float* ro, int rnb) {
  __shared__ __align__(16) unsigned char smem[21504];
  int b = blockIdx.x;
  if (b < 600) {
    partition_body(G, cur, b / 120, b % 120, 120, smem);
  } else {
    rdot_body(rx, rv, ro, STU_N, b - 600, rnb);
  }
}

// ------------- mid4_k: build_lite (382 blks) ∥ MFMA GEMMs -----------------
// GEMM emits s8 codes + packed (score,scale) float2 tables.

struct GemmDesc { const float* X; s8* Y8; float2* SS; int n, b0;
                  const float* dv[6]; float* dq[6]; int ds[6]; };
struct BigC {
  GemmDesc g[5];
  int gemm_blocks;
};

__device__ void build_lite(const CsrGs& G, const int* __restrict__ bases, int bid,
                           int* lh, int* lex, int* lcu, int* wsum) {
  int gi = 0;
  for (int k = 1; k < 5; ++k) if (bid >= G.g[k].tb) gi = k;
  CsrG g = G.g[gi];
  int b = bid - g.tb;
  int base = bases[g.sb + b];
  int cnt = bases[g.sb + b + 1] - base;

  int tid = threadIdx.x;
  lh[tid] = 0; lh[tid + 256] = 0;
  __syncthreads();
  for (int j = tid; j < cnt; j += 256)
    atomicAdd(&lh[g.keys[base + j] >> 16], 1);
  __syncthreads();
  int a0 = lh[2 * tid], a1 = lh[2 * tid + 1];
  int pair = a0 + a1;
  int lane = tid & 63, wv = tid >> 6;
  int incl = pair;
  #pragma unroll
  for (int o = 1; o < 64; o <<= 1) {
    int y = __shfl_up(incl, o);
    if (lane >= o) incl += y;
  }
  if (lane == 63) wsum[wv] = incl;
  __syncthreads();
  if (tid == 0) {
    int s = 0;
    #pragma unroll
    for (int w = 0; w < 4; ++w) { int t = wsum[w]; wsum[w] = s; s += t; }
  }
  __syncthreads();
  int ep = wsum[wv] + incl - pair;
  lex[2 * tid] = ep;       lex[2 * tid + 1] = ep + a0;
  lcu[2 * tid] = ep;       lcu[2 * tid + 1] = ep + a0;
  __syncthreads();
  int dst0 = b << g.shift;
  int ndst = min(1 << g.shift, g.n - dst0);
  for (int dl = tid; dl < ndst; dl += 256) g.offs[dst0 + dl] = base + lex[dl];
  for (int j = tid; j < cnt; j += 256) {
    unsigned k = g.keys[base + j];
    int dl = k >> 16;
    int pos = atomicAdd(&lcu[dl], 1);
    g.srcs[base + pos] = (int)(k & 0xFFFFu);
  }
}

template <int NV>
__device__ void gemm_bodyT(const GemmDesc& gd, const ushort* __restrict__ Wf, int blk) {
  int tid = threadIdx.x;
  int lane = tid & 63, wv = tid >> 6;
  int x = lane & 15, g = lane >> 4;
  int row = blk * 64 + wv * 16 + x;
  const float* xr = &gd.X[(size_t)(row < gd.n ? row : 0) * 128];
  bf16x8 afrag[4];
  float dacc[NV == 0 ? 1 : NV];
  #pragma unroll
  for (int v = 0; v < NV; ++v) dacc[v] = 0.f;
  #pragma unroll
  for (int kk = 0; kk < 4; ++kk) {
    float4 lo = *(const float4*)&xr[kk * 32 + 4 * g];
    float4 hi = *(const float4*)&xr[kk * 32 + 16 + 4 * g];
    afrag[kk] = packfrag(lo, hi);
    #pragma unroll
    for (int v = 0; v < NV; ++v) {
      const float* vp = gd.dv[v];
      float4 vlo = *(const float4*)&vp[kk * 32 + 4 * g];
      float4 vhi = *(const float4*)&vp[kk * 32 + 16 + 4 * g];
      dacc[v] += lo.x * vlo.x + lo.y * vlo.y + lo.z * vlo.z + lo.w * vlo.w
               + hi.x * vhi.x + hi.y * vhi.y + hi.z * vhi.z + hi.w * vhi.w;
    }
  }
  #pragma unroll
  for (int v = 0; v < NV; ++v) {
    float dsum = dacc[v];
    dsum += __shfl_xor(dsum, 16);
    dsum += __shfl_xor(dsum, 32);
    if (lane < 16 && row < gd.n) gd.dq[v][(size_t)row * gd.ds[v]] = dsum;
  }
  f32x4 acc[8];
  #pragma unroll
  for (int t = 0; t < 8; ++t) acc[t] = (f32x4){0.f, 0.f, 0.f, 0.f};
  #pragma unroll
  for (int nt = 0; nt < 8; ++nt) {
    #pragma unroll
    for (int kk = 0; kk < 4; ++kk) {
      union { uint4 u; bf16x8 s; } bu;
      bu.u = *(const uint4*)&Wf[(size_t)((nt * 4 + kk) * 64 + lane) * 8];
      acc[nt] = __builtin_amdgcn_mfma_f32_16x16x32_bf16(afrag[kk], bu.s, acc[nt], 0, 0, 0);
    }
  }
  // D layout: col = lane&15, row = (lane>>4)*4 + r. Quantize per row to s8.
  int orow = blk * 64 + wv * 16 + 4 * g;
  #pragma unroll
  for (int r = 0; r < 4; ++r) {
    float m8 = 0.f;
    #pragma unroll
    for (int nt = 0; nt < 8; ++nt) m8 = fmaxf(m8, fabsf(acc[nt][r]));
    #pragma unroll
    for (int msk = 1; msk < 16; msk <<= 1) m8 = fmaxf(m8, __shfl_xor(m8, msk));
    int gr = orow + r;
    if (gr < gd.n) {
      float invs = (m8 > 0.f) ? 127.f / m8 : 0.f;
      if (x == 0) gd.SS[gr].y = m8 * (1.f / 127.f);
      #pragma unroll
      for (int nt = 0; nt < 8; ++nt) {
        int q = (int)rintf(acc[nt][r] * invs);
        gd.Y8[(size_t)gr * 128 + nt * 16 + x] = (s8)q;
      }
    }
  }
}

__global__ __launch_bounds__(256, 2) void mid4_k(CsrGs G, const int* bases, BigC C,
                                                 const ushort* W0, const ushort* W1,
                                                 const ushort* W2, const ushort* W3,
                                                 const ushort* W4) {
  __shared__ int lh[512], lex[512], lcu[512], wsum[4];
  int b = blockIdx.x;
  if (b < TBUCK) {
    build_lite(G, bases, b, lh, lex, lcu, wsum);
    return;
  }
  b -= TBUCK;
  if (b < C.g[1].b0)      gemm_bodyT<6>(C.g[0], W0, b - C.g[0].b0);
  else if (b < C.g[2].b0) gemm_bodyT<4>(C.g[1], W1, b - C.g[1].b0);
  else if (b < C.g[3].b0) gemm_bodyT<0>(C.g[2], W2, b - C.g[2].b0);
  else if (b < C.g[4].b0) gemm_bodyT<1>(C.g[3], W3, b - C.g[3].b0);
  else                    gemm_bodyT<0>(C.g[4], W4, b - C.g[4].b0);
}

// ---------------- GAT core: no-max softmax, packed (score,scale) gather ---

__device__ __forceinline__ void fma8q(float acc[8], float wj, uint2 u) {
  int lo = (int)u.x, hi = (int)u.y;
  acc[0] += wj * (float)((lo << 24) >> 24);
  acc[1] += wj * (float)((lo << 16) >> 24);
  acc[2] += wj * (float)((lo << 8) >> 24);
  acc[3] += wj * (float)(lo >> 24);
  acc[4] += wj * (float)((hi << 24) >> 24);
  acc[5] += wj * (float)((hi << 16) >> 24);
  acc[6] += wj * (float)((hi << 8) >> 24);
  acc[7] += wj * (float)(hi >> 24);
}

// t = t4 + (lane>>4); lane il = lane&15 owns dims il*8..il*8+7 (s8 codes).
// Direct exp (scores ~N(0,2); fminf(...,80) overflow guard), 4-deep loads.
__device__ void gat_core16(const int* __restrict__ offs, const int* __restrict__ srcs,
                           const float2* __restrict__ ssc, const float* __restrict__ sr,
                           const s8* __restrict__ x8,
                           int t4, int n_tgt, int lane, float acc[8]) {
  int q = lane >> 4, il = lane & 15;
  int t = t4 + q;
  bool tv = t < n_tgt;
  int sbeg = tv ? offs[t] : 0;
  int send = tv ? offs[t + 1] : 0;
  float srt = tv ? sr[t] : 0.f;

  float se = 0.f;
  #pragma unroll
  for (int r = 0; r < 8; ++r) acc[r] = 0.f;
  int qb = q << 4;

  for (int i0 = sbeg; i0 < send; i0 += 16) {
    int cnt = min(16, send - i0);
    int s = 0; float w = 0.f, ws = 0.f;
    if (il < cnt) {
      s = srcs[i0 + il];
      float2 ss = ssc[s];
      float ee = ss.x + srt;
      ee = ee > 0.f ? ee : 0.2f * ee;
      w = __expf(fminf(ee, 80.f));
      ws = w * ss.y;
    }
    se += w;
    int j = 0;
    for (; j + 4 <= cnt; j += 4) {
      int sj0 = __shfl(s, qb + j);
      int sj1 = __shfl(s, qb + j + 1);
      int sj2 = __shfl(s, qb + j + 2);
      int sj3 = __shfl(s, qb + j + 3);
      float wj0 = __shfl(ws, qb + j);
      float wj1 = __shfl(ws, qb + j + 1);
      float wj2 = __shfl(ws, qb + j + 2);
      float wj3 = __shfl(ws, qb + j + 3);
      uint2 u0 = *(const uint2*)&x8[(size_t)sj0 * 128 + il * 8];
      uint2 u1 = *(const uint2*)&x8[(size_t)sj1 * 128 + il * 8];
      uint2 u2 = *(const uint2*)&x8[(size_t)sj2 * 128 + il * 8];
      uint2 u3 = *(const uint2*)&x8[(size_t)sj3 * 128 + il * 8];
      fma8q(acc, wj0, u0);
      fma8q(acc, wj1, u1);
      fma8q(acc, wj2, u2);
      fma8q(acc, wj3, u3);
    }
    for (; j < cnt; ++j) {
      int sj = __shfl(s, qb + j);
      float wj = __shfl(ws, qb + j);
      uint2 u = *(const uint2*)&x8[(size_t)sj * 128 + il * 8];
      fma8q(acc, wj, u);
    }
  }
  // reduce se across the 16-lane group, normalize
  #pragma unroll
  for (int o = 8; o; o >>= 1) se += __shfl_xor(se, o);
  float inv = 1.f / (se + 1e-16f);
  #pragma unroll
  for (int r = 0; r < 8; ++r) acc[r] *= inv;
}

__device__ __forceinline__ void gat_store16(const float acc[8], const float* base0,
                                            float* out, int t4, int n_tgt, int lane) {
  int q = lane >> 4, il = lane & 15;
  int t = t4 + q;
  if (t >= n_tgt) return;
  int d = t * 128 + il * 8;
  float4 a0 = make_float4(acc[0], acc[1], acc[2], acc[3]);
  float4 a1 = make_float4(acc[4], acc[5], acc[6], acc[7]);
  if (base0) {
    const float4 b0 = *(const float4*)&base0[d];
    const float4 b1 = *(const float4*)&base0[d + 4];
    a0.x += b0.x; a0.y += b0.y; a0.z += b0.z; a0.w += b0.w;
    a1.x += b1.x; a1.y += b1.y; a1.z += b1.z; a1.w += b1.w;
  }
  *(float4*)&out[d] = a0;
  *(float4*)&out[d + 4] = a1;
}

__device__ void c1c2_body16(const int* offs, const int* srcs, const float2* ssc,
                            const float* sr, const s8* x8,
                            const float* al, float* o, float* slo,
                            int t4, int n_tgt, int lane) {
  float acc[8];
  gat_core16(offs, srcs, ssc, sr, x8, t4, n_tgt, lane, acc);
  int q = lane >> 4, il = lane & 15;
  int t = t4 + q;
  float4 v0 = *(const float4*)&al[il * 8];
  float4 v1 = *(const float4*)&al[il * 8 + 4];
  float p = acc[0] * v0.x + acc[1] * v0.y + acc[2] * v0.z + acc[3] * v0.w +
            acc[4] * v1.x + acc[5] * v1.y + acc[6] * v1.z + acc[7] * v1.w;
  #pragma unroll
  for (int o2 = 8; o2; o2 >>= 1) p += __shfl_xor(p, o2);
  if (t < n_tgt) {
    if (il == 0) slo[t] = p;
    int d = t * 128 + il * 8;
    *(float4*)&o[d] = make_float4(acc[0], acc[1], acc[2], acc[3]);
    *(float4*)&o[d + 4] = make_float4(acc[4], acc[5], acc[6], acc[7]);
  }
}

// dual (fp32 gather of c1/c2 on cc graph), wave per target (small)
__device__ void gat_dual_core(const int* __restrict__ offs, const int* __restrict__ srcs,
                              const float* __restrict__ sl1, const float* __restrict__ sr1,
                              const float* __restrict__ xl1,
                              const float* __restrict__ sl2, const float* __restrict__ sr2,
                              const float* __restrict__ xl2,
                              const float* __restrict__ base,
                              float* __restrict__ out, int t, int lane) {
  int sbeg = offs[t], send = offs[t + 1];
  float srt1 = sr1[t], srt2 = sr2[t];
  float m1 = -1e30f, m2 = -1e30f;
  for (int i = sbeg + lane; i < send; i += 64) {
    int s = srcs[i];
    float e1 = sl1[s] + srt1; e1 = e1 > 0.f ? e1 : 0.2f * e1;
    float e2 = sl2[s] + srt2; e2 = e2 > 0.f ? e2 : 0.2f * e2;
    m1 = fmaxf(m1, e1); m2 = fmaxf(m2, e2);
  }
  #pragma unroll
  for (int o = 32; o; o >>= 1) {
    m1 = fmaxf(m1, __shfl_xor(m1, o));
    m2 = fmaxf(m2, __shfl_xor(m2, o));
  }
  float se1 = 0.f, se2 = 0.f;
  for (int i = sbeg + lane; i < send; i += 64) {
    int s = srcs[i];
    float e1 = sl1[s] + srt1; e1 = e1 > 0.f ? e1 : 0.2f * e1;
    float e2 = sl2[s] + srt2; e2 = e2 > 0.f ? e2 : 0.2f * e2;
    se1 += __expf(e1 - m1); se2 += __expf(e2 - m2);
  }
  #pragma unroll
  for (int o = 32; o; o >>= 1) {
    se1 += __shfl_xor(se1, o);
    se2 += __shfl_xor(se2, o);
  }
  float inv1 = 1.f / (se1 + 1e-16f), inv2 = 1.f / (se2 + 1e-16f);
  float ax = 0.f, ay = 0.f;
  for (int i0 = sbeg; i0 < send; i0 += 64) {
    int cnt = min(64, send - i0);
    int s = 0; float w1 = 0.f, w2 = 0.f;
    if (lane < cnt) {
      s = srcs[i0 + lane];
      float e1 = sl1[s] + srt1; e1 = e1 > 0.f ? e1 : 0.2f * e1;
      float e2 = sl2[s] + srt2; e2 = e2 > 0.f ? e2 : 0.2f * e2;
      w1 = __expf(e1 - m1) * inv1;
      w2 = __expf(e2 - m2) * inv2;
    }
    for (int j = 0; j < cnt; ++j) {
      int sj = __shfl(s, j);
      float wj1 = __shfl(w1, j);
      float wj2 = __shfl(w2, j);
      const float2 v1 = *(const float2*)&xl1[sj * 128 + lane * 2];
      const float2 v2 = *(const float2*)&xl2[sj * 128 + lane * 2];
      ax += wj1 * v1.x + wj2 * v2.x;
      ay += wj1 * v1.y + wj2 * v2.y;
    }
  }
  const float2 b = *(const float2*)&base[t * 128 + lane * 2];
  float2 o2; o2.x = ax + b.x; o2.y = ay + b.y;
  *(float2*)&out[t * 128 + lane * 2] = o2;
}

// ---- gats_k: [i1+i2 merged | s1 | c1c2], heavy blocks first ---------------

#define NB_I12 1250   // ceil(20000/16)
#define NB_S1  3125   // ceil(50000/16)
#define NB_CC  125    // ceil(2000/16)

struct GatsArgs {
  const int *offs4, *srcs4; const float2* ssc_is; const float* sr_is;
  const s8* x_is; const float* stu_raw_x; float* out_stu;
  const int *offs3, *srcs3; const float2* ssc_si; const float* sr_si; const s8* x_si;
  const int *offs2, *srcs2; const float2* ssc_ci; const float* sr_ci; const s8* x_ci;
  const float* item_x; float* out_item;
  const int *offs0, *srcs0; const float2* ssc_cc; const float* sr_cc; const s8* x_cc;
  const float* al_cce; float *c1, *sl_cce;
  const int *offs1, *srcs1; const float2* ssc_ic; const float* sr_ic; const s8* x_ic;
  const float* al_ice; float *c2, *sl_ice;
};

__global__ void gats_k(GatsArgs A) {
  int b = blockIdx.x;
  int lane = threadIdx.x & 63;
  int wv = threadIdx.x >> 6;
  if (b < NB_I12) {
    int t4 = b * 16 + wv * 4;
    float acc1[8], acc2[8];
    gat_core16(A.offs2, A.srcs2, A.ssc_ci, A.sr_ci, A.x_ci, t4, ITEM_N, lane, acc1);
    gat_core16(A.offs3, A.srcs3, A.ssc_si, A.sr_si, A.x_si, t4, ITEM_N, lane, acc2);
    #pragma unroll
    for (int r = 0; r < 8; ++r) acc1[r] += acc2[r];
    gat_store16(acc1, A.item_x, A.out_item, t4, ITEM_N, lane);
  } else if (b < NB_I12 + NB_S1) {
    int t4 = (b - NB_I12) * 16 + wv * 4;
    float acc[8];
    gat_core16(A.offs4, A.srcs4, A.ssc_is, A.sr_is, A.x_is, t4, STU_N, lane, acc);
    gat_store16(acc, A.stu_raw_x, A.out_stu, t4, STU_N, lane);
  } else {
    int sub = b - NB_I12 - NB_S1;   // 0..2*NB_CC-1
    int which = sub >= NB_CC;
    int t4 = (sub - which * NB_CC) * 16 + wv * 4;
    if (!which)
      c1c2_body16(A.offs0, A.srcs0, A.ssc_cc, A.sr_cc, A.x_cc, A.al_cce,
                  A.c1, A.sl_cce, t4, CONC_N, lane);
    else
      c1c2_body16(A.offs1, A.srcs1, A.ssc_ic, A.sr_ic, A.x_ic, A.al_ice,
                  A.c2, A.sl_ice, t4, CONC_N, lane);
  }
}

// ---- fin_k: dual(conc) only ----------------------------------------------

__global__ void fin_k(const int* offs0, const int* srcs0,
                      const float* sl_cce, const float* sr_cce, const float* c1,
                      const float* sl_ice, const float* sr_ice, const float* c2,
                      const float* conc_x, float* out_conc) {
  int t = (blockIdx.x * blockDim.x + threadIdx.x) >> 6;
  if (t >= CONC_N) return;
  gat_dual_core(offs0, srcs0, sl_cce, sr_cce, c1, sl_ice, sr_ice, c2,
                conc_x, out_conc, t, threadIdx.x & 63);
}

// ---------------- launch ----------------

extern "C" void kernel_launch(void* const* d_in, const int* in_sizes, int n_in,
                              void* d_out, int out_size, void* d_ws, size_t ws_size,
                              hipStream_t stream) {
  const float* stu_x     = (const float*)d_in[0];
  const float* item_x    = (const float*)d_in[1];
  const float* conc_x    = (const float*)d_in[2];
  const float* stu_raw_x = (const float*)d_in[3];
  const float* W_cc  = (const float*)d_in[4];
  const float* al_cc = (const float*)d_in[5];
  const float* ar_cc = (const float*)d_in[6];
  const float* W_ic  = (const float*)d_in[7];
  const float* al_ic = (const float*)d_in[8];
  const float* ar_ic = (const float*)d_in[9];
  const float* al_cce = (const float*)d_in[10];
  const float* ar_cce = (const float*)d_in[11];
  const float* al_ice = (const float*)d_in[12];
  const float* ar_ice = (const float*)d_in[13];
  const float* W_ci  = (const float*)d_in[14];
  const float* al_ci = (const float*)d_in[15];
  const float* ar_ci = (const float*)d_in[16];
  const float* W_si  = (const float*)d_in[17];
  const float* al_si = (const float*)d_in[18];
  const float* ar_si = (const float*)d_in[19];
  const float* W_is  = (const float*)d_in[22];
  const float* al_is = (const float*)d_in[23];
  const float* ar_is = (const float*)d_in[24];
  const int* cc_src  = (const int*)d_in[25];
  const int* cc_dst  = (const int*)d_in[26];
  const int* ic_item = (const int*)d_in[27];
  const int* ic_conc = (const int*)d_in[28];
  const int* si_stu  = (const int*)d_in[29];
  const int* si_item = (const int*)d_in[30];

  char* wsb = (char*)d_ws;
  size_t off = 0;
  auto alloc = [&](size_t bytes) -> void* {
    void* p = wsb + off;
    off = (off + bytes + 255) & ~(size_t)255;
    return p;
  };

  // int8 W-product tables + packed (score,scale) float2 tables
  s8* concWcc = (s8*)alloc((size_t)CONC_N * 128);
  s8* itemWic = (s8*)alloc((size_t)ITEM_N * 128);
  s8* concWci = (s8*)alloc((size_t)CONC_N * 128);
  s8* stuWsi  = (s8*)alloc((size_t)STU_N  * 128);
  s8* itemWis = (s8*)alloc((size_t)ITEM_N * 128);
  float2* ssc_cc = (float2*)alloc((size_t)CONC_N * 8);
  float2* ssc_ic = (float2*)alloc((size_t)ITEM_N * 8);
  float2* ssc_ci = (float2*)alloc((size_t)CONC_N * 8);
  float2* ssc_si = (float2*)alloc((size_t)STU_N * 8);
  float2* ssc_is = (float2*)alloc((size_t)ITEM_N * 8);
  ushort* Wbf[5];
  for (int i = 0; i < 5; ++i) Wbf[i] = (ushort*)alloc(128 * 128 * 2);
  float* c1buf   = (float*)alloc((size_t)CONC_N * 128 * 4);
  float* c2buf   = (float*)alloc((size_t)CONC_N * 128 * 4);
  float* vecs    = (float*)alloc(10 * 128 * 4);
  float* sr_cc  = (float*)alloc(CONC_N * 4);
  float* sr_ic  = (float*)alloc(CONC_N * 4);
  float* sr_ci  = (float*)alloc(ITEM_N * 4);
  float* sr_si  = (float*)alloc(ITEM_N * 4);
  float* sr_is  = (float*)alloc(STU_N * 4);
  float* sl_cce = (float*)alloc(CONC_N * 4);
  float* sr_cce = (float*)alloc(CONC_N * 4);
  float* sl_ice = (float*)alloc(CONC_N * 4);
  float* sr_ice = (float*)alloc(CONC_N * 4);

  unsigned* keys0 = (unsigned*)alloc((size_t)NE_CC * 4);
  unsigned* keys1 = (unsigned*)alloc((size_t)NE_IC * 4);
  unsigned* keys2 = (unsigned*)alloc((size_t)NE_IC * 4);
  unsigned* keys3 = (unsigned*)alloc((size_t)NE_SI * 4);
  unsigned* keys4 = (unsigned*)alloc((size_t)NE_SI * 4);
  int* srcs0 = (int*)alloc((size_t)NE_CC * 4);
  int* srcs1 = (int*)alloc((size_t)NE_IC * 4);
  int* srcs2 = (int*)alloc((size_t)NE_IC * 4);
  int* srcs3 = (int*)alloc((size_t)NE_SI * 4);
  int* srcs4 = (int*)alloc((size_t)NE_SI * 4);
  int* offs0 = (int*)alloc((CONC_N + 1) * 4);
  int* offs1 = (int*)alloc((CONC_N + 1) * 4);
  int* offs2 = (int*)alloc((ITEM_N + 1) * 4);
  int* offs3 = (int*)alloc((ITEM_N + 1) * 4);
  int* offs4 = (int*)alloc((STU_N + 1) * 4);
  int* pcnt      = (int*)alloc(5 * 32 * 128 * 4);
  int* cur_all   = (int*)alloc(TBUCK * 4);
  int* bases_all = (int*)alloc((TBUCK + 5) * 4);

  float* out = (float*)d_out;
  float* out_conc = out;
  float* out_item = out + (size_t)CONC_N * 128;
  float* out_stu  = out + (size_t)(CONC_N + ITEM_N) * 128;

  CsrGs G;
  G.g[0] = {cc_dst,  cc_src,  keys0, srcs0, offs0, NE_CC, CONC_N, 5, 63,   0,   0};
  G.g[1] = {ic_conc, ic_item, keys1, srcs1, offs1, NE_IC, CONC_N, 5, 63,  63,  64};
  G.g[2] = {ic_item, ic_conc, keys2, srcs2, offs2, NE_IC, ITEM_N, 8, 79, 126, 128};
  G.g[3] = {si_item, si_stu,  keys3, srcs3, offs3, NE_SI, ITEM_N, 8, 79, 205, 208};
  G.g[4] = {si_stu,  si_item, keys4, srcs4, offs4, NE_SI, STU_N,  9, 98, 284, 288};

  // K1: setup (proj vectors + CSR histograms + W->frag-bf16)
  SetupArgs SA;
  SA.p[0] = {W_cc, al_cc, vecs + 0 * 128};
  SA.p[1] = {W_cc, ar_cc, vecs + 1 * 128};
  SA.p[2] = {W_ic, al_ic, vecs + 2 * 128};
  SA.p[3] = {W_ic, ar_ic, vecs + 3 * 128};
  SA.p[4] = {W_ci, al_ci, vecs + 4 * 128};
  SA.p[5] = {W_ci, ar_ci, vecs + 5 * 128};
  SA.p[6] = {W_si, al_si, vecs + 6 * 128};
  SA.p[7] = {W_si, ar_si, vecs + 7 * 128};
  SA.p[8] = {W_is, al_is, vecs + 8 * 128};
  SA.p[9] = {W_is, ar_is, vecs + 9 * 128};
  SA.G = G;
  SA.pcnt = pcnt;
  SA.wsrc[0] = W_cc; SA.wsrc[1] = W_ic; SA.wsrc[2] = W_ci;
  SA.wsrc[3] = W_si; SA.wsrc[4] = W_is;
  for (int i = 0; i < 5; ++i) SA.wdst[i] = Wbf[i];
  setup_k<<<175, 256, 0, stream>>>(SA);

  // K2: scan
  csr_scan<<<1, 512, 0, stream>>>(G, pcnt, cur_all, bases_all);

  // K3: partition (600) ∥ rdot (1024)
  mid3_k<<<600 + 1024, 256, 0, stream>>>(G, cur_all, stu_raw_x, vecs + 9 * 128,
                                         sr_is, 1024);

  // K4: build_lite (382) ∥ MFMA gemms (+fused dots -> packed ssc, s8 output)
  BigC C;
  C.g[0] = {conc_x, concWcc, ssc_cc, CONC_N, 0,
            {vecs + 0 * 128, vecs + 1 * 128, vecs + 3 * 128, vecs + 4 * 128, ar_cce, ar_ice},
            {(float*)ssc_cc, sr_cc, sr_ic, (float*)ssc_ci, sr_cce, sr_ice},
            {2, 1, 1, 2, 1, 1}};
  C.g[1] = {item_x, itemWic, ssc_ic, ITEM_N, 32,
            {vecs + 2 * 128, vecs + 5 * 128, vecs + 7 * 128, vecs + 8 * 128, nullptr, nullptr},
            {(float*)ssc_ic, sr_ci, sr_si, (float*)ssc_is, nullptr, nullptr},
            {2, 1, 1, 2, 1, 1}};
  C.g[2] = {conc_x, concWci, ssc_ci, CONC_N, 345,
            {nullptr, nullptr, nullptr, nullptr, nullptr, nullptr},
            {nullptr, nullptr, nullptr, nullptr, nullptr, nullptr},
            {1, 1, 1, 1, 1, 1}};
  C.g[3] = {stu_x, stuWsi, ssc_si, STU_N, 377,
            {vecs + 6 * 128, nullptr, nullptr, nullptr, nullptr, nullptr},
            {(float*)ssc_si, nullptr, nullptr, nullptr, nullptr, nullptr},
            {2, 1, 1, 1, 1, 1}};
  C.g[4] = {item_x, itemWis, ssc_is, ITEM_N, 1159,
            {nullptr, nullptr, nullptr, nullptr, nullptr, nullptr},
            {nullptr, nullptr, nullptr, nullptr, nullptr, nullptr},
            {1, 1, 1, 1, 1, 1}};
  C.gemm_blocks = 1472;
  mid4_k<<<TBUCK + 1472, 256, 0, stream>>>(G, bases_all, C,
                                           Wbf[0], Wbf[1], Wbf[2], Wbf[3], Wbf[4]);

  // K5: all independent GATs in one launch (i1+i2 | s1 | c1c2), heavy first
  GatsArgs GA;
  GA.offs4 = offs4; GA.srcs4 = srcs4; GA.ssc_is = ssc_is; GA.sr_is = sr_is;
  GA.x_is = itemWis; GA.stu_raw_x = stu_raw_x; GA.out_stu = out_stu;
  GA.offs3 = offs3; GA.srcs3 = srcs3; GA.ssc_si = ssc_si; GA.sr_si = sr_si;
  GA.x_si = stuWsi;
  GA.offs2 = offs2; GA.srcs2 = srcs2; GA.ssc_ci = ssc_ci; GA.sr_ci = sr_ci;
  GA.x_ci = concWci; GA.item_x = item_x; GA.out_item = out_item;
  GA.offs0 = offs0; GA.srcs0 = srcs0; GA.ssc_cc = ssc_cc; GA.sr_cc = sr_cc;
  GA.x_cc = concWcc; GA.al_cce = al_cce; GA.c1 = c1buf; GA.sl_cce = sl_cce;
  GA.offs1 = offs1; GA.srcs1 = srcs1; GA.ssc_ic = ssc_ic; GA.sr_ic = sr_ic;
  GA.x_ic = itemWic; GA.al_ice = al_ice; GA.c2 = c2buf; GA.sl_ice = sl_ice;
  gats_k<<<NB_I12 + NB_S1 + 2 * NB_CC, 256, 0, stream>>>(GA);

  // K6: dual (needs c1/c2 + their dots)
  fin_k<<<500, 256, 0, stream>>>(offs0, srcs0, sl_cce, sr_cce, c1buf,
                                 sl_ice, sr_ice, c2buf, conc_x, out_conc);
}